// Round 6
// baseline (375.838 us; speedup 1.0000x reference)
//
#include <hip/hip_runtime.h>
#include <hip/hip_bf16.h>
#include <stdint.h>

typedef __attribute__((ext_vector_type(8))) short bf16x8;
typedef __attribute__((ext_vector_type(4))) float f32x4;
typedef __attribute__((ext_vector_type(4))) unsigned short us4;

#define AS1C(p) ((const __attribute__((address_space(1))) void*)(p))
#define AS3(p)  ((__attribute__((address_space(3))) void*)(p))

// raw v_exp_f32 (2^x). exp2f (libm) lowers to OCML with denormal fixup — slow.
#if __has_builtin(__builtin_amdgcn_exp2f)
#define EXP2(x) __builtin_amdgcn_exp2f(x)
#else
#define EXP2(x) __expf((x) * 0.69314718f)
#endif

static __device__ __forceinline__ unsigned short f2b(float f) {
  union { __hip_bfloat16 h; unsigned short u; } cv;
  cv.h = __float2bfloat16(f);
  return cv.u;
}

// ---------------------------------------------------------------------------
// Conversions
// ---------------------------------------------------------------------------
__global__ __launch_bounds__(256) void conv_x_kernel(const float* __restrict__ x,
                                                     unsigned short* __restrict__ xb,
                                                     int n4) {
  int i = blockIdx.x * 256 + threadIdx.x;
  if (i >= n4) return;
  float4 v = ((const float4*)x)[i];
  us4 r = { f2b(v.x), f2b(v.y), f2b(v.z), f2b(v.w) };
  *(us4*)&xb[(size_t)i * 4] = r;
}

// WqkvT[n][d] = W_{which}[h][d][c],  n = which*1024 + h*64 + c
__global__ __launch_bounds__(256) void conv_wqkv_kernel(const float* __restrict__ Wq,
                                                        const float* __restrict__ Wk,
                                                        const float* __restrict__ Wv,
                                                        unsigned short* __restrict__ WqkvT) {
  int bid = blockIdx.x;          // 3*16*16 = 768 blocks
  int which = bid >> 8;
  int h  = (bid >> 4) & 15;
  int dt = bid & 15;
  const float* W = (which == 0) ? Wq : (which == 1 ? Wk : Wv);
  __shared__ float tile[64][65];
  const int t = threadIdx.x;
  const int c  = t & 63;
  const int r0 = t >> 6;         // 0..3
  const float* src = W + (size_t)h * 65536 + (size_t)dt * 64 * 64;
#pragma unroll
  for (int it = 0; it < 16; ++it) {
    int r = r0 + it * 4;
    tile[r][c] = src[r * 64 + c];     // tile[d_local][c_local]
  }
  __syncthreads();
  const size_t n0 = (size_t)which * 1024 + h * 64;
  const int d0 = dt * 64;
#pragma unroll
  for (int it = 0; it < 16; ++it) {
    int cc = r0 + it * 4;             // c_local (output row)
    WqkvT[(n0 + cc) * 1024 + d0 + c] = f2b(tile[c][cc]);
  }
}

// WoT[n][k] = Wo[k][n]
__global__ __launch_bounds__(256) void conv_wo_kernel(const float* __restrict__ Wo,
                                                      unsigned short* __restrict__ WoT) {
  int kt = blockIdx.x >> 4, nt = blockIdx.x & 15;   // 256 blocks
  __shared__ float tile[64][65];
  const int t = threadIdx.x;
  const int c  = t & 63;
  const int r0 = t >> 6;
  const float* src = Wo + (size_t)(kt * 64) * 1024 + nt * 64;
#pragma unroll
  for (int it = 0; it < 16; ++it) {
    int r = r0 + it * 4;
    tile[r][c] = src[(size_t)r * 1024 + c];   // tile[k_local][n_local]
  }
  __syncthreads();
#pragma unroll
  for (int it = 0; it < 16; ++it) {
    int cc = r0 + it * 4;                     // n_local (output row)
    WoT[((size_t)nt * 64 + cc) * 1024 + kt * 64 + c] = f2b(tile[c][cc]);
  }
}

// ---------------------------------------------------------------------------
// GEMM 1: C[8192][3072] = x_bf16 [8192][1024] * WqkvT[3072][1024]^T
// epilogue: Q pre-scaled by (1/8)*log2(e) (exp2-folded softmax); K straight;
// V written TRANSPOSED into Vt[B*H][dk][S] (us4 packed stores, j spans s).
// ---------------------------------------------------------------------------
__global__ __launch_bounds__(256) void gemm_qkv_kernel(
    const unsigned short* __restrict__ A,
    const unsigned short* __restrict__ Bt,
    unsigned short* __restrict__ Q,
    unsigned short* __restrict__ Ko,
    unsigned short* __restrict__ Vt) {
  __shared__ __align__(16) unsigned short sA[128 * 32];
  __shared__ __align__(16) unsigned short sB[128 * 32];
  const int tid  = threadIdx.x;
  const int lane = tid & 63;
  const int wid  = tid >> 6;
  const int wr = wid >> 1, wc = wid & 1;
  const int brow = blockIdx.y * 128;
  const int bcol = blockIdx.x * 128;
  const int K = 1024;

  f32x4 acc[4][4] = {};

  const int r4 = tid >> 2;          // 0..63
  const int c8 = (tid & 3) * 8;
  const unsigned short* ga = A  + (size_t)(brow + r4) * K + c8;
  const unsigned short* gb = Bt + (size_t)(bcol + r4) * K + c8;
  unsigned short* lAw = sA + wid * 512;   // wave-uniform LDS base (lane*16B added by HW)
  unsigned short* lBw = sB + wid * 512;

  for (int kb = 0; kb < K; kb += 32) {
    if (kb) __syncthreads();
    __builtin_amdgcn_global_load_lds(AS1C(ga + kb),            AS3(lAw),        16, 0, 0);
    __builtin_amdgcn_global_load_lds(AS1C(ga + 64 * K + kb),   AS3(lAw + 2048), 16, 0, 0);
    __builtin_amdgcn_global_load_lds(AS1C(gb + kb),            AS3(lBw),        16, 0, 0);
    __builtin_amdgcn_global_load_lds(AS1C(gb + 64 * K + kb),   AS3(lBw + 2048), 16, 0, 0);
    __syncthreads();

    bf16x8 af[4], bfr[4];
#pragma unroll
    for (int mi = 0; mi < 4; ++mi)
      af[mi] = *(const bf16x8*)&sA[(wr * 64 + mi * 16 + (lane & 15)) * 32 + (lane >> 4) * 8];
#pragma unroll
    for (int ni = 0; ni < 4; ++ni)
      bfr[ni] = *(const bf16x8*)&sB[(wc * 64 + ni * 16 + (lane & 15)) * 32 + (lane >> 4) * 8];
#pragma unroll
    for (int mi = 0; mi < 4; ++mi)
#pragma unroll
      for (int ni = 0; ni < 4; ++ni)
        acc[mi][ni] = __builtin_amdgcn_mfma_f32_16x16x32_bf16(af[mi], bfr[ni], acc[mi][ni], 0, 0, 0);
  }

#pragma unroll
  for (int mi = 0; mi < 4; ++mi) {
    int row0 = brow + wr * 64 + mi * 16 + (lane >> 4) * 4;
    int b = row0 >> 11, s0 = row0 & 2047;
#pragma unroll
    for (int ni = 0; ni < 4; ++ni) {
      int col = bcol + wc * 64 + ni * 16 + (lane & 15);
      int which = col >> 10;      // block-uniform
      int h  = (col >> 6) & 15;
      int kk = col & 63;
      if (which == 2) {
        us4 pk = { f2b(acc[mi][ni][0]), f2b(acc[mi][ni][1]),
                   f2b(acc[mi][ni][2]), f2b(acc[mi][ni][3]) };
        *(us4*)&Vt[((size_t)(b * 16 + h) * 64 + kk) * 2048 + s0] = pk;
      } else {
        unsigned short* dst = (which == 0) ? Q : Ko;
        // Q: fold 1/sqrt(dk) * log2(e) so softmax uses raw v_exp (2^x)
        float scl = (which == 0) ? 0.18033688f : 1.0f;
#pragma unroll
        for (int j = 0; j < 4; ++j)
          dst[((size_t)(b * 16 + h) * 2048 + (s0 + j)) * 64 + kk] = f2b(acc[mi][ni][j] * scl);
      }
    }
  }
}

// ---------------------------------------------------------------------------
// GEMM 2: out[8192][1024] (fp32) = O_bf16 [8192][1024] * WoT[1024][1024]^T
// ---------------------------------------------------------------------------
__global__ __launch_bounds__(256) void gemm_out_kernel(
    const unsigned short* __restrict__ A,
    const unsigned short* __restrict__ Bt,
    float* __restrict__ out) {
  __shared__ __align__(16) unsigned short sA[128 * 32];
  __shared__ __align__(16) unsigned short sB[128 * 32];
  const int tid  = threadIdx.x;
  const int lane = tid & 63;
  const int wid  = tid >> 6;
  const int wr = wid >> 1, wc = wid & 1;
  const int brow = blockIdx.y * 128;
  const int bcol = blockIdx.x * 128;
  const int K = 1024;

  f32x4 acc[4][4] = {};

  const int r4 = tid >> 2;
  const int c8 = (tid & 3) * 8;
  const unsigned short* ga = A  + (size_t)(brow + r4) * K + c8;
  const unsigned short* gb = Bt + (size_t)(bcol + r4) * K + c8;
  unsigned short* lAw = sA + wid * 512;
  unsigned short* lBw = sB + wid * 512;

  for (int kb = 0; kb < K; kb += 32) {
    if (kb) __syncthreads();
    __builtin_amdgcn_global_load_lds(AS1C(ga + kb),          AS3(lAw),        16, 0, 0);
    __builtin_amdgcn_global_load_lds(AS1C(ga + 64 * K + kb), AS3(lAw + 2048), 16, 0, 0);
    __builtin_amdgcn_global_load_lds(AS1C(gb + kb),          AS3(lBw),        16, 0, 0);
    __builtin_amdgcn_global_load_lds(AS1C(gb + 64 * K + kb), AS3(lBw + 2048), 16, 0, 0);
    __syncthreads();

    bf16x8 af[4], bfr[4];
#pragma unroll
    for (int mi = 0; mi < 4; ++mi)
      af[mi] = *(const bf16x8*)&sA[(wr * 64 + mi * 16 + (lane & 15)) * 32 + (lane >> 4) * 8];
#pragma unroll
    for (int ni = 0; ni < 4; ++ni)
      bfr[ni] = *(const bf16x8*)&sB[(wc * 64 + ni * 16 + (lane & 15)) * 32 + (lane >> 4) * 8];
#pragma unroll
    for (int mi = 0; mi < 4; ++mi)
#pragma unroll
      for (int ni = 0; ni < 4; ++ni)
        acc[mi][ni] = __builtin_amdgcn_mfma_f32_16x16x32_bf16(af[mi], bfr[ni], acc[mi][ni], 0, 0, 0);
  }

#pragma unroll
  for (int mi = 0; mi < 4; ++mi) {
    int row0 = brow + wr * 64 + mi * 16 + (lane >> 4) * 4;
#pragma unroll
    for (int ni = 0; ni < 4; ++ni) {
      int col = bcol + wc * 64 + ni * 16 + (lane & 15);
#pragma unroll
      for (int j = 0; j < 4; ++j)
        out[(size_t)(row0 + j) * 1024 + col] = acc[mi][ni][j];
    }
  }
}

// ---------------------------------------------------------------------------
// Flash attention, swapped QK^T + defer-max + exp2-folded softmax.
// BARRIER-FREE: K/V fragments read directly from global (L2-resident thanks
// to the XCD relabel: 8 bh x 512KB = 4MB per XCD = one L2). Only per-wave
// P-exchange uses LDS (no cross-wave sharing -> no __syncthreads at all).
// Q,K: [64][2048][64] bf16 (Q pre-scaled by 0.125*log2e).  Vt: [64][64][2048].
// O: [4][2048][1024] bf16.
// mfma(K,Q) -> C col = q = lane&15, row = key = (lane>>4)*4+reg.
// ---------------------------------------------------------------------------
__global__ __launch_bounds__(256) void attn_kernel(
    const unsigned short* __restrict__ Q,
    const unsigned short* __restrict__ K,
    const unsigned short* __restrict__ Vt,
    unsigned short* __restrict__ O) {
  __shared__ __align__(16) unsigned short sP[8][16 * 72];  // [w*2+mi][q][key] pad 72

  const int tid = threadIdx.x, lane = tid & 63, w = tid >> 6;
  const int l15 = lane & 15, hi = lane >> 4;
  // bijective XCD relabel: dispatch n -> xcd = n&7; 8 bh per XCD, 16 q-blocks each
  const int n = blockIdx.x + (blockIdx.y << 4);
  const int bh = (n & 7) * 8 + ((n >> 3) >> 4);
  const int qx = (n >> 3) & 15;
  const int qb = qx * 128;
  const unsigned short* Qp  = Q  + (size_t)bh * 131072;
  const unsigned short* Kp  = K  + (size_t)bh * 131072;
  const unsigned short* Vtp = Vt + (size_t)bh * 131072;

  bf16x8 qf[2][2];
#pragma unroll
  for (int mi = 0; mi < 2; ++mi) {
    int qrow = qb + w * 32 + mi * 16 + l15;
    qf[mi][0] = *(const bf16x8*)&Qp[(size_t)qrow * 64 + hi * 8];
    qf[mi][1] = *(const bf16x8*)&Qp[(size_t)qrow * 64 + 32 + hi * 8];
  }

  f32x4 o[2][4] = {};
  float m_[2] = { 0.f, 0.f };      // defer-max: start at 0 (scores log2-scaled)
  float l_[2] = { 0.f, 0.f };

  // per-lane fragment base pointers (advance by one tile each iteration)
  const unsigned short* kfp = Kp  + (size_t)l15 * 64 + hi * 8;           // + ni*1024 + kcol*64
  const unsigned short* vfp = Vtp + (size_t)l15 * 2048 + hi * 8;         // + ni*32768 + kcol

  for (int kt = 0; kt < 32; ++kt) {
    // ---- QK^T: K fragments straight from global/L2 (shared by both mi) ----
    f32x4 sc[2][4] = {};
    {
      bf16x8 kf0[4], kf1[4];
#pragma unroll
      for (int ni = 0; ni < 4; ++ni) {
        kf0[ni] = *(const bf16x8*)(kfp + ni * 1024);
        kf1[ni] = *(const bf16x8*)(kfp + ni * 1024 + 32);
      }
      __builtin_amdgcn_s_setprio(1);
#pragma unroll
      for (int ni = 0; ni < 4; ++ni)
#pragma unroll
        for (int mi = 0; mi < 2; ++mi) {
          sc[mi][ni] = __builtin_amdgcn_mfma_f32_16x16x32_bf16(kf0[ni], qf[mi][0], sc[mi][ni], 0, 0, 0);
          sc[mi][ni] = __builtin_amdgcn_mfma_f32_16x16x32_bf16(kf1[ni], qf[mi][1], sc[mi][ni], 0, 0, 0);
        }
      __builtin_amdgcn_s_setprio(0);
    }
    kfp += 4096;

    // ---- online softmax (per mi; one q-row per lane) ----
#pragma unroll
    for (int mi = 0; mi < 2; ++mi) {
      float mx0 = fmaxf(fmaxf(sc[mi][0][0], sc[mi][0][1]), fmaxf(sc[mi][0][2], sc[mi][0][3]));
      float mx1 = fmaxf(fmaxf(sc[mi][1][0], sc[mi][1][1]), fmaxf(sc[mi][1][2], sc[mi][1][3]));
      float mx2 = fmaxf(fmaxf(sc[mi][2][0], sc[mi][2][1]), fmaxf(sc[mi][2][2], sc[mi][2][3]));
      float mx3 = fmaxf(fmaxf(sc[mi][3][0], sc[mi][3][1]), fmaxf(sc[mi][3][2], sc[mi][3][3]));
      float pmax = fmaxf(fmaxf(mx0, mx1), fmaxf(mx2, mx3));
      pmax = fmaxf(pmax, __shfl_xor(pmax, 16));
      pmax = fmaxf(pmax, __shfl_xor(pmax, 32));

      // T13: rescale only if P would exceed 2^8 (never fires on sane data)
      if (!__all(pmax - m_[mi] <= 8.0f)) {
        float mnew  = fmaxf(m_[mi], pmax);
        float alpha = EXP2(m_[mi] - mnew);
        l_[mi] *= alpha;
#pragma unroll
        for (int j = 0; j < 4; ++j) {
          float aj = __shfl(alpha, hi * 4 + j);
#pragma unroll
          for (int ni = 0; ni < 4; ++ni) o[mi][ni][j] *= aj;
        }
        m_[mi] = mnew;
      }

      const float mcur = m_[mi];
      f32x4 sum4 = {};
#pragma unroll
      for (int ni = 0; ni < 4; ++ni)
#pragma unroll
        for (int r = 0; r < 4; ++r) {
          float p = EXP2(sc[mi][ni][r] - mcur);
          sc[mi][ni][r] = p;
          sum4[r] += p;
        }
      float rsum = (sum4[0] + sum4[1]) + (sum4[2] + sum4[3]);
      rsum += __shfl_xor(rsum, 16);
      rsum += __shfl_xor(rsum, 32);
      l_[mi] += rsum;

      // P -> per-wave LDS [q=l15][key], packed us4 (4 consecutive keys)
      unsigned short* pb = &sP[w * 2 + mi][l15 * 72];
#pragma unroll
      for (int ni = 0; ni < 4; ++ni) {
        us4 pk = { f2b(sc[mi][ni][0]), f2b(sc[mi][ni][1]), f2b(sc[mi][ni][2]), f2b(sc[mi][ni][3]) };
        *(us4*)&pb[ni * 16 + hi * 4] = pk;
      }
    }

    // ---- PV: V^T fragments straight from global/L2 ----
    bf16x8 pa[2][2];
#pragma unroll
    for (int mi = 0; mi < 2; ++mi) {
      pa[mi][0] = *(const bf16x8*)&sP[w * 2 + mi][l15 * 72 + hi * 8];
      pa[mi][1] = *(const bf16x8*)&sP[w * 2 + mi][l15 * 72 + 32 + hi * 8];
    }
    {
      bf16x8 vf0[4], vf1[4];
#pragma unroll
      for (int ni = 0; ni < 4; ++ni) {
        vf0[ni] = *(const bf16x8*)(vfp + (size_t)ni * 32768);
        vf1[ni] = *(const bf16x8*)(vfp + (size_t)ni * 32768 + 32);
      }
      __builtin_amdgcn_s_setprio(1);
#pragma unroll
      for (int ni = 0; ni < 4; ++ni)
#pragma unroll
        for (int mi = 0; mi < 2; ++mi) {
          o[mi][ni] = __builtin_amdgcn_mfma_f32_16x16x32_bf16(pa[mi][0], vf0[ni], o[mi][ni], 0, 0, 0);
          o[mi][ni] = __builtin_amdgcn_mfma_f32_16x16x32_bf16(pa[mi][1], vf1[ni], o[mi][ni], 0, 0, 0);
        }
      __builtin_amdgcn_s_setprio(0);
    }
    vfp += 64;
  }

  const int b = bh >> 4, h = bh & 15;
#pragma unroll
  for (int mi = 0; mi < 2; ++mi) {
    float linv = 1.0f / l_[mi];
#pragma unroll
    for (int j = 0; j < 4; ++j) {
      float inv = __shfl(linv, hi * 4 + j);
      int row = qb + w * 32 + mi * 16 + hi * 4 + j;
#pragma unroll
      for (int ni = 0; ni < 4; ++ni)
        O[((size_t)b * 2048 + row) * 1024 + h * 64 + ni * 16 + l15] = f2b(o[mi][ni][j] * inv);
    }
  }
}

// ---------------------------------------------------------------------------
extern "C" void kernel_launch(void* const* d_in, const int* in_sizes, int n_in,
                              void* d_out, int out_size, void* d_ws, size_t ws_size,
                              hipStream_t stream) {
  const float* x  = (const float*)d_in[0];
  const float* Wq = (const float*)d_in[1];
  const float* Wk = (const float*)d_in[2];
  const float* Wv = (const float*)d_in[3];
  const float* Wo = (const float*)d_in[4];
  float* out = (float*)d_out;

  char* w = (char*)d_ws;
  unsigned short* xb   = (unsigned short*)(w);                       // 16 MB
  unsigned short* wqkv = (unsigned short*)(w + 16777216);            //  6 MB
  unsigned short* wo   = (unsigned short*)(w + 23068672);            //  2 MB
  unsigned short* Qb   = (unsigned short*)(w + 25165824);            // 16 MB
  unsigned short* Kb   = (unsigned short*)(w + 41943040);            // 16 MB
  unsigned short* Vtb  = (unsigned short*)(w + 58720256);            // 16 MB (V transposed)
  unsigned short* Ob   = (unsigned short*)(w + 75497472);            // 16 MB

  conv_x_kernel<<<8192, 256, 0, stream>>>(x, xb, 2097152);
  conv_wqkv_kernel<<<768, 256, 0, stream>>>(Wq, Wk, Wv, wqkv);
  conv_wo_kernel<<<256, 256, 0, stream>>>(Wo, wo);
  gemm_qkv_kernel<<<dim3(24, 64), 256, 0, stream>>>(xb, wqkv, Qb, Kb, Vtb);
  attn_kernel<<<dim3(16, 64), 256, 0, stream>>>(Qb, Kb, Vtb, Ob);
  gemm_out_kernel<<<dim3(8, 64), 256, 0, stream>>>(Ob, wo, out);
}

// Round 7
// 234.816 us; speedup vs baseline: 1.6006x; 1.6006x over previous
//
#include <hip/hip_runtime.h>
#include <hip/hip_bf16.h>
#include <stdint.h>

typedef __attribute__((ext_vector_type(8))) short bf16x8;
typedef __attribute__((ext_vector_type(4))) float f32x4;
typedef __attribute__((ext_vector_type(4))) unsigned short us4;

#define AS1C(p) ((const __attribute__((address_space(1))) void*)(p))
#define AS3(p)  ((__attribute__((address_space(3))) void*)(p))

// raw v_exp_f32 (2^x). exp2f (libm) lowers to OCML with denormal fixup — slow.
#if __has_builtin(__builtin_amdgcn_exp2f)
#define EXP2(x) __builtin_amdgcn_exp2f(x)
#else
#define EXP2(x) __expf((x) * 0.69314718f)
#endif

static __device__ __forceinline__ unsigned short f2b(float f) {
  union { __hip_bfloat16 h; unsigned short u; } cv;
  cv.h = __float2bfloat16(f);
  return cv.u;
}

// pack two f32 -> two bf16 in one u32 (round-half-up: +0x8000 then truncate).
// 2 v_add + 1 v_perm (or v_and_or) vs ~10 ops for two __float2bfloat16.
static __device__ __forceinline__ unsigned int pack2bf(float a, float b) {
  union { float f; unsigned int u; } ua, ub;
  ua.f = a; ub.f = b;
  unsigned int x = ua.u + 0x8000u, y = ub.u + 0x8000u;
#if __has_builtin(__builtin_amdgcn_perm)
  return __builtin_amdgcn_perm(y, x, 0x07060302u);   // {y.b7,y.b6,x.b3,x.b2}
#else
  return (x >> 16) | (y & 0xFFFF0000u);
#endif
}

// ---------------------------------------------------------------------------
// Conversions
// ---------------------------------------------------------------------------
__global__ __launch_bounds__(256) void conv_x_kernel(const float* __restrict__ x,
                                                     unsigned short* __restrict__ xb,
                                                     int n4) {
  int i = blockIdx.x * 256 + threadIdx.x;
  if (i >= n4) return;
  float4 v = ((const float4*)x)[i];
  us4 r = { f2b(v.x), f2b(v.y), f2b(v.z), f2b(v.w) };
  *(us4*)&xb[(size_t)i * 4] = r;
}

// WqkvT[n][d] = W_{which}[h][d][c],  n = which*1024 + h*64 + c
__global__ __launch_bounds__(256) void conv_wqkv_kernel(const float* __restrict__ Wq,
                                                        const float* __restrict__ Wk,
                                                        const float* __restrict__ Wv,
                                                        unsigned short* __restrict__ WqkvT) {
  int bid = blockIdx.x;          // 3*16*16 = 768 blocks
  int which = bid >> 8;
  int h  = (bid >> 4) & 15;
  int dt = bid & 15;
  const float* W = (which == 0) ? Wq : (which == 1 ? Wk : Wv);
  __shared__ float tile[64][65];
  const int t = threadIdx.x;
  const int c  = t & 63;
  const int r0 = t >> 6;         // 0..3
  const float* src = W + (size_t)h * 65536 + (size_t)dt * 64 * 64;
#pragma unroll
  for (int it = 0; it < 16; ++it) {
    int r = r0 + it * 4;
    tile[r][c] = src[r * 64 + c];     // tile[d_local][c_local]
  }
  __syncthreads();
  const size_t n0 = (size_t)which * 1024 + h * 64;
  const int d0 = dt * 64;
#pragma unroll
  for (int it = 0; it < 16; ++it) {
    int cc = r0 + it * 4;             // c_local (output row)
    WqkvT[(n0 + cc) * 1024 + d0 + c] = f2b(tile[c][cc]);
  }
}

// WoT[n][k] = Wo[k][n]
__global__ __launch_bounds__(256) void conv_wo_kernel(const float* __restrict__ Wo,
                                                      unsigned short* __restrict__ WoT) {
  int kt = blockIdx.x >> 4, nt = blockIdx.x & 15;   // 256 blocks
  __shared__ float tile[64][65];
  const int t = threadIdx.x;
  const int c  = t & 63;
  const int r0 = t >> 6;
  const float* src = Wo + (size_t)(kt * 64) * 1024 + nt * 64;
#pragma unroll
  for (int it = 0; it < 16; ++it) {
    int r = r0 + it * 4;
    tile[r][c] = src[(size_t)r * 1024 + c];   // tile[k_local][n_local]
  }
  __syncthreads();
#pragma unroll
  for (int it = 0; it < 16; ++it) {
    int cc = r0 + it * 4;                     // n_local (output row)
    WoT[((size_t)nt * 64 + cc) * 1024 + kt * 64 + c] = f2b(tile[c][cc]);
  }
}

// ---------------------------------------------------------------------------
// GEMM 1: C[8192][3072] = x_bf16 [8192][1024] * WqkvT[3072][1024]^T
// epilogue: Q pre-scaled by (1/8)*log2(e) (exp2-folded softmax); K straight;
// V written TRANSPOSED into Vt[B*H][dk][S] (us4 packed stores, j spans s).
// ---------------------------------------------------------------------------
__global__ __launch_bounds__(256) void gemm_qkv_kernel(
    const unsigned short* __restrict__ A,
    const unsigned short* __restrict__ Bt,
    unsigned short* __restrict__ Q,
    unsigned short* __restrict__ Ko,
    unsigned short* __restrict__ Vt) {
  __shared__ __align__(16) unsigned short sA[128 * 32];
  __shared__ __align__(16) unsigned short sB[128 * 32];
  const int tid  = threadIdx.x;
  const int lane = tid & 63;
  const int wid  = tid >> 6;
  const int wr = wid >> 1, wc = wid & 1;
  const int brow = blockIdx.y * 128;
  const int bcol = blockIdx.x * 128;
  const int K = 1024;

  f32x4 acc[4][4] = {};

  const int r4 = tid >> 2;          // 0..63
  const int c8 = (tid & 3) * 8;
  const unsigned short* ga = A  + (size_t)(brow + r4) * K + c8;
  const unsigned short* gb = Bt + (size_t)(bcol + r4) * K + c8;
  unsigned short* lAw = sA + wid * 512;   // wave-uniform LDS base (lane*16B added by HW)
  unsigned short* lBw = sB + wid * 512;

  for (int kb = 0; kb < K; kb += 32) {
    if (kb) __syncthreads();
    __builtin_amdgcn_global_load_lds(AS1C(ga + kb),            AS3(lAw),        16, 0, 0);
    __builtin_amdgcn_global_load_lds(AS1C(ga + 64 * K + kb),   AS3(lAw + 2048), 16, 0, 0);
    __builtin_amdgcn_global_load_lds(AS1C(gb + kb),            AS3(lBw),        16, 0, 0);
    __builtin_amdgcn_global_load_lds(AS1C(gb + 64 * K + kb),   AS3(lBw + 2048), 16, 0, 0);
    __syncthreads();

    bf16x8 af[4], bfr[4];
#pragma unroll
    for (int mi = 0; mi < 4; ++mi)
      af[mi] = *(const bf16x8*)&sA[(wr * 64 + mi * 16 + (lane & 15)) * 32 + (lane >> 4) * 8];
#pragma unroll
    for (int ni = 0; ni < 4; ++ni)
      bfr[ni] = *(const bf16x8*)&sB[(wc * 64 + ni * 16 + (lane & 15)) * 32 + (lane >> 4) * 8];
#pragma unroll
    for (int mi = 0; mi < 4; ++mi)
#pragma unroll
      for (int ni = 0; ni < 4; ++ni)
        acc[mi][ni] = __builtin_amdgcn_mfma_f32_16x16x32_bf16(af[mi], bfr[ni], acc[mi][ni], 0, 0, 0);
  }

#pragma unroll
  for (int mi = 0; mi < 4; ++mi) {
    int row0 = brow + wr * 64 + mi * 16 + (lane >> 4) * 4;
    int b = row0 >> 11, s0 = row0 & 2047;
#pragma unroll
    for (int ni = 0; ni < 4; ++ni) {
      int col = bcol + wc * 64 + ni * 16 + (lane & 15);
      int which = col >> 10;      // block-uniform
      int h  = (col >> 6) & 15;
      int kk = col & 63;
      if (which == 2) {
        us4 pk = { f2b(acc[mi][ni][0]), f2b(acc[mi][ni][1]),
                   f2b(acc[mi][ni][2]), f2b(acc[mi][ni][3]) };
        *(us4*)&Vt[((size_t)(b * 16 + h) * 64 + kk) * 2048 + s0] = pk;
      } else {
        unsigned short* dst = (which == 0) ? Q : Ko;
        // Q: fold 1/sqrt(dk) * log2(e) so softmax uses raw v_exp (2^x)
        float scl = (which == 0) ? 0.18033688f : 1.0f;
#pragma unroll
        for (int j = 0; j < 4; ++j)
          dst[((size_t)(b * 16 + h) * 2048 + (s0 + j)) * 64 + kk] = f2b(acc[mi][ni][j] * scl);
      }
    }
  }
}

// ---------------------------------------------------------------------------
// GEMM 2: out[8192][1024] (fp32) = O_bf16 [8192][1024] * WoT[1024][1024]^T
// ---------------------------------------------------------------------------
__global__ __launch_bounds__(256) void gemm_out_kernel(
    const unsigned short* __restrict__ A,
    const unsigned short* __restrict__ Bt,
    float* __restrict__ out) {
  __shared__ __align__(16) unsigned short sA[128 * 32];
  __shared__ __align__(16) unsigned short sB[128 * 32];
  const int tid  = threadIdx.x;
  const int lane = tid & 63;
  const int wid  = tid >> 6;
  const int wr = wid >> 1, wc = wid & 1;
  const int brow = blockIdx.y * 128;
  const int bcol = blockIdx.x * 128;
  const int K = 1024;

  f32x4 acc[4][4] = {};

  const int r4 = tid >> 2;
  const int c8 = (tid & 3) * 8;
  const unsigned short* ga = A  + (size_t)(brow + r4) * K + c8;
  const unsigned short* gb = Bt + (size_t)(bcol + r4) * K + c8;
  unsigned short* lAw = sA + wid * 512;
  unsigned short* lBw = sB + wid * 512;

  for (int kb = 0; kb < K; kb += 32) {
    if (kb) __syncthreads();
    __builtin_amdgcn_global_load_lds(AS1C(ga + kb),          AS3(lAw),        16, 0, 0);
    __builtin_amdgcn_global_load_lds(AS1C(ga + 64 * K + kb), AS3(lAw + 2048), 16, 0, 0);
    __builtin_amdgcn_global_load_lds(AS1C(gb + kb),          AS3(lBw),        16, 0, 0);
    __builtin_amdgcn_global_load_lds(AS1C(gb + 64 * K + kb), AS3(lBw + 2048), 16, 0, 0);
    __syncthreads();

    bf16x8 af[4], bfr[4];
#pragma unroll
    for (int mi = 0; mi < 4; ++mi)
      af[mi] = *(const bf16x8*)&sA[(wr * 64 + mi * 16 + (lane & 15)) * 32 + (lane >> 4) * 8];
#pragma unroll
    for (int ni = 0; ni < 4; ++ni)
      bfr[ni] = *(const bf16x8*)&sB[(wc * 64 + ni * 16 + (lane & 15)) * 32 + (lane >> 4) * 8];
#pragma unroll
    for (int mi = 0; mi < 4; ++mi)
#pragma unroll
      for (int ni = 0; ni < 4; ++ni)
        acc[mi][ni] = __builtin_amdgcn_mfma_f32_16x16x32_bf16(af[mi], bfr[ni], acc[mi][ni], 0, 0, 0);
  }

#pragma unroll
  for (int mi = 0; mi < 4; ++mi) {
    int row0 = brow + wr * 64 + mi * 16 + (lane >> 4) * 4;
#pragma unroll
    for (int ni = 0; ni < 4; ++ni) {
      int col = bcol + wc * 64 + ni * 16 + (lane & 15);
#pragma unroll
      for (int j = 0; j < 4; ++j)
        out[(size_t)(row0 + j) * 1024 + col] = acc[mi][ni][j];
    }
  }
}

// ---------------------------------------------------------------------------
// Flash attention (R5 structure, proven): swapped QK^T + defer-max +
// exp2-folded softmax + LDS-staged K/V with register prefetch (latency hiding)
// + fast P-pack (pack2bf). grid 1024 blocks, XCD-relabeled (8 bh per XCD).
// Q,K: [64][2048][64] bf16 (Q pre-scaled by 0.125*log2e).  Vt: [64][64][2048].
// O: [4][2048][1024] bf16.
// mfma(K,Q) -> C col = q = lane&15, row = key = (lane>>4)*4+reg.
// ---------------------------------------------------------------------------
__global__ __launch_bounds__(256) void attn_kernel(
    const unsigned short* __restrict__ Q,
    const unsigned short* __restrict__ K,
    const unsigned short* __restrict__ Vt,
    unsigned short* __restrict__ O) {
  __shared__ __align__(16) unsigned short sK[64 * 72];     // [key][dk] pad 72
  __shared__ __align__(16) unsigned short sVt[64 * 72];    // [dk][key] pad 72
  __shared__ __align__(16) unsigned short sP[8][16 * 72];  // [w*2+mi][q][key] pad 72

  const int tid = threadIdx.x, lane = tid & 63, w = tid >> 6;
  const int l15 = lane & 15, hi = lane >> 4;
  // bijective XCD relabel: dispatch n -> xcd = n&7; 8 bh per XCD, 16 q-blocks each
  const int n = blockIdx.x + (blockIdx.y << 4);
  const int bh = (n & 7) * 8 + ((n >> 3) >> 4);
  const int qx = (n >> 3) & 15;
  const int qb = qx * 128;
  const unsigned short* Qp  = Q  + (size_t)bh * 131072;
  const unsigned short* Kp  = K  + (size_t)bh * 131072;
  const unsigned short* Vtp = Vt + (size_t)bh * 131072;

  bf16x8 qf[2][2];
#pragma unroll
  for (int mi = 0; mi < 2; ++mi) {
    int qrow = qb + w * 32 + mi * 16 + l15;
    qf[mi][0] = *(const bf16x8*)&Qp[(size_t)qrow * 64 + hi * 8];
    qf[mi][1] = *(const bf16x8*)&Qp[(size_t)qrow * 64 + 32 + hi * 8];
  }

  f32x4 o[2][4] = {};
  float m_[2] = { 0.f, 0.f };      // defer-max: start at 0 (scores log2-scaled)
  float l_[2] = { 0.f, 0.f };

  const int sr  = tid >> 3;        // 0..31
  const int sc8 = (tid & 7) * 8;

  // staging pointers (strength-reduced; tile strides 4096 / 64)
  const unsigned short* kptr = Kp  + (size_t)sr * 64 + sc8;
  const unsigned short* vptr = Vtp + (size_t)sr * 2048 + sc8;

  // prologue: tile 0 into regs (async-stage: issue early, write late)
  bf16x8 rk0 = *(const bf16x8*)kptr;
  bf16x8 rk1 = *(const bf16x8*)(kptr + 2048);
  bf16x8 rv0 = *(const bf16x8*)vptr;
  bf16x8 rv1 = *(const bf16x8*)(vptr + 65536);

  for (int kt = 0; kt < 32; ++kt) {
    __syncthreads();               // previous tile's compute done
    *(bf16x8*)&sK[sr * 72 + sc8]         = rk0;
    *(bf16x8*)&sK[(sr + 32) * 72 + sc8]  = rk1;
    *(bf16x8*)&sVt[sr * 72 + sc8]        = rv0;
    *(bf16x8*)&sVt[(sr + 32) * 72 + sc8] = rv1;
    __syncthreads();               // LDS ready

    if (kt < 31) {                 // issue next tile's loads; land next iter
      kptr += 4096; vptr += 64;
      rk0 = *(const bf16x8*)kptr;
      rk1 = *(const bf16x8*)(kptr + 2048);
      rv0 = *(const bf16x8*)vptr;
      rv1 = *(const bf16x8*)(vptr + 65536);
    }

#pragma unroll
    for (int mi = 0; mi < 2; ++mi) {
      // S^T = K Q^T : sc[ni][r] = S[key=16ni+4hi+r][q=l15]  (log2-units)
      f32x4 sc[4] = {};
      __builtin_amdgcn_s_setprio(1);
#pragma unroll
      for (int ni = 0; ni < 4; ++ni) {
        bf16x8 kf0 = *(const bf16x8*)&sK[(ni * 16 + l15) * 72 + hi * 8];
        bf16x8 kf1 = *(const bf16x8*)&sK[(ni * 16 + l15) * 72 + 32 + hi * 8];
        sc[ni] = __builtin_amdgcn_mfma_f32_16x16x32_bf16(kf0, qf[mi][0], sc[ni], 0, 0, 0);
        sc[ni] = __builtin_amdgcn_mfma_f32_16x16x32_bf16(kf1, qf[mi][1], sc[ni], 0, 0, 0);
      }
      __builtin_amdgcn_s_setprio(0);

      // per-q (= lane) tile max, for the defer-max guard
      float mx0 = fmaxf(fmaxf(sc[0][0], sc[0][1]), fmaxf(sc[0][2], sc[0][3]));
      float mx1 = fmaxf(fmaxf(sc[1][0], sc[1][1]), fmaxf(sc[1][2], sc[1][3]));
      float mx2 = fmaxf(fmaxf(sc[2][0], sc[2][1]), fmaxf(sc[2][2], sc[2][3]));
      float mx3 = fmaxf(fmaxf(sc[3][0], sc[3][1]), fmaxf(sc[3][2], sc[3][3]));
      float pmax = fmaxf(fmaxf(mx0, mx1), fmaxf(mx2, mx3));
      pmax = fmaxf(pmax, __shfl_xor(pmax, 16));
      pmax = fmaxf(pmax, __shfl_xor(pmax, 32));

      // T13: rescale only if P would exceed 2^8 (never fires on sane data)
      if (!__all(pmax - m_[mi] <= 8.0f)) {
        float mnew  = fmaxf(m_[mi], pmax);
        float alpha = EXP2(m_[mi] - mnew);
        l_[mi] *= alpha;
#pragma unroll
        for (int j = 0; j < 4; ++j) {
          float aj = __shfl(alpha, hi * 4 + j);
#pragma unroll
          for (int ni = 0; ni < 4; ++ni) o[mi][ni][j] *= aj;
        }
        m_[mi] = mnew;
      }

      const float mcur = m_[mi];
      f32x4 sum4 = {};
#pragma unroll
      for (int ni = 0; ni < 4; ++ni)
#pragma unroll
        for (int r = 0; r < 4; ++r) {
          float p = EXP2(sc[ni][r] - mcur);
          sc[ni][r] = p;
          sum4[r] += p;
        }
      float rsum = (sum4[0] + sum4[1]) + (sum4[2] + sum4[3]);
      rsum += __shfl_xor(rsum, 16);
      rsum += __shfl_xor(rsum, 32);
      l_[mi] += rsum;

      // P -> per-wave LDS [q=l15][key]; fast pack2bf (2 f32 -> 1 u32)
      unsigned short* pb = &sP[w * 2 + mi][l15 * 72];
#pragma unroll
      for (int ni = 0; ni < 4; ++ni) {
        uint2 pk = { pack2bf(sc[ni][0], sc[ni][1]), pack2bf(sc[ni][2], sc[ni][3]) };
        *(uint2*)&pb[ni * 16 + hi * 4] = pk;
      }
    }

    // O += P V
    bf16x8 pa[2][2];
#pragma unroll
    for (int mi = 0; mi < 2; ++mi) {
      pa[mi][0] = *(const bf16x8*)&sP[w * 2 + mi][l15 * 72 + hi * 8];
      pa[mi][1] = *(const bf16x8*)&sP[w * 2 + mi][l15 * 72 + 32 + hi * 8];
    }
    __builtin_amdgcn_s_setprio(1);
#pragma unroll
    for (int ni = 0; ni < 4; ++ni) {
      bf16x8 vf0 = *(const bf16x8*)&sVt[(ni * 16 + l15) * 72 + hi * 8];
      bf16x8 vf1 = *(const bf16x8*)&sVt[(ni * 16 + l15) * 72 + 32 + hi * 8];
#pragma unroll
      for (int mi = 0; mi < 2; ++mi) {
        o[mi][ni] = __builtin_amdgcn_mfma_f32_16x16x32_bf16(pa[mi][0], vf0, o[mi][ni], 0, 0, 0);
        o[mi][ni] = __builtin_amdgcn_mfma_f32_16x16x32_bf16(pa[mi][1], vf1, o[mi][ni], 0, 0, 0);
      }
    }
    __builtin_amdgcn_s_setprio(0);
  }

  const int b = bh >> 4, h = bh & 15;
#pragma unroll
  for (int mi = 0; mi < 2; ++mi) {
    float linv = 1.0f / l_[mi];
#pragma unroll
    for (int j = 0; j < 4; ++j) {
      float inv = __shfl(linv, hi * 4 + j);
      int row = qb + w * 32 + mi * 16 + hi * 4 + j;
#pragma unroll
      for (int ni = 0; ni < 4; ++ni)
        O[((size_t)b * 2048 + row) * 1024 + h * 64 + ni * 16 + l15] = f2b(o[mi][ni][j] * inv);
    }
  }
}

// ---------------------------------------------------------------------------
extern "C" void kernel_launch(void* const* d_in, const int* in_sizes, int n_in,
                              void* d_out, int out_size, void* d_ws, size_t ws_size,
                              hipStream_t stream) {
  const float* x  = (const float*)d_in[0];
  const float* Wq = (const float*)d_in[1];
  const float* Wk = (const float*)d_in[2];
  const float* Wv = (const float*)d_in[3];
  const float* Wo = (const float*)d_in[4];
  float* out = (float*)d_out;

  char* w = (char*)d_ws;
  unsigned short* xb   = (unsigned short*)(w);                       // 16 MB
  unsigned short* wqkv = (unsigned short*)(w + 16777216);            //  6 MB
  unsigned short* wo   = (unsigned short*)(w + 23068672);            //  2 MB
  unsigned short* Qb   = (unsigned short*)(w + 25165824);            // 16 MB
  unsigned short* Kb   = (unsigned short*)(w + 41943040);            // 16 MB
  unsigned short* Vtb  = (unsigned short*)(w + 58720256);            // 16 MB (V transposed)
  unsigned short* Ob   = (unsigned short*)(w + 75497472);            // 16 MB

  conv_x_kernel<<<8192, 256, 0, stream>>>(x, xb, 2097152);
  conv_wqkv_kernel<<<768, 256, 0, stream>>>(Wq, Wk, Wv, wqkv);
  conv_wo_kernel<<<256, 256, 0, stream>>>(Wo, wo);
  gemm_qkv_kernel<<<dim3(24, 64), 256, 0, stream>>>(xb, wqkv, Qb, Kb, Vtb);
  attn_kernel<<<dim3(16, 64), 256, 0, stream>>>(Qb, Kb, Vtb, Ob);
  gemm_out_kernel<<<dim3(8, 64), 256, 0, stream>>>(Ob, wo, out);
}

// Round 8
// 215.953 us; speedup vs baseline: 1.7404x; 1.0873x over previous
//
#include <hip/hip_runtime.h>
#include <hip/hip_bf16.h>
#include <stdint.h>

typedef __attribute__((ext_vector_type(8))) short bf16x8;
typedef __attribute__((ext_vector_type(4))) float f32x4;
typedef __attribute__((ext_vector_type(4))) unsigned short us4;

#define AS1C(p) ((const __attribute__((address_space(1))) void*)(p))
#define AS3(p)  ((__attribute__((address_space(3))) void*)(p))

// raw v_exp_f32 (2^x). exp2f (libm) lowers to OCML with denormal fixup — slow.
#if __has_builtin(__builtin_amdgcn_exp2f)
#define EXP2(x) __builtin_amdgcn_exp2f(x)
#else
#define EXP2(x) __expf((x) * 0.69314718f)
#endif

static __device__ __forceinline__ unsigned short f2b(float f) {
  union { __hip_bfloat16 h; unsigned short u; } cv;
  cv.h = __float2bfloat16(f);
  return cv.u;
}

// ---------------------------------------------------------------------------
// Conversions
// ---------------------------------------------------------------------------
__global__ __launch_bounds__(256) void conv_x_kernel(const float* __restrict__ x,
                                                     unsigned short* __restrict__ xb,
                                                     int n4) {
  int i = blockIdx.x * 256 + threadIdx.x;
  if (i >= n4) return;
  float4 v = ((const float4*)x)[i];
  us4 r = { f2b(v.x), f2b(v.y), f2b(v.z), f2b(v.w) };
  *(us4*)&xb[(size_t)i * 4] = r;
}

// WqkvT[n][d] = W_{which}[h][d][c],  n = which*1024 + h*64 + c
__global__ __launch_bounds__(256) void conv_wqkv_kernel(const float* __restrict__ Wq,
                                                        const float* __restrict__ Wk,
                                                        const float* __restrict__ Wv,
                                                        unsigned short* __restrict__ WqkvT) {
  int bid = blockIdx.x;          // 3*16*16 = 768 blocks
  int which = bid >> 8;
  int h  = (bid >> 4) & 15;
  int dt = bid & 15;
  const float* W = (which == 0) ? Wq : (which == 1 ? Wk : Wv);
  __shared__ float tile[64][65];
  const int t = threadIdx.x;
  const int c  = t & 63;
  const int r0 = t >> 6;         // 0..3
  const float* src = W + (size_t)h * 65536 + (size_t)dt * 64 * 64;
#pragma unroll
  for (int it = 0; it < 16; ++it) {
    int r = r0 + it * 4;
    tile[r][c] = src[r * 64 + c];     // tile[d_local][c_local]
  }
  __syncthreads();
  const size_t n0 = (size_t)which * 1024 + h * 64;
  const int d0 = dt * 64;
#pragma unroll
  for (int it = 0; it < 16; ++it) {
    int cc = r0 + it * 4;             // c_local (output row)
    WqkvT[(n0 + cc) * 1024 + d0 + c] = f2b(tile[c][cc]);
  }
}

// WoT[n][k] = Wo[k][n]
__global__ __launch_bounds__(256) void conv_wo_kernel(const float* __restrict__ Wo,
                                                      unsigned short* __restrict__ WoT) {
  int kt = blockIdx.x >> 4, nt = blockIdx.x & 15;   // 256 blocks
  __shared__ float tile[64][65];
  const int t = threadIdx.x;
  const int c  = t & 63;
  const int r0 = t >> 6;
  const float* src = Wo + (size_t)(kt * 64) * 1024 + nt * 64;
#pragma unroll
  for (int it = 0; it < 16; ++it) {
    int r = r0 + it * 4;
    tile[r][c] = src[(size_t)r * 1024 + c];   // tile[k_local][n_local]
  }
  __syncthreads();
#pragma unroll
  for (int it = 0; it < 16; ++it) {
    int cc = r0 + it * 4;                     // n_local (output row)
    WoT[((size_t)nt * 64 + cc) * 1024 + kt * 64 + c] = f2b(tile[c][cc]);
  }
}

// ---------------------------------------------------------------------------
// GEMM 1: C[8192][3072] = x_bf16 [8192][1024] * WqkvT[3072][1024]^T
// epilogue: Q pre-scaled by (1/8)*log2(e) (exp2-folded softmax); K straight;
// V written TRANSPOSED into Vt[B*H][dk][S] (us4 packed stores, j spans s).
// ---------------------------------------------------------------------------
__global__ __launch_bounds__(256) void gemm_qkv_kernel(
    const unsigned short* __restrict__ A,
    const unsigned short* __restrict__ Bt,
    unsigned short* __restrict__ Q,
    unsigned short* __restrict__ Ko,
    unsigned short* __restrict__ Vt) {
  __shared__ __align__(16) unsigned short sA[128 * 32];
  __shared__ __align__(16) unsigned short sB[128 * 32];
  const int tid  = threadIdx.x;
  const int lane = tid & 63;
  const int wid  = tid >> 6;
  const int wr = wid >> 1, wc = wid & 1;
  const int brow = blockIdx.y * 128;
  const int bcol = blockIdx.x * 128;
  const int K = 1024;

  f32x4 acc[4][4] = {};

  const int r4 = tid >> 2;          // 0..63
  const int c8 = (tid & 3) * 8;
  const unsigned short* ga = A  + (size_t)(brow + r4) * K + c8;
  const unsigned short* gb = Bt + (size_t)(bcol + r4) * K + c8;
  unsigned short* lAw = sA + wid * 512;   // wave-uniform LDS base (lane*16B added by HW)
  unsigned short* lBw = sB + wid * 512;

  for (int kb = 0; kb < K; kb += 32) {
    if (kb) __syncthreads();
    __builtin_amdgcn_global_load_lds(AS1C(ga + kb),            AS3(lAw),        16, 0, 0);
    __builtin_amdgcn_global_load_lds(AS1C(ga + 64 * K + kb),   AS3(lAw + 2048), 16, 0, 0);
    __builtin_amdgcn_global_load_lds(AS1C(gb + kb),            AS3(lBw),        16, 0, 0);
    __builtin_amdgcn_global_load_lds(AS1C(gb + 64 * K + kb),   AS3(lBw + 2048), 16, 0, 0);
    __syncthreads();

    bf16x8 af[4], bfr[4];
#pragma unroll
    for (int mi = 0; mi < 4; ++mi)
      af[mi] = *(const bf16x8*)&sA[(wr * 64 + mi * 16 + (lane & 15)) * 32 + (lane >> 4) * 8];
#pragma unroll
    for (int ni = 0; ni < 4; ++ni)
      bfr[ni] = *(const bf16x8*)&sB[(wc * 64 + ni * 16 + (lane & 15)) * 32 + (lane >> 4) * 8];
#pragma unroll
    for (int mi = 0; mi < 4; ++mi)
#pragma unroll
      for (int ni = 0; ni < 4; ++ni)
        acc[mi][ni] = __builtin_amdgcn_mfma_f32_16x16x32_bf16(af[mi], bfr[ni], acc[mi][ni], 0, 0, 0);
  }

#pragma unroll
  for (int mi = 0; mi < 4; ++mi) {
    int row0 = brow + wr * 64 + mi * 16 + (lane >> 4) * 4;
    int b = row0 >> 11, s0 = row0 & 2047;
#pragma unroll
    for (int ni = 0; ni < 4; ++ni) {
      int col = bcol + wc * 64 + ni * 16 + (lane & 15);
      int which = col >> 10;      // block-uniform
      int h  = (col >> 6) & 15;
      int kk = col & 63;
      if (which == 2) {
        us4 pk = { f2b(acc[mi][ni][0]), f2b(acc[mi][ni][1]),
                   f2b(acc[mi][ni][2]), f2b(acc[mi][ni][3]) };
        *(us4*)&Vt[((size_t)(b * 16 + h) * 64 + kk) * 2048 + s0] = pk;
      } else {
        unsigned short* dst = (which == 0) ? Q : Ko;
        // Q: fold 1/sqrt(dk) * log2(e) so softmax uses raw v_exp (2^x)
        float scl = (which == 0) ? 0.18033688f : 1.0f;
#pragma unroll
        for (int j = 0; j < 4; ++j)
          dst[((size_t)(b * 16 + h) * 2048 + (s0 + j)) * 64 + kk] = f2b(acc[mi][ni][j] * scl);
      }
    }
  }
}

// ---------------------------------------------------------------------------
// GEMM 2: out[8192][1024] (fp32) = O_bf16 [8192][1024] * WoT[1024][1024]^T
// ---------------------------------------------------------------------------
__global__ __launch_bounds__(256) void gemm_out_kernel(
    const unsigned short* __restrict__ A,
    const unsigned short* __restrict__ Bt,
    float* __restrict__ out) {
  __shared__ __align__(16) unsigned short sA[128 * 32];
  __shared__ __align__(16) unsigned short sB[128 * 32];
  const int tid  = threadIdx.x;
  const int lane = tid & 63;
  const int wid  = tid >> 6;
  const int wr = wid >> 1, wc = wid & 1;
  const int brow = blockIdx.y * 128;
  const int bcol = blockIdx.x * 128;
  const int K = 1024;

  f32x4 acc[4][4] = {};

  const int r4 = tid >> 2;
  const int c8 = (tid & 3) * 8;
  const unsigned short* ga = A  + (size_t)(brow + r4) * K + c8;
  const unsigned short* gb = Bt + (size_t)(bcol + r4) * K + c8;
  unsigned short* lAw = sA + wid * 512;
  unsigned short* lBw = sB + wid * 512;

  for (int kb = 0; kb < K; kb += 32) {
    if (kb) __syncthreads();
    __builtin_amdgcn_global_load_lds(AS1C(ga + kb),          AS3(lAw),        16, 0, 0);
    __builtin_amdgcn_global_load_lds(AS1C(ga + 64 * K + kb), AS3(lAw + 2048), 16, 0, 0);
    __builtin_amdgcn_global_load_lds(AS1C(gb + kb),          AS3(lBw),        16, 0, 0);
    __builtin_amdgcn_global_load_lds(AS1C(gb + 64 * K + kb), AS3(lBw + 2048), 16, 0, 0);
    __syncthreads();

    bf16x8 af[4], bfr[4];
#pragma unroll
    for (int mi = 0; mi < 4; ++mi)
      af[mi] = *(const bf16x8*)&sA[(wr * 64 + mi * 16 + (lane & 15)) * 32 + (lane >> 4) * 8];
#pragma unroll
    for (int ni = 0; ni < 4; ++ni)
      bfr[ni] = *(const bf16x8*)&sB[(wc * 64 + ni * 16 + (lane & 15)) * 32 + (lane >> 4) * 8];
#pragma unroll
    for (int mi = 0; mi < 4; ++mi)
#pragma unroll
      for (int ni = 0; ni < 4; ++ni)
        acc[mi][ni] = __builtin_amdgcn_mfma_f32_16x16x32_bf16(af[mi], bfr[ni], acc[mi][ni], 0, 0, 0);
  }

#pragma unroll
  for (int mi = 0; mi < 4; ++mi) {
    int row0 = brow + wr * 64 + mi * 16 + (lane >> 4) * 4;
#pragma unroll
    for (int ni = 0; ni < 4; ++ni) {
      int col = bcol + wc * 64 + ni * 16 + (lane & 15);
#pragma unroll
      for (int j = 0; j < 4; ++j)
        out[(size_t)(row0 + j) * 1024 + col] = acc[mi][ni][j];
    }
  }
}

// ---------------------------------------------------------------------------
// Flash attention: 512-thread / 8-wave blocks, each wave owns 16 q-rows.
// Same 1024-block grid (XCD-relabeled), LDS unchanged -> 8 waves/block raises
// resident waves/CU from 16 to 24-32 (TLP hides LDS/MFMA latency).
// Swapped QK^T + defer-max (guard via per-wave __all, shuffles only in the
// rare rescale branch) + deferred l cross-lane reduction (epilogue only).
// Q,K: [64][2048][64] bf16 (Q pre-scaled by 0.125*log2e).  Vt: [64][64][2048].
// O: [4][2048][1024] bf16.
// mfma(K,Q) -> C col = q = lane&15, row = key = (lane>>4)*4+reg.
// ---------------------------------------------------------------------------
__global__ __launch_bounds__(512) void attn_kernel(
    const unsigned short* __restrict__ Q,
    const unsigned short* __restrict__ K,
    const unsigned short* __restrict__ Vt,
    unsigned short* __restrict__ O) {
  __shared__ __align__(16) unsigned short sK[64 * 72];     // [key][dk] pad 72
  __shared__ __align__(16) unsigned short sVt[64 * 72];    // [dk][key] pad 72
  __shared__ __align__(16) unsigned short sP[8][16 * 72];  // [wave][q][key] pad 72

  const int tid = threadIdx.x, lane = tid & 63, w = tid >> 6;   // w = 0..7
  const int l15 = lane & 15, hi = lane >> 4;
  // bijective XCD relabel: dispatch n -> xcd = n&7; 8 bh per XCD, 16 q-blocks each
  const int n = blockIdx.x + (blockIdx.y << 4);
  const int bh = (n & 7) * 8 + ((n >> 3) >> 4);
  const int qx = (n >> 3) & 15;
  const int qb = qx * 128;
  const unsigned short* Qp  = Q  + (size_t)bh * 131072;
  const unsigned short* Kp  = K  + (size_t)bh * 131072;
  const unsigned short* Vtp = Vt + (size_t)bh * 131072;

  // per-wave 16 q-rows
  const int qrow = qb + w * 16 + l15;
  bf16x8 qf0 = *(const bf16x8*)&Qp[(size_t)qrow * 64 + hi * 8];
  bf16x8 qf1 = *(const bf16x8*)&Qp[(size_t)qrow * 64 + 32 + hi * 8];

  f32x4 o[4] = {};
  float m_ = 0.f;                  // defer-max: start at 0 (scores log2-scaled)
  float l_ = 0.f;                  // per-lane partial; cross-lane reduce at end

  // staging: 512 threads, one 16B K-chunk + one 16B Vt-chunk each
  const int sr  = tid >> 3;        // 0..63
  const int sc8 = (tid & 7) * 8;
  const unsigned short* kptr = Kp  + (size_t)sr * 64 + sc8;
  const unsigned short* vptr = Vtp + (size_t)sr * 2048 + sc8;

  // prologue: tile 0 into regs (async-stage: issue early, write late)
  bf16x8 rk = *(const bf16x8*)kptr;
  bf16x8 rv = *(const bf16x8*)vptr;

  for (int kt = 0; kt < 32; ++kt) {
    __syncthreads();               // previous tile's compute done
    *(bf16x8*)&sK[sr * 72 + sc8]  = rk;
    *(bf16x8*)&sVt[sr * 72 + sc8] = rv;
    __syncthreads();               // LDS ready

    if (kt < 31) {                 // issue next tile's loads; land next iter
      kptr += 4096; vptr += 64;
      rk = *(const bf16x8*)kptr;
      rv = *(const bf16x8*)vptr;
    }

    // S^T = K Q^T : sc[ni][r] = S[key=16ni+4hi+r][q=l15]  (log2-units)
    f32x4 sc[4] = {};
    __builtin_amdgcn_s_setprio(1);
#pragma unroll
    for (int ni = 0; ni < 4; ++ni) {
      bf16x8 kf0 = *(const bf16x8*)&sK[(ni * 16 + l15) * 72 + hi * 8];
      bf16x8 kf1 = *(const bf16x8*)&sK[(ni * 16 + l15) * 72 + 32 + hi * 8];
      sc[ni] = __builtin_amdgcn_mfma_f32_16x16x32_bf16(kf0, qf0, sc[ni], 0, 0, 0);
      sc[ni] = __builtin_amdgcn_mfma_f32_16x16x32_bf16(kf1, qf1, sc[ni], 0, 0, 0);
    }
    __builtin_amdgcn_s_setprio(0);

    // per-lane tile max (guard only; no cross-lane shuffles on the fast path)
    float mx0 = fmaxf(fmaxf(sc[0][0], sc[0][1]), fmaxf(sc[0][2], sc[0][3]));
    float mx1 = fmaxf(fmaxf(sc[1][0], sc[1][1]), fmaxf(sc[1][2], sc[1][3]));
    float mx2 = fmaxf(fmaxf(sc[2][0], sc[2][1]), fmaxf(sc[2][2], sc[2][3]));
    float mx3 = fmaxf(fmaxf(sc[3][0], sc[3][1]), fmaxf(sc[3][2], sc[3][3]));
    float pmax = fmaxf(fmaxf(mx0, mx1), fmaxf(mx2, mx3));

    // T13: rescale only if P would exceed 2^8 (never fires on sane data)
    if (!__all(pmax - m_ <= 8.0f)) {
      pmax = fmaxf(pmax, __shfl_xor(pmax, 16));     // row-uniform max
      pmax = fmaxf(pmax, __shfl_xor(pmax, 32));
      float mnew  = fmaxf(m_, pmax);
      float alpha = EXP2(m_ - mnew);
      l_ *= alpha;
#pragma unroll
      for (int j = 0; j < 4; ++j) {
        float aj = __shfl(alpha, hi * 4 + j);
#pragma unroll
        for (int ni = 0; ni < 4; ++ni) o[ni][j] *= aj;
      }
      m_ = mnew;
    }

    const float mcur = m_;
    f32x4 sum4 = {};
#pragma unroll
    for (int ni = 0; ni < 4; ++ni)
#pragma unroll
      for (int r = 0; r < 4; ++r) {
        float p = EXP2(sc[ni][r] - mcur);
        sc[ni][r] = p;
        sum4[r] += p;
      }
    l_ += (sum4[0] + sum4[1]) + (sum4[2] + sum4[3]);   // per-lane partial

    // P -> per-wave LDS [q=l15][key], packed us4 (4 consecutive keys)
    unsigned short* pb = &sP[w][l15 * 72];
#pragma unroll
    for (int ni = 0; ni < 4; ++ni) {
      us4 pk = { f2b(sc[ni][0]), f2b(sc[ni][1]), f2b(sc[ni][2]), f2b(sc[ni][3]) };
      *(us4*)&pb[ni * 16 + hi * 4] = pk;
    }

    // O += P V
    bf16x8 pa0 = *(const bf16x8*)&sP[w][l15 * 72 + hi * 8];
    bf16x8 pa1 = *(const bf16x8*)&sP[w][l15 * 72 + 32 + hi * 8];
    __builtin_amdgcn_s_setprio(1);
#pragma unroll
    for (int ni = 0; ni < 4; ++ni) {
      bf16x8 vf0 = *(const bf16x8*)&sVt[(ni * 16 + l15) * 72 + hi * 8];
      bf16x8 vf1 = *(const bf16x8*)&sVt[(ni * 16 + l15) * 72 + 32 + hi * 8];
      o[ni] = __builtin_amdgcn_mfma_f32_16x16x32_bf16(pa0, vf0, o[ni], 0, 0, 0);
      o[ni] = __builtin_amdgcn_mfma_f32_16x16x32_bf16(pa1, vf1, o[ni], 0, 0, 0);
    }
    __builtin_amdgcn_s_setprio(0);
  }

  // final l reduction (deferred): sum partials across hi groups of the row
  l_ += __shfl_xor(l_, 16);
  l_ += __shfl_xor(l_, 32);
  float linv = 1.0f / l_;

  const int b = bh >> 4, h = bh & 15;
#pragma unroll
  for (int j = 0; j < 4; ++j) {
    float inv = __shfl(linv, hi * 4 + j);
    int row = qb + w * 16 + hi * 4 + j;
#pragma unroll
    for (int ni = 0; ni < 4; ++ni)
      O[((size_t)b * 2048 + row) * 1024 + h * 64 + ni * 16 + l15] = f2b(o[ni][j] * inv);
  }
}

// ---------------------------------------------------------------------------
extern "C" void kernel_launch(void* const* d_in, const int* in_sizes, int n_in,
                              void* d_out, int out_size, void* d_ws, size_t ws_size,
                              hipStream_t stream) {
  const float* x  = (const float*)d_in[0];
  const float* Wq = (const float*)d_in[1];
  const float* Wk = (const float*)d_in[2];
  const float* Wv = (const float*)d_in[3];
  const float* Wo = (const float*)d_in[4];
  float* out = (float*)d_out;

  char* w = (char*)d_ws;
  unsigned short* xb   = (unsigned short*)(w);                       // 16 MB
  unsigned short* wqkv = (unsigned short*)(w + 16777216);            //  6 MB
  unsigned short* wo   = (unsigned short*)(w + 23068672);            //  2 MB
  unsigned short* Qb   = (unsigned short*)(w + 25165824);            // 16 MB
  unsigned short* Kb   = (unsigned short*)(w + 41943040);            // 16 MB
  unsigned short* Vtb  = (unsigned short*)(w + 58720256);            // 16 MB (V transposed)
  unsigned short* Ob   = (unsigned short*)(w + 75497472);            // 16 MB

  conv_x_kernel<<<8192, 256, 0, stream>>>(x, xb, 2097152);
  conv_wqkv_kernel<<<768, 256, 0, stream>>>(Wq, Wk, Wv, wqkv);
  conv_wo_kernel<<<256, 256, 0, stream>>>(Wo, wo);
  gemm_qkv_kernel<<<dim3(24, 64), 256, 0, stream>>>(xb, wqkv, Qb, Kb, Vtb);
  attn_kernel<<<dim3(16, 64), 512, 0, stream>>>(Qb, Kb, Vtb, Ob);
  gemm_out_kernel<<<dim3(8, 64), 256, 0, stream>>>(Ob, wo, out);
}

// Round 9
// 210.826 us; speedup vs baseline: 1.7827x; 1.0243x over previous
//
#include <hip/hip_runtime.h>
#include <hip/hip_bf16.h>
#include <stdint.h>

typedef __attribute__((ext_vector_type(8))) short bf16x8;
typedef __attribute__((ext_vector_type(4))) float f32x4;
typedef __attribute__((ext_vector_type(4))) unsigned short us4;

#define AS1C(p) ((const __attribute__((address_space(1))) void*)(p))
#define AS3(p)  ((__attribute__((address_space(3))) void*)(p))

// raw v_exp_f32 (2^x). exp2f (libm) lowers to OCML with denormal fixup — slow.
#if __has_builtin(__builtin_amdgcn_exp2f)
#define EXP2(x) __builtin_amdgcn_exp2f(x)
#else
#define EXP2(x) __expf((x) * 0.69314718f)
#endif

#define MAX3(a,b,c) fmaxf(fmaxf((a),(b)),(c))   // clang fuses to v_max3_f32

static __device__ __forceinline__ unsigned short f2b(float f) {
  union { __hip_bfloat16 h; unsigned short u; } cv;
  cv.h = __float2bfloat16(f);
  return cv.u;
}

// T12 recipe: v_cvt_pk_bf16_f32 has no builtin on gfx950 — inline asm.
// d.lo = bf16(a), d.hi = bf16(b). 1 instruction per 2 values.
static __device__ __forceinline__ unsigned int cvtpk(float a, float b) {
  unsigned int r;
  asm("v_cvt_pk_bf16_f32 %0, %1, %2" : "=v"(r) : "v"(a), "v"(b));
  return r;
}

// ---------------------------------------------------------------------------
// Conversions
// ---------------------------------------------------------------------------
__global__ __launch_bounds__(256) void conv_x_kernel(const float* __restrict__ x,
                                                     unsigned short* __restrict__ xb,
                                                     int n4) {
  int i = blockIdx.x * 256 + threadIdx.x;
  if (i >= n4) return;
  float4 v = ((const float4*)x)[i];
  us4 r = { f2b(v.x), f2b(v.y), f2b(v.z), f2b(v.w) };
  *(us4*)&xb[(size_t)i * 4] = r;
}

// WqkvT[n][d] = W_{which}[h][d][c],  n = which*1024 + h*64 + c
__global__ __launch_bounds__(256) void conv_wqkv_kernel(const float* __restrict__ Wq,
                                                        const float* __restrict__ Wk,
                                                        const float* __restrict__ Wv,
                                                        unsigned short* __restrict__ WqkvT) {
  int bid = blockIdx.x;          // 3*16*16 = 768 blocks
  int which = bid >> 8;
  int h  = (bid >> 4) & 15;
  int dt = bid & 15;
  const float* W = (which == 0) ? Wq : (which == 1 ? Wk : Wv);
  __shared__ float tile[64][65];
  const int t = threadIdx.x;
  const int c  = t & 63;
  const int r0 = t >> 6;         // 0..3
  const float* src = W + (size_t)h * 65536 + (size_t)dt * 64 * 64;
#pragma unroll
  for (int it = 0; it < 16; ++it) {
    int r = r0 + it * 4;
    tile[r][c] = src[r * 64 + c];     // tile[d_local][c_local]
  }
  __syncthreads();
  const size_t n0 = (size_t)which * 1024 + h * 64;
  const int d0 = dt * 64;
#pragma unroll
  for (int it = 0; it < 16; ++it) {
    int cc = r0 + it * 4;             // c_local (output row)
    WqkvT[(n0 + cc) * 1024 + d0 + c] = f2b(tile[c][cc]);
  }
}

// WoT[n][k] = Wo[k][n]
__global__ __launch_bounds__(256) void conv_wo_kernel(const float* __restrict__ Wo,
                                                      unsigned short* __restrict__ WoT) {
  int kt = blockIdx.x >> 4, nt = blockIdx.x & 15;   // 256 blocks
  __shared__ float tile[64][65];
  const int t = threadIdx.x;
  const int c  = t & 63;
  const int r0 = t >> 6;
  const float* src = Wo + (size_t)(kt * 64) * 1024 + nt * 64;
#pragma unroll
  for (int it = 0; it < 16; ++it) {
    int r = r0 + it * 4;
    tile[r][c] = src[(size_t)r * 1024 + c];   // tile[k_local][n_local]
  }
  __syncthreads();
#pragma unroll
  for (int it = 0; it < 16; ++it) {
    int cc = r0 + it * 4;                     // n_local (output row)
    WoT[((size_t)nt * 64 + cc) * 1024 + kt * 64 + c] = f2b(tile[c][cc]);
  }
}

// ---------------------------------------------------------------------------
// GEMM 1: C[8192][3072] = x_bf16 [8192][1024] * WqkvT[3072][1024]^T
// epilogue: Q pre-scaled by (1/8)*log2(e) (exp2-folded softmax); K straight;
// V written TRANSPOSED into Vt[B*H][dk][S] (us4 packed stores, j spans s).
// ---------------------------------------------------------------------------
__global__ __launch_bounds__(256) void gemm_qkv_kernel(
    const unsigned short* __restrict__ A,
    const unsigned short* __restrict__ Bt,
    unsigned short* __restrict__ Q,
    unsigned short* __restrict__ Ko,
    unsigned short* __restrict__ Vt) {
  __shared__ __align__(16) unsigned short sA[128 * 32];
  __shared__ __align__(16) unsigned short sB[128 * 32];
  const int tid  = threadIdx.x;
  const int lane = tid & 63;
  const int wid  = tid >> 6;
  const int wr = wid >> 1, wc = wid & 1;
  const int brow = blockIdx.y * 128;
  const int bcol = blockIdx.x * 128;
  const int K = 1024;

  f32x4 acc[4][4] = {};

  const int r4 = tid >> 2;          // 0..63
  const int c8 = (tid & 3) * 8;
  const unsigned short* ga = A  + (size_t)(brow + r4) * K + c8;
  const unsigned short* gb = Bt + (size_t)(bcol + r4) * K + c8;
  unsigned short* lAw = sA + wid * 512;   // wave-uniform LDS base (lane*16B added by HW)
  unsigned short* lBw = sB + wid * 512;

  for (int kb = 0; kb < K; kb += 32) {
    if (kb) __syncthreads();
    __builtin_amdgcn_global_load_lds(AS1C(ga + kb),            AS3(lAw),        16, 0, 0);
    __builtin_amdgcn_global_load_lds(AS1C(ga + 64 * K + kb),   AS3(lAw + 2048), 16, 0, 0);
    __builtin_amdgcn_global_load_lds(AS1C(gb + kb),            AS3(lBw),        16, 0, 0);
    __builtin_amdgcn_global_load_lds(AS1C(gb + 64 * K + kb),   AS3(lBw + 2048), 16, 0, 0);
    __syncthreads();

    bf16x8 af[4], bfr[4];
#pragma unroll
    for (int mi = 0; mi < 4; ++mi)
      af[mi] = *(const bf16x8*)&sA[(wr * 64 + mi * 16 + (lane & 15)) * 32 + (lane >> 4) * 8];
#pragma unroll
    for (int ni = 0; ni < 4; ++ni)
      bfr[ni] = *(const bf16x8*)&sB[(wc * 64 + ni * 16 + (lane & 15)) * 32 + (lane >> 4) * 8];
#pragma unroll
    for (int mi = 0; mi < 4; ++mi)
#pragma unroll
      for (int ni = 0; ni < 4; ++ni)
        acc[mi][ni] = __builtin_amdgcn_mfma_f32_16x16x32_bf16(af[mi], bfr[ni], acc[mi][ni], 0, 0, 0);
  }

#pragma unroll
  for (int mi = 0; mi < 4; ++mi) {
    int row0 = brow + wr * 64 + mi * 16 + (lane >> 4) * 4;
    int b = row0 >> 11, s0 = row0 & 2047;
#pragma unroll
    for (int ni = 0; ni < 4; ++ni) {
      int col = bcol + wc * 64 + ni * 16 + (lane & 15);
      int which = col >> 10;      // block-uniform
      int h  = (col >> 6) & 15;
      int kk = col & 63;
      if (which == 2) {
        us4 pk = { f2b(acc[mi][ni][0]), f2b(acc[mi][ni][1]),
                   f2b(acc[mi][ni][2]), f2b(acc[mi][ni][3]) };
        *(us4*)&Vt[((size_t)(b * 16 + h) * 64 + kk) * 2048 + s0] = pk;
      } else {
        unsigned short* dst = (which == 0) ? Q : Ko;
        // Q: fold 1/sqrt(dk) * log2(e) so softmax uses raw v_exp (2^x)
        float scl = (which == 0) ? 0.18033688f : 1.0f;
#pragma unroll
        for (int j = 0; j < 4; ++j)
          dst[((size_t)(b * 16 + h) * 2048 + (s0 + j)) * 64 + kk] = f2b(acc[mi][ni][j] * scl);
      }
    }
  }
}

// ---------------------------------------------------------------------------
// GEMM 2: out[8192][1024] (fp32) = O_bf16 [8192][1024] * WoT[1024][1024]^T
// ---------------------------------------------------------------------------
__global__ __launch_bounds__(256) void gemm_out_kernel(
    const unsigned short* __restrict__ A,
    const unsigned short* __restrict__ Bt,
    float* __restrict__ out) {
  __shared__ __align__(16) unsigned short sA[128 * 32];
  __shared__ __align__(16) unsigned short sB[128 * 32];
  const int tid  = threadIdx.x;
  const int lane = tid & 63;
  const int wid  = tid >> 6;
  const int wr = wid >> 1, wc = wid & 1;
  const int brow = blockIdx.y * 128;
  const int bcol = blockIdx.x * 128;
  const int K = 1024;

  f32x4 acc[4][4] = {};

  const int r4 = tid >> 2;
  const int c8 = (tid & 3) * 8;
  const unsigned short* ga = A  + (size_t)(brow + r4) * K + c8;
  const unsigned short* gb = Bt + (size_t)(bcol + r4) * K + c8;
  unsigned short* lAw = sA + wid * 512;
  unsigned short* lBw = sB + wid * 512;

  for (int kb = 0; kb < K; kb += 32) {
    if (kb) __syncthreads();
    __builtin_amdgcn_global_load_lds(AS1C(ga + kb),          AS3(lAw),        16, 0, 0);
    __builtin_amdgcn_global_load_lds(AS1C(ga + 64 * K + kb), AS3(lAw + 2048), 16, 0, 0);
    __builtin_amdgcn_global_load_lds(AS1C(gb + kb),          AS3(lBw),        16, 0, 0);
    __builtin_amdgcn_global_load_lds(AS1C(gb + 64 * K + kb), AS3(lBw + 2048), 16, 0, 0);
    __syncthreads();

    bf16x8 af[4], bfr[4];
#pragma unroll
    for (int mi = 0; mi < 4; ++mi)
      af[mi] = *(const bf16x8*)&sA[(wr * 64 + mi * 16 + (lane & 15)) * 32 + (lane >> 4) * 8];
#pragma unroll
    for (int ni = 0; ni < 4; ++ni)
      bfr[ni] = *(const bf16x8*)&sB[(wc * 64 + ni * 16 + (lane & 15)) * 32 + (lane >> 4) * 8];
#pragma unroll
    for (int mi = 0; mi < 4; ++mi)
#pragma unroll
      for (int ni = 0; ni < 4; ++ni)
        acc[mi][ni] = __builtin_amdgcn_mfma_f32_16x16x32_bf16(af[mi], bfr[ni], acc[mi][ni], 0, 0, 0);
  }

#pragma unroll
  for (int mi = 0; mi < 4; ++mi) {
    int row0 = brow + wr * 64 + mi * 16 + (lane >> 4) * 4;
#pragma unroll
    for (int ni = 0; ni < 4; ++ni) {
      int col = bcol + wc * 64 + ni * 16 + (lane & 15);
#pragma unroll
      for (int j = 0; j < 4; ++j)
        out[(size_t)(row0 + j) * 1024 + col] = acc[mi][ni][j];
    }
  }
}

// ---------------------------------------------------------------------------
// Flash attention: 512-thread / 8-wave blocks, each wave owns 16 q-rows.
// Swapped QK^T + defer-max + exp2-folded softmax + LDS-staged K/V with
// register prefetch. P-pack via inline-asm v_cvt_pk_bf16_f32 (T12 recipe) +
// v_max3 tile-max (T17). grid 1024 blocks, XCD-relabeled (8 bh per XCD).
// Q,K: [64][2048][64] bf16 (Q pre-scaled by 0.125*log2e).  Vt: [64][64][2048].
// O: [4][2048][1024] bf16.
// mfma(K,Q) -> C col = q = lane&15, row = key = (lane>>4)*4+reg.
// ---------------------------------------------------------------------------
__global__ __launch_bounds__(512) void attn_kernel(
    const unsigned short* __restrict__ Q,
    const unsigned short* __restrict__ K,
    const unsigned short* __restrict__ Vt,
    unsigned short* __restrict__ O) {
  __shared__ __align__(16) unsigned short sK[64 * 72];     // [key][dk] pad 72
  __shared__ __align__(16) unsigned short sVt[64 * 72];    // [dk][key] pad 72
  __shared__ __align__(16) unsigned short sP[8][16 * 72];  // [wave][q][key] pad 72

  const int tid = threadIdx.x, lane = tid & 63, w = tid >> 6;   // w = 0..7
  const int l15 = lane & 15, hi = lane >> 4;
  // bijective XCD relabel: dispatch n -> xcd = n&7; 8 bh per XCD, 16 q-blocks each
  const int n = blockIdx.x + (blockIdx.y << 4);
  const int bh = (n & 7) * 8 + ((n >> 3) >> 4);
  const int qx = (n >> 3) & 15;
  const int qb = qx * 128;
  const unsigned short* Qp  = Q  + (size_t)bh * 131072;
  const unsigned short* Kp  = K  + (size_t)bh * 131072;
  const unsigned short* Vtp = Vt + (size_t)bh * 131072;

  // per-wave 16 q-rows
  const int qrow = qb + w * 16 + l15;
  bf16x8 qf0 = *(const bf16x8*)&Qp[(size_t)qrow * 64 + hi * 8];
  bf16x8 qf1 = *(const bf16x8*)&Qp[(size_t)qrow * 64 + 32 + hi * 8];

  f32x4 o[4] = {};
  float m_ = 0.f;                  // defer-max: start at 0 (scores log2-scaled)
  float l_ = 0.f;                  // per-lane partial; cross-lane reduce at end

  // staging: 512 threads, one 16B K-chunk + one 16B Vt-chunk each
  const int sr  = tid >> 3;        // 0..63
  const int sc8 = (tid & 7) * 8;
  const unsigned short* kptr = Kp  + (size_t)sr * 64 + sc8;
  const unsigned short* vptr = Vtp + (size_t)sr * 2048 + sc8;

  // prologue: tile 0 into regs (async-stage: issue early, write late)
  bf16x8 rk = *(const bf16x8*)kptr;
  bf16x8 rv = *(const bf16x8*)vptr;

  for (int kt = 0; kt < 32; ++kt) {
    __syncthreads();               // previous tile's compute done
    *(bf16x8*)&sK[sr * 72 + sc8]  = rk;
    *(bf16x8*)&sVt[sr * 72 + sc8] = rv;
    __syncthreads();               // LDS ready

    if (kt < 31) {                 // issue next tile's loads; land next iter
      kptr += 4096; vptr += 64;
      rk = *(const bf16x8*)kptr;
      rv = *(const bf16x8*)vptr;
    }

    // S^T = K Q^T : sc[ni][r] = S[key=16ni+4hi+r][q=l15]  (log2-units)
    f32x4 sc[4] = {};
    __builtin_amdgcn_s_setprio(1);
#pragma unroll
    for (int ni = 0; ni < 4; ++ni) {
      bf16x8 kf0 = *(const bf16x8*)&sK[(ni * 16 + l15) * 72 + hi * 8];
      bf16x8 kf1 = *(const bf16x8*)&sK[(ni * 16 + l15) * 72 + 32 + hi * 8];
      sc[ni] = __builtin_amdgcn_mfma_f32_16x16x32_bf16(kf0, qf0, sc[ni], 0, 0, 0);
      sc[ni] = __builtin_amdgcn_mfma_f32_16x16x32_bf16(kf1, qf1, sc[ni], 0, 0, 0);
    }
    __builtin_amdgcn_s_setprio(0);

    // per-lane tile max via max3 groupings (guard only; no shuffles fast-path)
    float t0 = MAX3(sc[0][0], sc[0][1], sc[0][2]);
    float t1 = MAX3(sc[0][3], sc[1][0], sc[1][1]);
    float t2 = MAX3(sc[1][2], sc[1][3], sc[2][0]);
    float t3 = MAX3(sc[2][1], sc[2][2], sc[2][3]);
    float t4 = MAX3(sc[3][0], sc[3][1], sc[3][2]);
    float pmax = fmaxf(MAX3(t0, t1, t2), MAX3(t3, t4, sc[3][3]));

    // T13: rescale only if P would exceed 2^8 (never fires on sane data)
    if (!__all(pmax - m_ <= 8.0f)) {
      pmax = fmaxf(pmax, __shfl_xor(pmax, 16));     // row-uniform max
      pmax = fmaxf(pmax, __shfl_xor(pmax, 32));
      float mnew  = fmaxf(m_, pmax);
      float alpha = EXP2(m_ - mnew);
      l_ *= alpha;
#pragma unroll
      for (int j = 0; j < 4; ++j) {
        float aj = __shfl(alpha, hi * 4 + j);
#pragma unroll
        for (int ni = 0; ni < 4; ++ni) o[ni][j] *= aj;
      }
      m_ = mnew;
    }

    const float mcur = m_;
    f32x4 sum4 = {};
#pragma unroll
    for (int ni = 0; ni < 4; ++ni)
#pragma unroll
      for (int r = 0; r < 4; ++r) {
        float p = EXP2(sc[ni][r] - mcur);
        sc[ni][r] = p;
        sum4[r] += p;
      }
    l_ += (sum4[0] + sum4[1]) + (sum4[2] + sum4[3]);   // per-lane partial

    // P -> per-wave LDS [q=l15][key]; v_cvt_pk_bf16_f32 (1 inst per 2 vals)
    unsigned short* pb = &sP[w][l15 * 72];
#pragma unroll
    for (int ni = 0; ni < 4; ++ni) {
      uint2 pk = { cvtpk(sc[ni][0], sc[ni][1]), cvtpk(sc[ni][2], sc[ni][3]) };
      *(uint2*)&pb[ni * 16 + hi * 4] = pk;
    }

    // O += P V
    bf16x8 pa0 = *(const bf16x8*)&sP[w][l15 * 72 + hi * 8];
    bf16x8 pa1 = *(const bf16x8*)&sP[w][l15 * 72 + 32 + hi * 8];
    __builtin_amdgcn_s_setprio(1);
#pragma unroll
    for (int ni = 0; ni < 4; ++ni) {
      bf16x8 vf0 = *(const bf16x8*)&sVt[(ni * 16 + l15) * 72 + hi * 8];
      bf16x8 vf1 = *(const bf16x8*)&sVt[(ni * 16 + l15) * 72 + 32 + hi * 8];
      o[ni] = __builtin_amdgcn_mfma_f32_16x16x32_bf16(pa0, vf0, o[ni], 0, 0, 0);
      o[ni] = __builtin_amdgcn_mfma_f32_16x16x32_bf16(pa1, vf1, o[ni], 0, 0, 0);
    }
    __builtin_amdgcn_s_setprio(0);
  }

  // final l reduction (deferred): sum partials across hi groups of the row
  l_ += __shfl_xor(l_, 16);
  l_ += __shfl_xor(l_, 32);
  float linv = 1.0f / l_;

  const int b = bh >> 4, h = bh & 15;
#pragma unroll
  for (int j = 0; j < 4; ++j) {
    float inv = __shfl(linv, hi * 4 + j);
    int row = qb + w * 16 + hi * 4 + j;
#pragma unroll
    for (int ni = 0; ni < 4; ++ni)
      O[((size_t)b * 2048 + row) * 1024 + h * 64 + ni * 16 + l15] = f2b(o[ni][j] * inv);
  }
}

// ---------------------------------------------------------------------------
extern "C" void kernel_launch(void* const* d_in, const int* in_sizes, int n_in,
                              void* d_out, int out_size, void* d_ws, size_t ws_size,
                              hipStream_t stream) {
  const float* x  = (const float*)d_in[0];
  const float* Wq = (const float*)d_in[1];
  const float* Wk = (const float*)d_in[2];
  const float* Wv = (const float*)d_in[3];
  const float* Wo = (const float*)d_in[4];
  float* out = (float*)d_out;

  char* w = (char*)d_ws;
  unsigned short* xb   = (unsigned short*)(w);                       // 16 MB
  unsigned short* wqkv = (unsigned short*)(w + 16777216);            //  6 MB
  unsigned short* wo   = (unsigned short*)(w + 23068672);            //  2 MB
  unsigned short* Qb   = (unsigned short*)(w + 25165824);            // 16 MB
  unsigned short* Kb   = (unsigned short*)(w + 41943040);            // 16 MB
  unsigned short* Vtb  = (unsigned short*)(w + 58720256);            // 16 MB (V transposed)
  unsigned short* Ob   = (unsigned short*)(w + 75497472);            // 16 MB

  conv_x_kernel<<<8192, 256, 0, stream>>>(x, xb, 2097152);
  conv_wqkv_kernel<<<768, 256, 0, stream>>>(Wq, Wk, Wv, wqkv);
  conv_wo_kernel<<<256, 256, 0, stream>>>(Wo, wo);
  gemm_qkv_kernel<<<dim3(24, 64), 256, 0, stream>>>(xb, wqkv, Qb, Kb, Vtb);
  attn_kernel<<<dim3(16, 64), 512, 0, stream>>>(Qb, Kb, Vtb, Ob);
  gemm_out_kernel<<<dim3(8, 64), 256, 0, stream>>>(Ob, wo, out);
}

// Round 10
// 199.699 us; speedup vs baseline: 1.8820x; 1.0557x over previous
//
#include <hip/hip_runtime.h>
#include <hip/hip_bf16.h>
#include <stdint.h>

typedef __attribute__((ext_vector_type(8))) short bf16x8;
typedef __attribute__((ext_vector_type(4))) float f32x4;
typedef __attribute__((ext_vector_type(4))) unsigned short us4;

#define AS1C(p) ((const __attribute__((address_space(1))) void*)(p))
#define AS3(p)  ((__attribute__((address_space(3))) void*)(p))

// raw v_exp_f32 (2^x). exp2f (libm) lowers to OCML with denormal fixup — slow.
#if __has_builtin(__builtin_amdgcn_exp2f)
#define EXP2(x) __builtin_amdgcn_exp2f(x)
#else
#define EXP2(x) __expf((x) * 0.69314718f)
#endif

#define MAX3(a,b,c) fmaxf(fmaxf((a),(b)),(c))   // clang fuses to v_max3_f32

static __device__ __forceinline__ unsigned short f2b(float f) {
  union { __hip_bfloat16 h; unsigned short u; } cv;
  cv.h = __float2bfloat16(f);
  return cv.u;
}

// T12 recipe: v_cvt_pk_bf16_f32 has no builtin on gfx950 — inline asm.
static __device__ __forceinline__ unsigned int cvtpk(float a, float b) {
  unsigned int r;
  asm("v_cvt_pk_bf16_f32 %0, %1, %2" : "=v"(r) : "v"(a), "v"(b));
  return r;
}

// ---------------------------------------------------------------------------
// Conversions
// ---------------------------------------------------------------------------
__global__ __launch_bounds__(256) void conv_x_kernel(const float* __restrict__ x,
                                                     unsigned short* __restrict__ xb,
                                                     int n4) {
  int i = blockIdx.x * 256 + threadIdx.x;
  if (i >= n4) return;
  float4 v = ((const float4*)x)[i];
  us4 r = { f2b(v.x), f2b(v.y), f2b(v.z), f2b(v.w) };
  *(us4*)&xb[(size_t)i * 4] = r;
}

// WqkvT[n][d] = W_{which}[h][d][c],  n = which*1024 + h*64 + c
__global__ __launch_bounds__(256) void conv_wqkv_kernel(const float* __restrict__ Wq,
                                                        const float* __restrict__ Wk,
                                                        const float* __restrict__ Wv,
                                                        unsigned short* __restrict__ WqkvT) {
  int bid = blockIdx.x;          // 3*16*16 = 768 blocks
  int which = bid >> 8;
  int h  = (bid >> 4) & 15;
  int dt = bid & 15;
  const float* W = (which == 0) ? Wq : (which == 1 ? Wk : Wv);
  __shared__ float tile[64][65];
  const int t = threadIdx.x;
  const int c  = t & 63;
  const int r0 = t >> 6;         // 0..3
  const float* src = W + (size_t)h * 65536 + (size_t)dt * 64 * 64;
#pragma unroll
  for (int it = 0; it < 16; ++it) {
    int r = r0 + it * 4;
    tile[r][c] = src[r * 64 + c];     // tile[d_local][c_local]
  }
  __syncthreads();
  const size_t n0 = (size_t)which * 1024 + h * 64;
  const int d0 = dt * 64;
#pragma unroll
  for (int it = 0; it < 16; ++it) {
    int cc = r0 + it * 4;             // c_local (output row)
    WqkvT[(n0 + cc) * 1024 + d0 + c] = f2b(tile[c][cc]);
  }
}

// WoT[n][k] = Wo[k][n]
__global__ __launch_bounds__(256) void conv_wo_kernel(const float* __restrict__ Wo,
                                                      unsigned short* __restrict__ WoT) {
  int kt = blockIdx.x >> 4, nt = blockIdx.x & 15;   // 256 blocks
  __shared__ float tile[64][65];
  const int t = threadIdx.x;
  const int c  = t & 63;
  const int r0 = t >> 6;
  const float* src = Wo + (size_t)(kt * 64) * 1024 + nt * 64;
#pragma unroll
  for (int it = 0; it < 16; ++it) {
    int r = r0 + it * 4;
    tile[r][c] = src[(size_t)r * 1024 + c];   // tile[k_local][n_local]
  }
  __syncthreads();
#pragma unroll
  for (int it = 0; it < 16; ++it) {
    int cc = r0 + it * 4;                     // n_local (output row)
    WoT[((size_t)nt * 64 + cc) * 1024 + kt * 64 + c] = f2b(tile[c][cc]);
  }
}

// ---------------------------------------------------------------------------
// GEMM 1: C[8192][3072] = x_bf16 [8192][1024] * WqkvT[3072][1024]^T
// epilogue: Q pre-scaled by (1/8)*log2(e) (exp2-folded softmax); K straight;
// V written TRANSPOSED into Vt[B*H][dk][S] (us4 packed stores, j spans s).
// ---------------------------------------------------------------------------
__global__ __launch_bounds__(256) void gemm_qkv_kernel(
    const unsigned short* __restrict__ A,
    const unsigned short* __restrict__ Bt,
    unsigned short* __restrict__ Q,
    unsigned short* __restrict__ Ko,
    unsigned short* __restrict__ Vt) {
  __shared__ __align__(16) unsigned short sA[128 * 32];
  __shared__ __align__(16) unsigned short sB[128 * 32];
  const int tid  = threadIdx.x;
  const int lane = tid & 63;
  const int wid  = tid >> 6;
  const int wr = wid >> 1, wc = wid & 1;
  const int brow = blockIdx.y * 128;
  const int bcol = blockIdx.x * 128;
  const int K = 1024;

  f32x4 acc[4][4] = {};

  const int r4 = tid >> 2;          // 0..63
  const int c8 = (tid & 3) * 8;
  const unsigned short* ga = A  + (size_t)(brow + r4) * K + c8;
  const unsigned short* gb = Bt + (size_t)(bcol + r4) * K + c8;
  unsigned short* lAw = sA + wid * 512;   // wave-uniform LDS base (lane*16B added by HW)
  unsigned short* lBw = sB + wid * 512;

  for (int kb = 0; kb < K; kb += 32) {
    if (kb) __syncthreads();
    __builtin_amdgcn_global_load_lds(AS1C(ga + kb),            AS3(lAw),        16, 0, 0);
    __builtin_amdgcn_global_load_lds(AS1C(ga + 64 * K + kb),   AS3(lAw + 2048), 16, 0, 0);
    __builtin_amdgcn_global_load_lds(AS1C(gb + kb),            AS3(lBw),        16, 0, 0);
    __builtin_amdgcn_global_load_lds(AS1C(gb + 64 * K + kb),   AS3(lBw + 2048), 16, 0, 0);
    __syncthreads();

    bf16x8 af[4], bfr[4];
#pragma unroll
    for (int mi = 0; mi < 4; ++mi)
      af[mi] = *(const bf16x8*)&sA[(wr * 64 + mi * 16 + (lane & 15)) * 32 + (lane >> 4) * 8];
#pragma unroll
    for (int ni = 0; ni < 4; ++ni)
      bfr[ni] = *(const bf16x8*)&sB[(wc * 64 + ni * 16 + (lane & 15)) * 32 + (lane >> 4) * 8];
#pragma unroll
    for (int mi = 0; mi < 4; ++mi)
#pragma unroll
      for (int ni = 0; ni < 4; ++ni)
        acc[mi][ni] = __builtin_amdgcn_mfma_f32_16x16x32_bf16(af[mi], bfr[ni], acc[mi][ni], 0, 0, 0);
  }

#pragma unroll
  for (int mi = 0; mi < 4; ++mi) {
    int row0 = brow + wr * 64 + mi * 16 + (lane >> 4) * 4;
    int b = row0 >> 11, s0 = row0 & 2047;
#pragma unroll
    for (int ni = 0; ni < 4; ++ni) {
      int col = bcol + wc * 64 + ni * 16 + (lane & 15);
      int which = col >> 10;      // block-uniform
      int h  = (col >> 6) & 15;
      int kk = col & 63;
      if (which == 2) {
        us4 pk = { f2b(acc[mi][ni][0]), f2b(acc[mi][ni][1]),
                   f2b(acc[mi][ni][2]), f2b(acc[mi][ni][3]) };
        *(us4*)&Vt[((size_t)(b * 16 + h) * 64 + kk) * 2048 + s0] = pk;
      } else {
        unsigned short* dst = (which == 0) ? Q : Ko;
        // Q: fold 1/sqrt(dk) * log2(e) so softmax uses raw v_exp (2^x)
        float scl = (which == 0) ? 0.18033688f : 1.0f;
#pragma unroll
        for (int j = 0; j < 4; ++j)
          dst[((size_t)(b * 16 + h) * 2048 + (s0 + j)) * 64 + kk] = f2b(acc[mi][ni][j] * scl);
      }
    }
  }
}

// ---------------------------------------------------------------------------
// GEMM 2: out[8192][1024] (fp32) = O_bf16 [8192][1024] * WoT[1024][1024]^T
// ---------------------------------------------------------------------------
__global__ __launch_bounds__(256) void gemm_out_kernel(
    const unsigned short* __restrict__ A,
    const unsigned short* __restrict__ Bt,
    float* __restrict__ out) {
  __shared__ __align__(16) unsigned short sA[128 * 32];
  __shared__ __align__(16) unsigned short sB[128 * 32];
  const int tid  = threadIdx.x;
  const int lane = tid & 63;
  const int wid  = tid >> 6;
  const int wr = wid >> 1, wc = wid & 1;
  const int brow = blockIdx.y * 128;
  const int bcol = blockIdx.x * 128;
  const int K = 1024;

  f32x4 acc[4][4] = {};

  const int r4 = tid >> 2;
  const int c8 = (tid & 3) * 8;
  const unsigned short* ga = A  + (size_t)(brow + r4) * K + c8;
  const unsigned short* gb = Bt + (size_t)(bcol + r4) * K + c8;
  unsigned short* lAw = sA + wid * 512;
  unsigned short* lBw = sB + wid * 512;

  for (int kb = 0; kb < K; kb += 32) {
    if (kb) __syncthreads();
    __builtin_amdgcn_global_load_lds(AS1C(ga + kb),          AS3(lAw),        16, 0, 0);
    __builtin_amdgcn_global_load_lds(AS1C(ga + 64 * K + kb), AS3(lAw + 2048), 16, 0, 0);
    __builtin_amdgcn_global_load_lds(AS1C(gb + kb),          AS3(lBw),        16, 0, 0);
    __builtin_amdgcn_global_load_lds(AS1C(gb + 64 * K + kb), AS3(lBw + 2048), 16, 0, 0);
    __syncthreads();

    bf16x8 af[4], bfr[4];
#pragma unroll
    for (int mi = 0; mi < 4; ++mi)
      af[mi] = *(const bf16x8*)&sA[(wr * 64 + mi * 16 + (lane & 15)) * 32 + (lane >> 4) * 8];
#pragma unroll
    for (int ni = 0; ni < 4; ++ni)
      bfr[ni] = *(const bf16x8*)&sB[(wc * 64 + ni * 16 + (lane & 15)) * 32 + (lane >> 4) * 8];
#pragma unroll
    for (int mi = 0; mi < 4; ++mi)
#pragma unroll
      for (int ni = 0; ni < 4; ++ni)
        acc[mi][ni] = __builtin_amdgcn_mfma_f32_16x16x32_bf16(af[mi], bfr[ni], acc[mi][ni], 0, 0, 0);
  }

#pragma unroll
  for (int mi = 0; mi < 4; ++mi) {
    int row0 = brow + wr * 64 + mi * 16 + (lane >> 4) * 4;
#pragma unroll
    for (int ni = 0; ni < 4; ++ni) {
      int col = bcol + wc * 64 + ni * 16 + (lane & 15);
#pragma unroll
      for (int j = 0; j < 4; ++j)
        out[(size_t)(row0 + j) * 1024 + col] = acc[mi][ni][j];
    }
  }
}

// ---------------------------------------------------------------------------
// Flash attention: 512-thread / 8-wave blocks, each wave owns 16 q-rows.
// DOUBLE-BUFFERED K/V staged via global_load_lds DMA (1 barrier per tile):
// issue tile t+1 loads right after the previous barrier, compute tile t,
// then one __syncthreads (its implicit vmcnt(0) drain lands after compute
// has hidden the L2 latency). Linear [64][64] LDS tiles with rule-#21
// both-sides XOR swizzle: global source pre-swizzled (chunk (l&7)^(row&7)),
// reads at chunk hi^(l15&7) — same bank spread as the proven pad-72 layout.
// Swapped QK^T + defer-max + exp2-folded softmax + cvt_pk P-pack + max3.
// grid 1024 blocks XCD-relabeled (8 bh per XCD).
// Q,K: [64][2048][64] bf16 (Q pre-scaled by 0.125*log2e).  Vt: [64][64][2048].
// O: [4][2048][1024] bf16.
// mfma(K,Q) -> C col = q = lane&15, row = key = (lane>>4)*4+reg.
// ---------------------------------------------------------------------------
__global__ __launch_bounds__(512) void attn_kernel(
    const unsigned short* __restrict__ Q,
    const unsigned short* __restrict__ K,
    const unsigned short* __restrict__ Vt,
    unsigned short* __restrict__ O) {
  __shared__ __align__(16) unsigned short sK[2][64 * 64];   // dbuf, XOR-swizzled
  __shared__ __align__(16) unsigned short sVt[2][64 * 64];  // dbuf, XOR-swizzled
  __shared__ __align__(16) unsigned short sP[8][16 * 72];   // [wave][q][key] pad 72

  const int tid = threadIdx.x, lane = tid & 63, w = tid >> 6;   // w = 0..7
  const int l15 = lane & 15, hi = lane >> 4;
  // bijective XCD relabel: dispatch n -> xcd = n&7; 8 bh per XCD, 16 q-blocks each
  const int n = blockIdx.x + (blockIdx.y << 4);
  const int bh = (n & 7) * 8 + ((n >> 3) >> 4);
  const int qx = (n >> 3) & 15;
  const int qb = qx * 128;
  const unsigned short* Qp  = Q  + (size_t)bh * 131072;
  const unsigned short* Kp  = K  + (size_t)bh * 131072;
  const unsigned short* Vtp = Vt + (size_t)bh * 131072;

  // per-wave 16 q-rows
  const int qrow = qb + w * 16 + l15;
  bf16x8 qf0 = *(const bf16x8*)&Qp[(size_t)qrow * 64 + hi * 8];
  bf16x8 qf1 = *(const bf16x8*)&Qp[(size_t)qrow * 64 + 32 + hi * 8];

  f32x4 o[4] = {};
  float m_ = 0.f;                  // defer-max: start at 0 (scores log2-scaled)
  float l_ = 0.f;                  // per-lane partial; cross-lane reduce at end

  // staging geometry: wave w owns rows w*8 .. w*8+7 of the 64-row tile.
  // lane l -> row w*8 + (l>>3), LDS chunk slot l&7 (HW: base + lane*16B).
  // pre-swizzle: global chunk = (l&7) ^ (row&7), row&7 == l>>3.
  const int lrow = lane >> 3;                 // 0..7
  const int uch  = (lane & 7) ^ lrow;         // unswizzled global chunk
  const unsigned short* kg = Kp  + (size_t)(w * 8 + lrow) * 64   + uch * 8;
  const unsigned short* vg = Vtp + (size_t)(w * 8 + lrow) * 2048 + uch * 8;
  unsigned short* dK0 = &sK[0][w * 512];      // wave-uniform LDS bases
  unsigned short* dK1 = &sK[1][w * 512];
  unsigned short* dV0 = &sVt[0][w * 512];
  unsigned short* dV1 = &sVt[1][w * 512];

  // read-side swizzle constant
  const int x7 = l15 & 7;
  const int ck0 = (hi ^ x7) * 8;              // chunk for elems 0..31 slice hi
  const int ck1 = ((hi + 4) ^ x7) * 8;        // chunk for elems 32..63 slice hi

  // prologue: tile 0 -> buf 0
  __builtin_amdgcn_global_load_lds(AS1C(kg), AS3(dK0), 16, 0, 0);
  __builtin_amdgcn_global_load_lds(AS1C(vg), AS3(dV0), 16, 0, 0);
  __syncthreads();

  for (int kt = 0; kt < 32; ++kt) {
    const int cur = kt & 1;
    if (kt < 31) {                 // issue next tile's DMA into the other buf
      kg += 4096; vg += 64;
      __builtin_amdgcn_global_load_lds(AS1C(kg), AS3(cur ? dK0 : dK1), 16, 0, 0);
      __builtin_amdgcn_global_load_lds(AS1C(vg), AS3(cur ? dV0 : dV1), 16, 0, 0);
    }
    const unsigned short* sKc  = &sK[cur][0];
    const unsigned short* sVtc = &sVt[cur][0];

    // S^T = K Q^T : sc[ni][r] = S[key=16ni+4hi+r][q=l15]  (log2-units)
    f32x4 sc[4] = {};
    __builtin_amdgcn_s_setprio(1);
#pragma unroll
    for (int ni = 0; ni < 4; ++ni) {
      bf16x8 kf0 = *(const bf16x8*)&sKc[(ni * 16 + l15) * 64 + ck0];
      bf16x8 kf1 = *(const bf16x8*)&sKc[(ni * 16 + l15) * 64 + ck1];
      sc[ni] = __builtin_amdgcn_mfma_f32_16x16x32_bf16(kf0, qf0, sc[ni], 0, 0, 0);
      sc[ni] = __builtin_amdgcn_mfma_f32_16x16x32_bf16(kf1, qf1, sc[ni], 0, 0, 0);
    }
    __builtin_amdgcn_s_setprio(0);

    // per-lane tile max via max3 groupings (guard only; no shuffles fast-path)
    float t0 = MAX3(sc[0][0], sc[0][1], sc[0][2]);
    float t1 = MAX3(sc[0][3], sc[1][0], sc[1][1]);
    float t2 = MAX3(sc[1][2], sc[1][3], sc[2][0]);
    float t3 = MAX3(sc[2][1], sc[2][2], sc[2][3]);
    float t4 = MAX3(sc[3][0], sc[3][1], sc[3][2]);
    float pmax = fmaxf(MAX3(t0, t1, t2), MAX3(t3, t4, sc[3][3]));

    // T13: rescale only if P would exceed 2^8 (never fires on sane data)
    if (!__all(pmax - m_ <= 8.0f)) {
      pmax = fmaxf(pmax, __shfl_xor(pmax, 16));     // row-uniform max
      pmax = fmaxf(pmax, __shfl_xor(pmax, 32));
      float mnew  = fmaxf(m_, pmax);
      float alpha = EXP2(m_ - mnew);
      l_ *= alpha;
#pragma unroll
      for (int j = 0; j < 4; ++j) {
        float aj = __shfl(alpha, hi * 4 + j);
#pragma unroll
        for (int ni = 0; ni < 4; ++ni) o[ni][j] *= aj;
      }
      m_ = mnew;
    }

    const float mcur = m_;
    f32x4 sum4 = {};
#pragma unroll
    for (int ni = 0; ni < 4; ++ni)
#pragma unroll
      for (int r = 0; r < 4; ++r) {
        float p = EXP2(sc[ni][r] - mcur);
        sc[ni][r] = p;
        sum4[r] += p;
      }
    l_ += (sum4[0] + sum4[1]) + (sum4[2] + sum4[3]);   // per-lane partial

    // P -> per-wave LDS [q=l15][key]; v_cvt_pk_bf16_f32 (1 inst per 2 vals)
    unsigned short* pb = &sP[w][l15 * 72];
#pragma unroll
    for (int ni = 0; ni < 4; ++ni) {
      uint2 pk = { cvtpk(sc[ni][0], sc[ni][1]), cvtpk(sc[ni][2], sc[ni][3]) };
      *(uint2*)&pb[ni * 16 + hi * 4] = pk;
    }

    // O += P V
    bf16x8 pa0 = *(const bf16x8*)&sP[w][l15 * 72 + hi * 8];
    bf16x8 pa1 = *(const bf16x8*)&sP[w][l15 * 72 + 32 + hi * 8];
    __builtin_amdgcn_s_setprio(1);
#pragma unroll
    for (int ni = 0; ni < 4; ++ni) {
      bf16x8 vf0 = *(const bf16x8*)&sVtc[(ni * 16 + l15) * 64 + ck0];
      bf16x8 vf1 = *(const bf16x8*)&sVtc[(ni * 16 + l15) * 64 + ck1];
      o[ni] = __builtin_amdgcn_mfma_f32_16x16x32_bf16(pa0, vf0, o[ni], 0, 0, 0);
      o[ni] = __builtin_amdgcn_mfma_f32_16x16x32_bf16(pa1, vf1, o[ni], 0, 0, 0);
    }
    __builtin_amdgcn_s_setprio(0);

    __syncthreads();               // publish next tile (vmcnt drained here)
  }

  // final l reduction (deferred): sum partials across hi groups of the row
  l_ += __shfl_xor(l_, 16);
  l_ += __shfl_xor(l_, 32);
  float linv = 1.0f / l_;

  const int b = bh >> 4, h = bh & 15;
#pragma unroll
  for (int j = 0; j < 4; ++j) {
    float inv = __shfl(linv, hi * 4 + j);
    int row = qb + w * 16 + hi * 4 + j;
#pragma unroll
    for (int ni = 0; ni < 4; ++ni)
      O[((size_t)b * 2048 + row) * 1024 + h * 64 + ni * 16 + l15] = f2b(o[ni][j] * inv);
  }
}

// ---------------------------------------------------------------------------
extern "C" void kernel_launch(void* const* d_in, const int* in_sizes, int n_in,
                              void* d_out, int out_size, void* d_ws, size_t ws_size,
                              hipStream_t stream) {
  const float* x  = (const float*)d_in[0];
  const float* Wq = (const float*)d_in[1];
  const float* Wk = (const float*)d_in[2];
  const float* Wv = (const float*)d_in[3];
  const float* Wo = (const float*)d_in[4];
  float* out = (float*)d_out;

  char* w = (char*)d_ws;
  unsigned short* xb   = (unsigned short*)(w);                       // 16 MB
  unsigned short* wqkv = (unsigned short*)(w + 16777216);            //  6 MB
  unsigned short* wo   = (unsigned short*)(w + 23068672);            //  2 MB
  unsigned short* Qb   = (unsigned short*)(w + 25165824);            // 16 MB
  unsigned short* Kb   = (unsigned short*)(w + 41943040);            // 16 MB
  unsigned short* Vtb  = (unsigned short*)(w + 58720256);            // 16 MB (V transposed)
  unsigned short* Ob   = (unsigned short*)(w + 75497472);            // 16 MB

  conv_x_kernel<<<8192, 256, 0, stream>>>(x, xb, 2097152);
  conv_wqkv_kernel<<<768, 256, 0, stream>>>(Wq, Wk, Wv, wqkv);
  conv_wo_kernel<<<256, 256, 0, stream>>>(Wo, wo);
  gemm_qkv_kernel<<<dim3(24, 64), 256, 0, stream>>>(xb, wqkv, Qb, Kb, Vtb);
  attn_kernel<<<dim3(16, 64), 512, 0, stream>>>(Qb, Kb, Vtb, Ob);
  gemm_out_kernel<<<dim3(8, 64), 256, 0, stream>>>(Ob, wo, out);
}

// Round 11
// 190.685 us; speedup vs baseline: 1.9710x; 1.0473x over previous
//
#include <hip/hip_runtime.h>
#include <hip/hip_bf16.h>
#include <stdint.h>

typedef __attribute__((ext_vector_type(8))) short bf16x8;
typedef __attribute__((ext_vector_type(4))) float f32x4;
typedef __attribute__((ext_vector_type(4))) unsigned short us4;

#define AS1C(p) ((const __attribute__((address_space(1))) void*)(p))
#define AS3(p)  ((__attribute__((address_space(3))) void*)(p))

// raw v_exp_f32 (2^x). exp2f (libm) lowers to OCML with denormal fixup — slow.
#if __has_builtin(__builtin_amdgcn_exp2f)
#define EXP2(x) __builtin_amdgcn_exp2f(x)
#else
#define EXP2(x) __expf((x) * 0.69314718f)
#endif

#define MAX3(a,b,c) fmaxf(fmaxf((a),(b)),(c))   // clang fuses to v_max3_f32

static __device__ __forceinline__ unsigned short f2b(float f) {
  union { __hip_bfloat16 h; unsigned short u; } cv;
  cv.h = __float2bfloat16(f);
  return cv.u;
}

// T12 recipe: v_cvt_pk_bf16_f32 has no builtin on gfx950 — inline asm.
static __device__ __forceinline__ unsigned int cvtpk(float a, float b) {
  unsigned int r;
  asm("v_cvt_pk_bf16_f32 %0, %1, %2" : "=v"(r) : "v"(a), "v"(b));
  return r;
}

// ---------------------------------------------------------------------------
// Conversions
// ---------------------------------------------------------------------------
__global__ __launch_bounds__(256) void conv_x_kernel(const float* __restrict__ x,
                                                     unsigned short* __restrict__ xb,
                                                     int n4) {
  int i = blockIdx.x * 256 + threadIdx.x;
  if (i >= n4) return;
  float4 v = ((const float4*)x)[i];
  us4 r = { f2b(v.x), f2b(v.y), f2b(v.z), f2b(v.w) };
  *(us4*)&xb[(size_t)i * 4] = r;
}

// WqkvT[n][d] = W_{which}[h][d][c],  n = which*1024 + h*64 + c
__global__ __launch_bounds__(256) void conv_wqkv_kernel(const float* __restrict__ Wq,
                                                        const float* __restrict__ Wk,
                                                        const float* __restrict__ Wv,
                                                        unsigned short* __restrict__ WqkvT) {
  int bid = blockIdx.x;          // 3*16*16 = 768 blocks
  int which = bid >> 8;
  int h  = (bid >> 4) & 15;
  int dt = bid & 15;
  const float* W = (which == 0) ? Wq : (which == 1 ? Wk : Wv);
  __shared__ float tile[64][65];
  const int t = threadIdx.x;
  const int c  = t & 63;
  const int r0 = t >> 6;         // 0..3
  const float* src = W + (size_t)h * 65536 + (size_t)dt * 64 * 64;
#pragma unroll
  for (int it = 0; it < 16; ++it) {
    int r = r0 + it * 4;
    tile[r][c] = src[r * 64 + c];     // tile[d_local][c_local]
  }
  __syncthreads();
  const size_t n0 = (size_t)which * 1024 + h * 64;
  const int d0 = dt * 64;
#pragma unroll
  for (int it = 0; it < 16; ++it) {
    int cc = r0 + it * 4;             // c_local (output row)
    WqkvT[(n0 + cc) * 1024 + d0 + c] = f2b(tile[c][cc]);
  }
}

// WoT[n][k] = Wo[k][n]
__global__ __launch_bounds__(256) void conv_wo_kernel(const float* __restrict__ Wo,
                                                      unsigned short* __restrict__ WoT) {
  int kt = blockIdx.x >> 4, nt = blockIdx.x & 15;   // 256 blocks
  __shared__ float tile[64][65];
  const int t = threadIdx.x;
  const int c  = t & 63;
  const int r0 = t >> 6;
  const float* src = Wo + (size_t)(kt * 64) * 1024 + nt * 64;
#pragma unroll
  for (int it = 0; it < 16; ++it) {
    int r = r0 + it * 4;
    tile[r][c] = src[(size_t)r * 1024 + c];   // tile[k_local][n_local]
  }
  __syncthreads();
#pragma unroll
  for (int it = 0; it < 16; ++it) {
    int cc = r0 + it * 4;                     // n_local (output row)
    WoT[((size_t)nt * 64 + cc) * 1024 + kt * 64 + c] = f2b(tile[c][cc]);
  }
}

// ---------------------------------------------------------------------------
// GEMM 1: C[8192][3072] = x_bf16 [8192][1024] * WqkvT[3072][1024]^T
// XCD-relabeled grid (bijective, 1536 = 8*192): consecutive blocks within an
// XCD share the A-row panel -> panel stays in that XCD's L2.
// epilogue: Q pre-scaled by (1/8)*log2(e); K straight; V transposed.
// ---------------------------------------------------------------------------
__global__ __launch_bounds__(256) void gemm_qkv_kernel(
    const unsigned short* __restrict__ A,
    const unsigned short* __restrict__ Bt,
    unsigned short* __restrict__ Q,
    unsigned short* __restrict__ Ko,
    unsigned short* __restrict__ Vt) {
  __shared__ __align__(16) unsigned short sA[128 * 32];
  __shared__ __align__(16) unsigned short sB[128 * 32];
  const int tid  = threadIdx.x;
  const int lane = tid & 63;
  const int wid  = tid >> 6;
  const int wr = wid >> 1, wc = wid & 1;
  const int n0 = blockIdx.y * 24 + blockIdx.x;        // 1536 blocks
  const int n1 = (n0 & 7) * 192 + (n0 >> 3);          // XCD-contiguous relabel
  const int brow = (n1 / 24) * 128;
  const int bcol = (n1 % 24) * 128;
  const int K = 1024;

  f32x4 acc[4][4] = {};

  const int r4 = tid >> 2;          // 0..63
  const int c8 = (tid & 3) * 8;
  const unsigned short* ga = A  + (size_t)(brow + r4) * K + c8;
  const unsigned short* gb = Bt + (size_t)(bcol + r4) * K + c8;
  unsigned short* lAw = sA + wid * 512;   // wave-uniform LDS base (lane*16B added by HW)
  unsigned short* lBw = sB + wid * 512;

  for (int kb = 0; kb < K; kb += 32) {
    if (kb) __syncthreads();
    __builtin_amdgcn_global_load_lds(AS1C(ga + kb),            AS3(lAw),        16, 0, 0);
    __builtin_amdgcn_global_load_lds(AS1C(ga + 64 * K + kb),   AS3(lAw + 2048), 16, 0, 0);
    __builtin_amdgcn_global_load_lds(AS1C(gb + kb),            AS3(lBw),        16, 0, 0);
    __builtin_amdgcn_global_load_lds(AS1C(gb + 64 * K + kb),   AS3(lBw + 2048), 16, 0, 0);
    __syncthreads();

    bf16x8 af[4], bfr[4];
#pragma unroll
    for (int mi = 0; mi < 4; ++mi)
      af[mi] = *(const bf16x8*)&sA[(wr * 64 + mi * 16 + (lane & 15)) * 32 + (lane >> 4) * 8];
#pragma unroll
    for (int ni = 0; ni < 4; ++ni)
      bfr[ni] = *(const bf16x8*)&sB[(wc * 64 + ni * 16 + (lane & 15)) * 32 + (lane >> 4) * 8];
#pragma unroll
    for (int mi = 0; mi < 4; ++mi)
#pragma unroll
      for (int ni = 0; ni < 4; ++ni)
        acc[mi][ni] = __builtin_amdgcn_mfma_f32_16x16x32_bf16(af[mi], bfr[ni], acc[mi][ni], 0, 0, 0);
  }

#pragma unroll
  for (int mi = 0; mi < 4; ++mi) {
    int row0 = brow + wr * 64 + mi * 16 + (lane >> 4) * 4;
    int b = row0 >> 11, s0 = row0 & 2047;
#pragma unroll
    for (int ni = 0; ni < 4; ++ni) {
      int col = bcol + wc * 64 + ni * 16 + (lane & 15);
      int which = col >> 10;      // block-uniform
      int h  = (col >> 6) & 15;
      int kk = col & 63;
      if (which == 2) {
        us4 pk = { f2b(acc[mi][ni][0]), f2b(acc[mi][ni][1]),
                   f2b(acc[mi][ni][2]), f2b(acc[mi][ni][3]) };
        *(us4*)&Vt[((size_t)(b * 16 + h) * 64 + kk) * 2048 + s0] = pk;
      } else {
        unsigned short* dst = (which == 0) ? Q : Ko;
        // Q: fold 1/sqrt(dk) * log2(e) so softmax uses raw v_exp (2^x)
        float scl = (which == 0) ? 0.18033688f : 1.0f;
#pragma unroll
        for (int j = 0; j < 4; ++j)
          dst[((size_t)(b * 16 + h) * 2048 + (s0 + j)) * 64 + kk] = f2b(acc[mi][ni][j] * scl);
      }
    }
  }
}

// ---------------------------------------------------------------------------
// GEMM 2: out[8192][1024] (fp32) = O_bf16 [8192][1024] * WoT[1024][1024]^T
// XCD-relabeled grid (512 = 8*64).
// ---------------------------------------------------------------------------
__global__ __launch_bounds__(256) void gemm_out_kernel(
    const unsigned short* __restrict__ A,
    const unsigned short* __restrict__ Bt,
    float* __restrict__ out) {
  __shared__ __align__(16) unsigned short sA[128 * 32];
  __shared__ __align__(16) unsigned short sB[128 * 32];
  const int tid  = threadIdx.x;
  const int lane = tid & 63;
  const int wid  = tid >> 6;
  const int wr = wid >> 1, wc = wid & 1;
  const int n0 = blockIdx.y * 8 + blockIdx.x;         // 512 blocks
  const int n1 = (n0 & 7) * 64 + (n0 >> 3);           // XCD-contiguous relabel
  const int brow = (n1 >> 3) * 128;
  const int bcol = (n1 & 7) * 128;
  const int K = 1024;

  f32x4 acc[4][4] = {};

  const int r4 = tid >> 2;
  const int c8 = (tid & 3) * 8;
  const unsigned short* ga = A  + (size_t)(brow + r4) * K + c8;
  const unsigned short* gb = Bt + (size_t)(bcol + r4) * K + c8;
  unsigned short* lAw = sA + wid * 512;
  unsigned short* lBw = sB + wid * 512;

  for (int kb = 0; kb < K; kb += 32) {
    if (kb) __syncthreads();
    __builtin_amdgcn_global_load_lds(AS1C(ga + kb),          AS3(lAw),        16, 0, 0);
    __builtin_amdgcn_global_load_lds(AS1C(ga + 64 * K + kb), AS3(lAw + 2048), 16, 0, 0);
    __builtin_amdgcn_global_load_lds(AS1C(gb + kb),          AS3(lBw),        16, 0, 0);
    __builtin_amdgcn_global_load_lds(AS1C(gb + 64 * K + kb), AS3(lBw + 2048), 16, 0, 0);
    __syncthreads();

    bf16x8 af[4], bfr[4];
#pragma unroll
    for (int mi = 0; mi < 4; ++mi)
      af[mi] = *(const bf16x8*)&sA[(wr * 64 + mi * 16 + (lane & 15)) * 32 + (lane >> 4) * 8];
#pragma unroll
    for (int ni = 0; ni < 4; ++ni)
      bfr[ni] = *(const bf16x8*)&sB[(wc * 64 + ni * 16 + (lane & 15)) * 32 + (lane >> 4) * 8];
#pragma unroll
    for (int mi = 0; mi < 4; ++mi)
#pragma unroll
      for (int ni = 0; ni < 4; ++ni)
        acc[mi][ni] = __builtin_amdgcn_mfma_f32_16x16x32_bf16(af[mi], bfr[ni], acc[mi][ni], 0, 0, 0);
  }

#pragma unroll
  for (int mi = 0; mi < 4; ++mi) {
    int row0 = brow + wr * 64 + mi * 16 + (lane >> 4) * 4;
#pragma unroll
    for (int ni = 0; ni < 4; ++ni) {
      int col = bcol + wc * 64 + ni * 16 + (lane & 15);
#pragma unroll
      for (int j = 0; j < 4; ++j)
        out[(size_t)(row0 + j) * 1024 + col] = acc[mi][ni][j];
    }
  }
}

// ---------------------------------------------------------------------------
// Flash attention: 512-thread / 8-wave blocks, each wave owns 32 q-rows
// (mi = 0,1 x 16), grid 512 blocks = exactly 2/CU -> zero scheduling tail.
// K/V staging (DMA dbuf, 1 barrier/tile) amortized over 2x compute; V
// fragments loaded once per ni, reused for both mi. Swapped QK^T + defer-max
// + exp2-folded softmax + cvt_pk P-pack + max3 + rule-#21 XOR swizzle.
// XCD relabel: 8 consecutive bh per XCD.
// Q,K: [64][2048][64] bf16 (Q pre-scaled by 0.125*log2e).  Vt: [64][64][2048].
// O: [4][2048][1024] bf16.
// mfma(K,Q) -> C col = q = lane&15, row = key = (lane>>4)*4+reg.
// ---------------------------------------------------------------------------
__global__ __launch_bounds__(512) void attn_kernel(
    const unsigned short* __restrict__ Q,
    const unsigned short* __restrict__ K,
    const unsigned short* __restrict__ Vt,
    unsigned short* __restrict__ O) {
  __shared__ __align__(16) unsigned short sK[2][64 * 64];   // dbuf, XOR-swizzled
  __shared__ __align__(16) unsigned short sVt[2][64 * 64];  // dbuf, XOR-swizzled
  __shared__ __align__(16) unsigned short sP[16][16 * 72];  // [w*2+mi][q][key] pad 72

  const int tid = threadIdx.x, lane = tid & 63, w = tid >> 6;   // w = 0..7
  const int l15 = lane & 15, hi = lane >> 4;
  // bijective relabel: grid (8, 64); xcd = n&7 -> 8 consecutive bh per XCD
  const int n = blockIdx.x + (blockIdx.y << 3);
  const int bh = (n & 7) * 8 + (n >> 6);
  const int qx = (n >> 3) & 7;
  const int qb = qx * 256;
  const unsigned short* Qp  = Q  + (size_t)bh * 131072;
  const unsigned short* Kp  = K  + (size_t)bh * 131072;
  const unsigned short* Vtp = Vt + (size_t)bh * 131072;

  // per-wave 32 q-rows (mi = 0,1)
  bf16x8 qf[2][2];
#pragma unroll
  for (int mi = 0; mi < 2; ++mi) {
    int qrow = qb + w * 32 + mi * 16 + l15;
    qf[mi][0] = *(const bf16x8*)&Qp[(size_t)qrow * 64 + hi * 8];
    qf[mi][1] = *(const bf16x8*)&Qp[(size_t)qrow * 64 + 32 + hi * 8];
  }

  f32x4 o[2][4] = {};
  float m_[2] = { 0.f, 0.f };      // defer-max: start at 0 (scores log2-scaled)
  float l_[2] = { 0.f, 0.f };      // per-lane partials; cross-lane reduce at end

  // staging geometry: wave w owns rows w*8 .. w*8+7 of the 64-row tile.
  // lane l -> row w*8 + (l>>3), LDS chunk slot l&7 (HW: base + lane*16B).
  // pre-swizzle: global chunk = (l&7) ^ (row&7), row&7 == l>>3.
  const int lrow = lane >> 3;                 // 0..7
  const int uch  = (lane & 7) ^ lrow;         // unswizzled global chunk
  const unsigned short* kg = Kp  + (size_t)(w * 8 + lrow) * 64   + uch * 8;
  const unsigned short* vg = Vtp + (size_t)(w * 8 + lrow) * 2048 + uch * 8;
  unsigned short* dK0 = &sK[0][w * 512];      // wave-uniform LDS bases
  unsigned short* dK1 = &sK[1][w * 512];
  unsigned short* dV0 = &sVt[0][w * 512];
  unsigned short* dV1 = &sVt[1][w * 512];

  // read-side swizzle constant
  const int x7 = l15 & 7;
  const int ck0 = (hi ^ x7) * 8;              // chunk for elems 0..31 slice hi
  const int ck1 = ((hi + 4) ^ x7) * 8;        // chunk for elems 32..63 slice hi

  // prologue: tile 0 -> buf 0
  __builtin_amdgcn_global_load_lds(AS1C(kg), AS3(dK0), 16, 0, 0);
  __builtin_amdgcn_global_load_lds(AS1C(vg), AS3(dV0), 16, 0, 0);
  __syncthreads();

  for (int kt = 0; kt < 32; ++kt) {
    const int cur = kt & 1;
    if (kt < 31) {                 // issue next tile's DMA into the other buf
      kg += 4096; vg += 64;
      __builtin_amdgcn_global_load_lds(AS1C(kg), AS3(cur ? dK0 : dK1), 16, 0, 0);
      __builtin_amdgcn_global_load_lds(AS1C(vg), AS3(cur ? dV0 : dV1), 16, 0, 0);
    }
    const unsigned short* sKc  = &sK[cur][0];
    const unsigned short* sVtc = &sVt[cur][0];

#pragma unroll
    for (int mi = 0; mi < 2; ++mi) {
      // S^T = K Q^T : sc[ni][r] = S[key=16ni+4hi+r][q=l15]  (log2-units)
      f32x4 sc[4] = {};
      __builtin_amdgcn_s_setprio(1);
#pragma unroll
      for (int ni = 0; ni < 4; ++ni) {
        bf16x8 kf0 = *(const bf16x8*)&sKc[(ni * 16 + l15) * 64 + ck0];
        bf16x8 kf1 = *(const bf16x8*)&sKc[(ni * 16 + l15) * 64 + ck1];
        sc[ni] = __builtin_amdgcn_mfma_f32_16x16x32_bf16(kf0, qf[mi][0], sc[ni], 0, 0, 0);
        sc[ni] = __builtin_amdgcn_mfma_f32_16x16x32_bf16(kf1, qf[mi][1], sc[ni], 0, 0, 0);
      }
      __builtin_amdgcn_s_setprio(0);

      // per-lane tile max via max3 (guard only; no shuffles on fast path)
      float t0 = MAX3(sc[0][0], sc[0][1], sc[0][2]);
      float t1 = MAX3(sc[0][3], sc[1][0], sc[1][1]);
      float t2 = MAX3(sc[1][2], sc[1][3], sc[2][0]);
      float t3 = MAX3(sc[2][1], sc[2][2], sc[2][3]);
      float t4 = MAX3(sc[3][0], sc[3][1], sc[3][2]);
      float pmax = fmaxf(MAX3(t0, t1, t2), MAX3(t3, t4, sc[3][3]));

      // T13: rescale only if P would exceed 2^8 (never fires on sane data)
      if (!__all(pmax - m_[mi] <= 8.0f)) {
        pmax = fmaxf(pmax, __shfl_xor(pmax, 16));     // row-uniform max
        pmax = fmaxf(pmax, __shfl_xor(pmax, 32));
        float mnew  = fmaxf(m_[mi], pmax);
        float alpha = EXP2(m_[mi] - mnew);
        l_[mi] *= alpha;
#pragma unroll
        for (int j = 0; j < 4; ++j) {
          float aj = __shfl(alpha, hi * 4 + j);
#pragma unroll
          for (int ni = 0; ni < 4; ++ni) o[mi][ni][j] *= aj;
        }
        m_[mi] = mnew;
      }

      const float mcur = m_[mi];
      f32x4 sum4 = {};
#pragma unroll
      for (int ni = 0; ni < 4; ++ni)
#pragma unroll
        for (int r = 0; r < 4; ++r) {
          float p = EXP2(sc[ni][r] - mcur);
          sc[ni][r] = p;
          sum4[r] += p;
        }
      l_[mi] += (sum4[0] + sum4[1]) + (sum4[2] + sum4[3]);   // per-lane partial

      // P -> per-wave LDS [q=l15][key]; v_cvt_pk_bf16_f32 (1 inst / 2 vals)
      unsigned short* pb = &sP[w * 2 + mi][l15 * 72];
#pragma unroll
      for (int ni = 0; ni < 4; ++ni) {
        uint2 pk = { cvtpk(sc[ni][0], sc[ni][1]), cvtpk(sc[ni][2], sc[ni][3]) };
        *(uint2*)&pb[ni * 16 + hi * 4] = pk;
      }
    }

    // O += P V  (vf loaded once per ni, reused for both mi)
    bf16x8 pa[2][2];
#pragma unroll
    for (int mi = 0; mi < 2; ++mi) {
      pa[mi][0] = *(const bf16x8*)&sP[w * 2 + mi][l15 * 72 + hi * 8];
      pa[mi][1] = *(const bf16x8*)&sP[w * 2 + mi][l15 * 72 + 32 + hi * 8];
    }
    __builtin_amdgcn_s_setprio(1);
#pragma unroll
    for (int ni = 0; ni < 4; ++ni) {
      bf16x8 vf0 = *(const bf16x8*)&sVtc[(ni * 16 + l15) * 64 + ck0];
      bf16x8 vf1 = *(const bf16x8*)&sVtc[(ni * 16 + l15) * 64 + ck1];
#pragma unroll
      for (int mi = 0; mi < 2; ++mi) {
        o[mi][ni] = __builtin_amdgcn_mfma_f32_16x16x32_bf16(pa[mi][0], vf0, o[mi][ni], 0, 0, 0);
        o[mi][ni] = __builtin_amdgcn_mfma_f32_16x16x32_bf16(pa[mi][1], vf1, o[mi][ni], 0, 0, 0);
      }
    }
    __builtin_amdgcn_s_setprio(0);

    __syncthreads();               // publish next tile (vmcnt drained here)
  }

  // final l reduction (deferred): sum partials across hi groups of the row
  const int b = bh >> 4, h = bh & 15;
#pragma unroll
  for (int mi = 0; mi < 2; ++mi) {
    float lm = l_[mi];
    lm += __shfl_xor(lm, 16);
    lm += __shfl_xor(lm, 32);
    float linv = 1.0f / lm;
#pragma unroll
    for (int j = 0; j < 4; ++j) {
      float inv = __shfl(linv, hi * 4 + j);
      int row = qb + w * 32 + mi * 16 + hi * 4 + j;
#pragma unroll
      for (int ni = 0; ni < 4; ++ni)
        O[((size_t)b * 2048 + row) * 1024 + h * 64 + ni * 16 + l15] = f2b(o[mi][ni][j] * inv);
    }
  }
}

// ---------------------------------------------------------------------------
extern "C" void kernel_launch(void* const* d_in, const int* in_sizes, int n_in,
                              void* d_out, int out_size, void* d_ws, size_t ws_size,
                              hipStream_t stream) {
  const float* x  = (const float*)d_in[0];
  const float* Wq = (const float*)d_in[1];
  const float* Wk = (const float*)d_in[2];
  const float* Wv = (const float*)d_in[3];
  const float* Wo = (const float*)d_in[4];
  float* out = (float*)d_out;

  char* w = (char*)d_ws;
  unsigned short* xb   = (unsigned short*)(w);                       // 16 MB
  unsigned short* wqkv = (unsigned short*)(w + 16777216);            //  6 MB
  unsigned short* wo   = (unsigned short*)(w + 23068672);            //  2 MB
  unsigned short* Qb   = (unsigned short*)(w + 25165824);            // 16 MB
  unsigned short* Kb   = (unsigned short*)(w + 41943040);            // 16 MB
  unsigned short* Vtb  = (unsigned short*)(w + 58720256);            // 16 MB (V transposed)
  unsigned short* Ob   = (unsigned short*)(w + 75497472);            // 16 MB

  conv_x_kernel<<<8192, 256, 0, stream>>>(x, xb, 2097152);
  conv_wqkv_kernel<<<768, 256, 0, stream>>>(Wq, Wk, Wv, wqkv);
  conv_wo_kernel<<<256, 256, 0, stream>>>(Wo, wo);
  gemm_qkv_kernel<<<dim3(24, 64), 256, 0, stream>>>(xb, wqkv, Qb, Kb, Vtb);
  attn_kernel<<<dim3(8, 64), 512, 0, stream>>>(Qb, Kb, Vtb, Ob);
  gemm_out_kernel<<<dim3(8, 64), 256, 0, stream>>>(Ob, wo, out);
}

// Round 12
// 184.625 us; speedup vs baseline: 2.0357x; 1.0328x over previous
//
#include <hip/hip_runtime.h>
#include <hip/hip_bf16.h>
#include <stdint.h>

typedef __attribute__((ext_vector_type(8))) short bf16x8;
typedef __attribute__((ext_vector_type(4))) float f32x4;
typedef __attribute__((ext_vector_type(4))) unsigned short us4;

#define AS1C(p) ((const __attribute__((address_space(1))) void*)(p))
#define AS3(p)  ((__attribute__((address_space(3))) void*)(p))

// raw v_exp_f32 (2^x). exp2f (libm) lowers to OCML with denormal fixup — slow.
#if __has_builtin(__builtin_amdgcn_exp2f)
#define EXP2(x) __builtin_amdgcn_exp2f(x)
#else
#define EXP2(x) __expf((x) * 0.69314718f)
#endif

#define MAX3(a,b,c) fmaxf(fmaxf((a),(b)),(c))   // clang fuses to v_max3_f32

static __device__ __forceinline__ unsigned short f2b(float f) {
  union { __hip_bfloat16 h; unsigned short u; } cv;
  cv.h = __float2bfloat16(f);
  return cv.u;
}

// T12 recipe: v_cvt_pk_bf16_f32 has no builtin on gfx950 — inline asm.
static __device__ __forceinline__ unsigned int cvtpk(float a, float b) {
  unsigned int r;
  asm("v_cvt_pk_bf16_f32 %0, %1, %2" : "=v"(r) : "v"(a), "v"(b));
  return r;
}

// ---------------------------------------------------------------------------
// Conversions
// ---------------------------------------------------------------------------
__global__ __launch_bounds__(256) void conv_x_kernel(const float* __restrict__ x,
                                                     unsigned short* __restrict__ xb,
                                                     int n4) {
  int i = blockIdx.x * 256 + threadIdx.x;
  if (i >= n4) return;
  float4 v = ((const float4*)x)[i];
  us4 r = { f2b(v.x), f2b(v.y), f2b(v.z), f2b(v.w) };
  *(us4*)&xb[(size_t)i * 4] = r;
}

// WqkvT[n][d] = W_{which}[h][d][c],  n = which*1024 + h*64 + c
__global__ __launch_bounds__(256) void conv_wqkv_kernel(const float* __restrict__ Wq,
                                                        const float* __restrict__ Wk,
                                                        const float* __restrict__ Wv,
                                                        unsigned short* __restrict__ WqkvT) {
  int bid = blockIdx.x;          // 3*16*16 = 768 blocks
  int which = bid >> 8;
  int h  = (bid >> 4) & 15;
  int dt = bid & 15;
  const float* W = (which == 0) ? Wq : (which == 1 ? Wk : Wv);
  __shared__ float tile[64][65];
  const int t = threadIdx.x;
  const int c  = t & 63;
  const int r0 = t >> 6;         // 0..3
  const float* src = W + (size_t)h * 65536 + (size_t)dt * 64 * 64;
#pragma unroll
  for (int it = 0; it < 16; ++it) {
    int r = r0 + it * 4;
    tile[r][c] = src[r * 64 + c];     // tile[d_local][c_local]
  }
  __syncthreads();
  const size_t n0 = (size_t)which * 1024 + h * 64;
  const int d0 = dt * 64;
#pragma unroll
  for (int it = 0; it < 16; ++it) {
    int cc = r0 + it * 4;             // c_local (output row)
    WqkvT[(n0 + cc) * 1024 + d0 + c] = f2b(tile[c][cc]);
  }
}

// WoT[n][k] = Wo[k][n]
__global__ __launch_bounds__(256) void conv_wo_kernel(const float* __restrict__ Wo,
                                                      unsigned short* __restrict__ WoT) {
  int kt = blockIdx.x >> 4, nt = blockIdx.x & 15;   // 256 blocks
  __shared__ float tile[64][65];
  const int t = threadIdx.x;
  const int c  = t & 63;
  const int r0 = t >> 6;
  const float* src = Wo + (size_t)(kt * 64) * 1024 + nt * 64;
#pragma unroll
  for (int it = 0; it < 16; ++it) {
    int r = r0 + it * 4;
    tile[r][c] = src[(size_t)r * 1024 + c];   // tile[k_local][n_local]
  }
  __syncthreads();
#pragma unroll
  for (int it = 0; it < 16; ++it) {
    int cc = r0 + it * 4;                     // n_local (output row)
    WoT[((size_t)nt * 64 + cc) * 1024 + kt * 64 + c] = f2b(tile[c][cc]);
  }
}

// ---------------------------------------------------------------------------
// GEMM 1: C[8192][3072] = x_bf16 [8192][1024] * WqkvT[3072][1024]^T
// XCD-relabeled grid (bijective, 1536 = 8*192).
// epilogue: Q pre-scaled by (1/8)*log2(e); K straight; V transposed.
// ---------------------------------------------------------------------------
__global__ __launch_bounds__(256) void gemm_qkv_kernel(
    const unsigned short* __restrict__ A,
    const unsigned short* __restrict__ Bt,
    unsigned short* __restrict__ Q,
    unsigned short* __restrict__ Ko,
    unsigned short* __restrict__ Vt) {
  __shared__ __align__(16) unsigned short sA[128 * 32];
  __shared__ __align__(16) unsigned short sB[128 * 32];
  const int tid  = threadIdx.x;
  const int lane = tid & 63;
  const int wid  = tid >> 6;
  const int wr = wid >> 1, wc = wid & 1;
  const int n0 = blockIdx.y * 24 + blockIdx.x;        // 1536 blocks
  const int n1 = (n0 & 7) * 192 + (n0 >> 3);          // XCD-contiguous relabel
  const int brow = (n1 / 24) * 128;
  const int bcol = (n1 % 24) * 128;
  const int K = 1024;

  f32x4 acc[4][4] = {};

  const int r4 = tid >> 2;          // 0..63
  const int c8 = (tid & 3) * 8;
  const unsigned short* ga = A  + (size_t)(brow + r4) * K + c8;
  const unsigned short* gb = Bt + (size_t)(bcol + r4) * K + c8;
  unsigned short* lAw = sA + wid * 512;   // wave-uniform LDS base (lane*16B added by HW)
  unsigned short* lBw = sB + wid * 512;

  for (int kb = 0; kb < K; kb += 32) {
    if (kb) __syncthreads();
    __builtin_amdgcn_global_load_lds(AS1C(ga + kb),            AS3(lAw),        16, 0, 0);
    __builtin_amdgcn_global_load_lds(AS1C(ga + 64 * K + kb),   AS3(lAw + 2048), 16, 0, 0);
    __builtin_amdgcn_global_load_lds(AS1C(gb + kb),            AS3(lBw),        16, 0, 0);
    __builtin_amdgcn_global_load_lds(AS1C(gb + 64 * K + kb),   AS3(lBw + 2048), 16, 0, 0);
    __syncthreads();

    bf16x8 af[4], bfr[4];
#pragma unroll
    for (int mi = 0; mi < 4; ++mi)
      af[mi] = *(const bf16x8*)&sA[(wr * 64 + mi * 16 + (lane & 15)) * 32 + (lane >> 4) * 8];
#pragma unroll
    for (int ni = 0; ni < 4; ++ni)
      bfr[ni] = *(const bf16x8*)&sB[(wc * 64 + ni * 16 + (lane & 15)) * 32 + (lane >> 4) * 8];
#pragma unroll
    for (int mi = 0; mi < 4; ++mi)
#pragma unroll
      for (int ni = 0; ni < 4; ++ni)
        acc[mi][ni] = __builtin_amdgcn_mfma_f32_16x16x32_bf16(af[mi], bfr[ni], acc[mi][ni], 0, 0, 0);
  }

#pragma unroll
  for (int mi = 0; mi < 4; ++mi) {
    int row0 = brow + wr * 64 + mi * 16 + (lane >> 4) * 4;
    int b = row0 >> 11, s0 = row0 & 2047;
#pragma unroll
    for (int ni = 0; ni < 4; ++ni) {
      int col = bcol + wc * 64 + ni * 16 + (lane & 15);
      int which = col >> 10;      // block-uniform
      int h  = (col >> 6) & 15;
      int kk = col & 63;
      if (which == 2) {
        us4 pk = { f2b(acc[mi][ni][0]), f2b(acc[mi][ni][1]),
                   f2b(acc[mi][ni][2]), f2b(acc[mi][ni][3]) };
        *(us4*)&Vt[((size_t)(b * 16 + h) * 64 + kk) * 2048 + s0] = pk;
      } else {
        unsigned short* dst = (which == 0) ? Q : Ko;
        // Q: fold 1/sqrt(dk) * log2(e) so softmax uses raw v_exp (2^x)
        float scl = (which == 0) ? 0.18033688f : 1.0f;
#pragma unroll
        for (int j = 0; j < 4; ++j)
          dst[((size_t)(b * 16 + h) * 2048 + (s0 + j)) * 64 + kk] = f2b(acc[mi][ni][j] * scl);
      }
    }
  }
}

// ---------------------------------------------------------------------------
// GEMM 2: out[8192][1024] (fp32) = O_bf16 [8192][1024] * WoT[1024][1024]^T
// XCD-relabeled grid (512 = 8*64).
// ---------------------------------------------------------------------------
__global__ __launch_bounds__(256) void gemm_out_kernel(
    const unsigned short* __restrict__ A,
    const unsigned short* __restrict__ Bt,
    float* __restrict__ out) {
  __shared__ __align__(16) unsigned short sA[128 * 32];
  __shared__ __align__(16) unsigned short sB[128 * 32];
  const int tid  = threadIdx.x;
  const int lane = tid & 63;
  const int wid  = tid >> 6;
  const int wr = wid >> 1, wc = wid & 1;
  const int n0 = blockIdx.y * 8 + blockIdx.x;         // 512 blocks
  const int n1 = (n0 & 7) * 64 + (n0 >> 3);           // XCD-contiguous relabel
  const int brow = (n1 >> 3) * 128;
  const int bcol = (n1 & 7) * 128;
  const int K = 1024;

  f32x4 acc[4][4] = {};

  const int r4 = tid >> 2;
  const int c8 = (tid & 3) * 8;
  const unsigned short* ga = A  + (size_t)(brow + r4) * K + c8;
  const unsigned short* gb = Bt + (size_t)(bcol + r4) * K + c8;
  unsigned short* lAw = sA + wid * 512;
  unsigned short* lBw = sB + wid * 512;

  for (int kb = 0; kb < K; kb += 32) {
    if (kb) __syncthreads();
    __builtin_amdgcn_global_load_lds(AS1C(ga + kb),          AS3(lAw),        16, 0, 0);
    __builtin_amdgcn_global_load_lds(AS1C(ga + 64 * K + kb), AS3(lAw + 2048), 16, 0, 0);
    __builtin_amdgcn_global_load_lds(AS1C(gb + kb),          AS3(lBw),        16, 0, 0);
    __builtin_amdgcn_global_load_lds(AS1C(gb + 64 * K + kb), AS3(lBw + 2048), 16, 0, 0);
    __syncthreads();

    bf16x8 af[4], bfr[4];
#pragma unroll
    for (int mi = 0; mi < 4; ++mi)
      af[mi] = *(const bf16x8*)&sA[(wr * 64 + mi * 16 + (lane & 15)) * 32 + (lane >> 4) * 8];
#pragma unroll
    for (int ni = 0; ni < 4; ++ni)
      bfr[ni] = *(const bf16x8*)&sB[(wc * 64 + ni * 16 + (lane & 15)) * 32 + (lane >> 4) * 8];
#pragma unroll
    for (int mi = 0; mi < 4; ++mi)
#pragma unroll
      for (int ni = 0; ni < 4; ++ni)
        acc[mi][ni] = __builtin_amdgcn_mfma_f32_16x16x32_bf16(af[mi], bfr[ni], acc[mi][ni], 0, 0, 0);
  }

#pragma unroll
  for (int mi = 0; mi < 4; ++mi) {
    int row0 = brow + wr * 64 + mi * 16 + (lane >> 4) * 4;
#pragma unroll
    for (int ni = 0; ni < 4; ++ni) {
      int col = bcol + wc * 64 + ni * 16 + (lane & 15);
#pragma unroll
      for (int j = 0; j < 4; ++j)
        out[(size_t)(row0 + j) * 1024 + col] = acc[mi][ni][j];
    }
  }
}

// ---------------------------------------------------------------------------
// Flash attention: 512-thread / 8-wave blocks, each wave owns 32 q-rows
// (mi = 0,1 x 16), grid 512 blocks = 2/CU, DMA-dbuf staging, 1 barrier/tile.
// VALU cuts this round:
//  (1) -m folded into QK^T accumulator init (biased scores; sub eliminated)
//  (2) l computed by MFMA against a ones-fragment (lacc[mi][j] = full row
//      sum; 20 VALU adds/tile + epilogue shuffles eliminated)
// Swapped QK^T + defer-max + exp2-folded softmax + cvt_pk P-pack + max3 +
// rule-#21 XOR swizzle. XCD relabel: 8 consecutive bh per XCD.
// Q,K: [64][2048][64] bf16 (Q pre-scaled by 0.125*log2e).  Vt: [64][64][2048].
// O: [4][2048][1024] bf16.
// mfma(K,Q) -> C col = q = lane&15, row = key = (lane>>4)*4+reg.
// ---------------------------------------------------------------------------
__global__ __launch_bounds__(512) void attn_kernel(
    const unsigned short* __restrict__ Q,
    const unsigned short* __restrict__ K,
    const unsigned short* __restrict__ Vt,
    unsigned short* __restrict__ O) {
  __shared__ __align__(16) unsigned short sK[2][64 * 64];   // dbuf, XOR-swizzled
  __shared__ __align__(16) unsigned short sVt[2][64 * 64];  // dbuf, XOR-swizzled
  __shared__ __align__(16) unsigned short sP[16][16 * 72];  // [w*2+mi][q][key] pad 72

  const int tid = threadIdx.x, lane = tid & 63, w = tid >> 6;   // w = 0..7
  const int l15 = lane & 15, hi = lane >> 4;
  // bijective relabel: grid (8, 64); xcd = n&7 -> 8 consecutive bh per XCD
  const int n = blockIdx.x + (blockIdx.y << 3);
  const int bh = (n & 7) * 8 + (n >> 6);
  const int qx = (n >> 3) & 7;
  const int qb = qx * 256;
  const unsigned short* Qp  = Q  + (size_t)bh * 131072;
  const unsigned short* Kp  = K  + (size_t)bh * 131072;
  const unsigned short* Vtp = Vt + (size_t)bh * 131072;

  // per-wave 32 q-rows (mi = 0,1)
  bf16x8 qf[2][2];
#pragma unroll
  for (int mi = 0; mi < 2; ++mi) {
    int qrow = qb + w * 32 + mi * 16 + l15;
    qf[mi][0] = *(const bf16x8*)&Qp[(size_t)qrow * 64 + hi * 8];
    qf[mi][1] = *(const bf16x8*)&Qp[(size_t)qrow * 64 + 32 + hi * 8];
  }

  // ones fragment for the l-sum MFMA (bf16 1.0 = 0x3F80)
  bf16x8 ones;
#pragma unroll
  for (int j = 0; j < 8; ++j) ones[j] = (short)0x3F80;

  f32x4 o[2][4] = {};
  f32x4 lacc[2] = {};              // lacc[mi][j] = running l for q = hi*4+j
  float m_[2] = { 0.f, 0.f };      // defer-max: absolute running max (log2 units)

  // staging geometry: wave w owns rows w*8 .. w*8+7 of the 64-row tile.
  const int lrow = lane >> 3;                 // 0..7
  const int uch  = (lane & 7) ^ lrow;         // pre-swizzled global chunk
  const unsigned short* kg = Kp  + (size_t)(w * 8 + lrow) * 64   + uch * 8;
  const unsigned short* vg = Vtp + (size_t)(w * 8 + lrow) * 2048 + uch * 8;
  unsigned short* dK0 = &sK[0][w * 512];      // wave-uniform LDS bases
  unsigned short* dK1 = &sK[1][w * 512];
  unsigned short* dV0 = &sVt[0][w * 512];
  unsigned short* dV1 = &sVt[1][w * 512];

  // read-side swizzle constants
  const int x7 = l15 & 7;
  const int ck0 = (hi ^ x7) * 8;
  const int ck1 = ((hi + 4) ^ x7) * 8;

  // prologue: tile 0 -> buf 0
  __builtin_amdgcn_global_load_lds(AS1C(kg), AS3(dK0), 16, 0, 0);
  __builtin_amdgcn_global_load_lds(AS1C(vg), AS3(dV0), 16, 0, 0);
  __syncthreads();

  for (int kt = 0; kt < 32; ++kt) {
    const int cur = kt & 1;
    if (kt < 31) {                 // issue next tile's DMA into the other buf
      kg += 4096; vg += 64;
      __builtin_amdgcn_global_load_lds(AS1C(kg), AS3(cur ? dK0 : dK1), 16, 0, 0);
      __builtin_amdgcn_global_load_lds(AS1C(vg), AS3(cur ? dV0 : dV1), 16, 0, 0);
    }
    const unsigned short* sKc  = &sK[cur][0];
    const unsigned short* sVtc = &sVt[cur][0];

#pragma unroll
    for (int mi = 0; mi < 2; ++mi) {
      // S^T - m = K Q^T + (-m) : acc init carries the bias (cut 1)
      const float mneg = -m_[mi];
      f32x4 sc[4] = { { mneg, mneg, mneg, mneg }, { mneg, mneg, mneg, mneg },
                      { mneg, mneg, mneg, mneg }, { mneg, mneg, mneg, mneg } };
      __builtin_amdgcn_s_setprio(1);
#pragma unroll
      for (int ni = 0; ni < 4; ++ni) {
        bf16x8 kf0 = *(const bf16x8*)&sKc[(ni * 16 + l15) * 64 + ck0];
        bf16x8 kf1 = *(const bf16x8*)&sKc[(ni * 16 + l15) * 64 + ck1];
        sc[ni] = __builtin_amdgcn_mfma_f32_16x16x32_bf16(kf0, qf[mi][0], sc[ni], 0, 0, 0);
        sc[ni] = __builtin_amdgcn_mfma_f32_16x16x32_bf16(kf1, qf[mi][1], sc[ni], 0, 0, 0);
      }
      __builtin_amdgcn_s_setprio(0);

      // per-lane biased tile max via max3 (guard only)
      float t0 = MAX3(sc[0][0], sc[0][1], sc[0][2]);
      float t1 = MAX3(sc[0][3], sc[1][0], sc[1][1]);
      float t2 = MAX3(sc[1][2], sc[1][3], sc[2][0]);
      float t3 = MAX3(sc[2][1], sc[2][2], sc[2][3]);
      float t4 = MAX3(sc[3][0], sc[3][1], sc[3][2]);
      float pmax = fmaxf(MAX3(t0, t1, t2), MAX3(t3, t4, sc[3][3]));

      // T13: rescale only if biased P would exceed 2^8 (never fires normally)
      if (!__all(pmax <= 8.0f)) {
        pmax = fmaxf(pmax, __shfl_xor(pmax, 16));     // row-uniform biased max
        pmax = fmaxf(pmax, __shfl_xor(pmax, 32));
        float delta = fmaxf(pmax, 0.f);               // mnew - mold
        float alpha = EXP2(-delta);
#pragma unroll
        for (int j = 0; j < 4; ++j) {
          float dj = __shfl(delta, hi * 4 + j);
          float aj = EXP2(-dj);
          lacc[mi][j] *= aj;
#pragma unroll
          for (int ni = 0; ni < 4; ++ni) o[mi][ni][j] *= aj;
        }
#pragma unroll
        for (int ni = 0; ni < 4; ++ni)
#pragma unroll
          for (int r = 0; r < 4; ++r) sc[ni][r] -= delta;
        m_[mi] += delta;
        (void)alpha;
      }

      f32x4 p4[4];
#pragma unroll
      for (int ni = 0; ni < 4; ++ni)
#pragma unroll
        for (int r = 0; r < 4; ++r)
          p4[ni][r] = EXP2(sc[ni][r]);

      // P -> per-wave LDS [q=l15][key]; v_cvt_pk_bf16_f32 (1 inst / 2 vals)
      unsigned short* pb = &sP[w * 2 + mi][l15 * 72];
#pragma unroll
      for (int ni = 0; ni < 4; ++ni) {
        uint2 pk = { cvtpk(p4[ni][0], p4[ni][1]), cvtpk(p4[ni][2], p4[ni][3]) };
        *(uint2*)&pb[ni * 16 + hi * 4] = pk;
      }
    }

    // O += P V ; lacc += P * ones (cut 2: l on the matrix pipe)
    bf16x8 pa[2][2];
#pragma unroll
    for (int mi = 0; mi < 2; ++mi) {
      pa[mi][0] = *(const bf16x8*)&sP[w * 2 + mi][l15 * 72 + hi * 8];
      pa[mi][1] = *(const bf16x8*)&sP[w * 2 + mi][l15 * 72 + 32 + hi * 8];
    }
    __builtin_amdgcn_s_setprio(1);
#pragma unroll
    for (int mi = 0; mi < 2; ++mi) {
      lacc[mi] = __builtin_amdgcn_mfma_f32_16x16x32_bf16(pa[mi][0], ones, lacc[mi], 0, 0, 0);
      lacc[mi] = __builtin_amdgcn_mfma_f32_16x16x32_bf16(pa[mi][1], ones, lacc[mi], 0, 0, 0);
    }
#pragma unroll
    for (int ni = 0; ni < 4; ++ni) {
      bf16x8 vf0 = *(const bf16x8*)&sVtc[(ni * 16 + l15) * 64 + ck0];
      bf16x8 vf1 = *(const bf16x8*)&sVtc[(ni * 16 + l15) * 64 + ck1];
#pragma unroll
      for (int mi = 0; mi < 2; ++mi) {
        o[mi][ni] = __builtin_amdgcn_mfma_f32_16x16x32_bf16(pa[mi][0], vf0, o[mi][ni], 0, 0, 0);
        o[mi][ni] = __builtin_amdgcn_mfma_f32_16x16x32_bf16(pa[mi][1], vf1, o[mi][ni], 0, 0, 0);
      }
    }
    __builtin_amdgcn_s_setprio(0);

    __syncthreads();               // publish next tile (vmcnt drained here)
  }

  // epilogue: lacc[mi][j] already holds the full l for q = hi*4+j — no shuffles
  const int b = bh >> 4, h = bh & 15;
#pragma unroll
  for (int mi = 0; mi < 2; ++mi) {
#pragma unroll
    for (int j = 0; j < 4; ++j) {
      float inv = 1.0f / lacc[mi][j];
      int row = qb + w * 32 + mi * 16 + hi * 4 + j;
#pragma unroll
      for (int ni = 0; ni < 4; ++ni)
        O[((size_t)b * 2048 + row) * 1024 + h * 64 + ni * 16 + l15] = f2b(o[mi][ni][j] * inv);
    }
  }
}

// ---------------------------------------------------------------------------
extern "C" void kernel_launch(void* const* d_in, const int* in_sizes, int n_in,
                              void* d_out, int out_size, void* d_ws, size_t ws_size,
                              hipStream_t stream) {
  const float* x  = (const float*)d_in[0];
  const float* Wq = (const float*)d_in[1];
  const float* Wk = (const float*)d_in[2];
  const float* Wv = (const float*)d_in[3];
  const float* Wo = (const float*)d_in[4];
  float* out = (float*)d_out;

  char* w = (char*)d_ws;
  unsigned short* xb   = (unsigned short*)(w);                       // 16 MB
  unsigned short* wqkv = (unsigned short*)(w + 16777216);            //  6 MB
  unsigned short* wo   = (unsigned short*)(w + 23068672);            //  2 MB
  unsigned short* Qb   = (unsigned short*)(w + 25165824);            // 16 MB
  unsigned short* Kb   = (unsigned short*)(w + 41943040);            // 16 MB
  unsigned short* Vtb  = (unsigned short*)(w + 58720256);            // 16 MB (V transposed)
  unsigned short* Ob   = (unsigned short*)(w + 75497472);            // 16 MB

  conv_x_kernel<<<8192, 256, 0, stream>>>(x, xb, 2097152);
  conv_wqkv_kernel<<<768, 256, 0, stream>>>(Wq, Wk, Wv, wqkv);
  conv_wo_kernel<<<256, 256, 0, stream>>>(Wo, wo);
  gemm_qkv_kernel<<<dim3(24, 64), 256, 0, stream>>>(xb, wqkv, Qb, Kb, Vtb);
  attn_kernel<<<dim3(8, 64), 512, 0, stream>>>(Qb, Kb, Vtb, Ob);
  gemm_out_kernel<<<dim3(8, 64), 256, 0, stream>>>(Ob, wo, out);
}

// Round 13
// 182.166 us; speedup vs baseline: 2.0632x; 1.0135x over previous
//
#include <hip/hip_runtime.h>
#include <hip/hip_bf16.h>
#include <stdint.h>

typedef __attribute__((ext_vector_type(8))) short bf16x8;
typedef __attribute__((ext_vector_type(4))) float f32x4;
typedef __attribute__((ext_vector_type(4))) unsigned short us4;

#define AS1C(p) ((const __attribute__((address_space(1))) void*)(p))
#define AS3(p)  ((__attribute__((address_space(3))) void*)(p))

// raw v_exp_f32 (2^x). exp2f (libm) lowers to OCML with denormal fixup — slow.
#if __has_builtin(__builtin_amdgcn_exp2f)
#define EXP2(x) __builtin_amdgcn_exp2f(x)
#else
#define EXP2(x) __expf((x) * 0.69314718f)
#endif

#define MAX3(a,b,c) fmaxf(fmaxf((a),(b)),(c))   // clang fuses to v_max3_f32

static __device__ __forceinline__ unsigned short f2b(float f) {
  union { __hip_bfloat16 h; unsigned short u; } cv;
  cv.h = __float2bfloat16(f);
  return cv.u;
}

// T12 recipe: v_cvt_pk_bf16_f32 has no builtin on gfx950 — inline asm.
static __device__ __forceinline__ unsigned int cvtpk(float a, float b) {
  unsigned int r;
  asm("v_cvt_pk_bf16_f32 %0, %1, %2" : "=v"(r) : "v"(a), "v"(b));
  return r;
}

// ---------------------------------------------------------------------------
// Fused conversions: one dispatch, blockIdx ranges select the job.
//   [0, 8192)      : x fp32 -> bf16 (vectorized)
//   [8192, 8960)   : Wq/Wk/Wv -> WqkvT[n][d] bf16 (LDS transpose)
//   [8960, 9216)   : Wo -> WoT[n][k] bf16 (LDS transpose)
// ---------------------------------------------------------------------------
__global__ __launch_bounds__(256) void conv_all_kernel(
    const float* __restrict__ x,  unsigned short* __restrict__ xb,
    const float* __restrict__ Wq, const float* __restrict__ Wk,
    const float* __restrict__ Wv, unsigned short* __restrict__ WqkvT,
    const float* __restrict__ Wo, unsigned short* __restrict__ WoT) {
  __shared__ float tile[64][65];
  const int bid = blockIdx.x;
  const int t = threadIdx.x;

  if (bid < 8192) {                       // ---- conv_x ----
    int i = bid * 256 + t;                // n4 = 2097152 exactly = 8192*256
    float4 v = ((const float4*)x)[i];
    us4 r = { f2b(v.x), f2b(v.y), f2b(v.z), f2b(v.w) };
    *(us4*)&xb[(size_t)i * 4] = r;
    return;
  }

  const int c  = t & 63;
  const int r0 = t >> 6;                  // 0..3

  if (bid < 8960) {                       // ---- conv_wqkv ----
    int b2 = bid - 8192;                  // 768 blocks
    int which = b2 >> 8;
    int h  = (b2 >> 4) & 15;
    int dt = b2 & 15;
    const float* W = (which == 0) ? Wq : (which == 1 ? Wk : Wv);
    const float* src = W + (size_t)h * 65536 + (size_t)dt * 64 * 64;
#pragma unroll
    for (int it = 0; it < 16; ++it) {
      int r = r0 + it * 4;
      tile[r][c] = src[r * 64 + c];       // tile[d_local][c_local]
    }
    __syncthreads();
    const size_t n0 = (size_t)which * 1024 + h * 64;
    const int d0 = dt * 64;
#pragma unroll
    for (int it = 0; it < 16; ++it) {
      int cc = r0 + it * 4;               // c_local (output row)
      WqkvT[(n0 + cc) * 1024 + d0 + c] = f2b(tile[c][cc]);
    }
    return;
  }

  {                                       // ---- conv_wo ----
    int b2 = bid - 8960;                  // 256 blocks
    int kt = b2 >> 4, nt = b2 & 15;
    const float* src = Wo + (size_t)(kt * 64) * 1024 + nt * 64;
#pragma unroll
    for (int it = 0; it < 16; ++it) {
      int r = r0 + it * 4;
      tile[r][c] = src[(size_t)r * 1024 + c];   // tile[k_local][n_local]
    }
    __syncthreads();
#pragma unroll
    for (int it = 0; it < 16; ++it) {
      int cc = r0 + it * 4;                     // n_local (output row)
      WoT[((size_t)nt * 64 + cc) * 1024 + kt * 64 + c] = f2b(tile[c][cc]);
    }
  }
}

// ---------------------------------------------------------------------------
// GEMM 1: C[8192][3072] = x_bf16 [8192][1024] * WqkvT[3072][1024]^T
// 512-thread / 8-wave blocks (wr = wid>>1 M-quadrant, wc = wid&1 N-half;
// per-wave 32x64 C, acc[2][4]) — ~85 VGPR/wave -> up to 4 blocks x 8 waves
// = 32 waves/CU (was ~12): wave-level overlap covers the barrier drain (m114).
// XCD-relabeled grid (bijective, 1536 = 8*192).
// epilogue: Q pre-scaled by (1/8)*log2(e); K straight; V transposed.
// ---------------------------------------------------------------------------
__global__ __launch_bounds__(512) void gemm_qkv_kernel(
    const unsigned short* __restrict__ A,
    const unsigned short* __restrict__ Bt,
    unsigned short* __restrict__ Q,
    unsigned short* __restrict__ Ko,
    unsigned short* __restrict__ Vt) {
  __shared__ __align__(16) unsigned short sA[128 * 32];
  __shared__ __align__(16) unsigned short sB[128 * 32];
  const int tid  = threadIdx.x;
  const int lane = tid & 63;
  const int wid  = tid >> 6;              // 0..7
  const int l15 = lane & 15, hi = lane >> 4;
  const int wr = wid >> 1, wc = wid & 1;
  const int n0 = blockIdx.y * 24 + blockIdx.x;        // 1536 blocks
  const int n1 = (n0 & 7) * 192 + (n0 >> 3);          // XCD-contiguous relabel
  const int brow = (n1 / 24) * 128;
  const int bcol = (n1 % 24) * 128;
  const int K = 1024;

  f32x4 acc[2][4] = {};

  const int r4 = tid >> 2;                // 0..127
  const int c8 = (tid & 3) * 8;
  const unsigned short* ga = A  + (size_t)(brow + r4) * K + c8;
  const unsigned short* gb = Bt + (size_t)(bcol + r4) * K + c8;
  unsigned short* lAw = sA + wid * 512;   // wave-uniform LDS base (lane*16B added by HW)
  unsigned short* lBw = sB + wid * 512;

  for (int kb = 0; kb < K; kb += 32) {
    if (kb) __syncthreads();
    __builtin_amdgcn_global_load_lds(AS1C(ga + kb), AS3(lAw), 16, 0, 0);
    __builtin_amdgcn_global_load_lds(AS1C(gb + kb), AS3(lBw), 16, 0, 0);
    __syncthreads();

    bf16x8 af[2], bfr[4];
#pragma unroll
    for (int mi = 0; mi < 2; ++mi)
      af[mi] = *(const bf16x8*)&sA[(wr * 32 + mi * 16 + l15) * 32 + hi * 8];
#pragma unroll
    for (int ni = 0; ni < 4; ++ni)
      bfr[ni] = *(const bf16x8*)&sB[(wc * 64 + ni * 16 + l15) * 32 + hi * 8];
#pragma unroll
    for (int mi = 0; mi < 2; ++mi)
#pragma unroll
      for (int ni = 0; ni < 4; ++ni)
        acc[mi][ni] = __builtin_amdgcn_mfma_f32_16x16x32_bf16(af[mi], bfr[ni], acc[mi][ni], 0, 0, 0);
  }

#pragma unroll
  for (int mi = 0; mi < 2; ++mi) {
    int row0 = brow + wr * 32 + mi * 16 + hi * 4;
    int b = row0 >> 11, s0 = row0 & 2047;
#pragma unroll
    for (int ni = 0; ni < 4; ++ni) {
      int col = bcol + wc * 64 + ni * 16 + l15;
      int which = col >> 10;      // block-uniform
      int h  = (col >> 6) & 15;
      int kk = col & 63;
      if (which == 2) {
        us4 pk = { f2b(acc[mi][ni][0]), f2b(acc[mi][ni][1]),
                   f2b(acc[mi][ni][2]), f2b(acc[mi][ni][3]) };
        *(us4*)&Vt[((size_t)(b * 16 + h) * 64 + kk) * 2048 + s0] = pk;
      } else {
        unsigned short* dst = (which == 0) ? Q : Ko;
        // Q: fold 1/sqrt(dk) * log2(e) so softmax uses raw v_exp (2^x)
        float scl = (which == 0) ? 0.18033688f : 1.0f;
#pragma unroll
        for (int j = 0; j < 4; ++j)
          dst[((size_t)(b * 16 + h) * 2048 + (s0 + j)) * 64 + kk] = f2b(acc[mi][ni][j] * scl);
      }
    }
  }
}

// ---------------------------------------------------------------------------
// GEMM 2: out[8192][1024] (fp32) = O_bf16 [8192][1024] * WoT[1024][1024]^T
// Same 8-wave restructure. XCD-relabeled grid (512 = 8*64).
// ---------------------------------------------------------------------------
__global__ __launch_bounds__(512) void gemm_out_kernel(
    const unsigned short* __restrict__ A,
    const unsigned short* __restrict__ Bt,
    float* __restrict__ out) {
  __shared__ __align__(16) unsigned short sA[128 * 32];
  __shared__ __align__(16) unsigned short sB[128 * 32];
  const int tid  = threadIdx.x;
  const int lane = tid & 63;
  const int wid  = tid >> 6;
  const int l15 = lane & 15, hi = lane >> 4;
  const int wr = wid >> 1, wc = wid & 1;
  const int n0 = blockIdx.y * 8 + blockIdx.x;         // 512 blocks
  const int n1 = (n0 & 7) * 64 + (n0 >> 3);           // XCD-contiguous relabel
  const int brow = (n1 >> 3) * 128;
  const int bcol = (n1 & 7) * 128;
  const int K = 1024;

  f32x4 acc[2][4] = {};

  const int r4 = tid >> 2;
  const int c8 = (tid & 3) * 8;
  const unsigned short* ga = A  + (size_t)(brow + r4) * K + c8;
  const unsigned short* gb = Bt + (size_t)(bcol + r4) * K + c8;
  unsigned short* lAw = sA + wid * 512;
  unsigned short* lBw = sB + wid * 512;

  for (int kb = 0; kb < K; kb += 32) {
    if (kb) __syncthreads();
    __builtin_amdgcn_global_load_lds(AS1C(ga + kb), AS3(lAw), 16, 0, 0);
    __builtin_amdgcn_global_load_lds(AS1C(gb + kb), AS3(lBw), 16, 0, 0);
    __syncthreads();

    bf16x8 af[2], bfr[4];
#pragma unroll
    for (int mi = 0; mi < 2; ++mi)
      af[mi] = *(const bf16x8*)&sA[(wr * 32 + mi * 16 + l15) * 32 + hi * 8];
#pragma unroll
    for (int ni = 0; ni < 4; ++ni)
      bfr[ni] = *(const bf16x8*)&sB[(wc * 64 + ni * 16 + l15) * 32 + hi * 8];
#pragma unroll
    for (int mi = 0; mi < 2; ++mi)
#pragma unroll
      for (int ni = 0; ni < 4; ++ni)
        acc[mi][ni] = __builtin_amdgcn_mfma_f32_16x16x32_bf16(af[mi], bfr[ni], acc[mi][ni], 0, 0, 0);
  }

#pragma unroll
  for (int mi = 0; mi < 2; ++mi) {
    int row0 = brow + wr * 32 + mi * 16 + hi * 4;
#pragma unroll
    for (int ni = 0; ni < 4; ++ni) {
      int col = bcol + wc * 64 + ni * 16 + l15;
#pragma unroll
      for (int j = 0; j < 4; ++j)
        out[(size_t)(row0 + j) * 1024 + col] = acc[mi][ni][j];
    }
  }
}

// ---------------------------------------------------------------------------
// Flash attention (UNCHANGED from R12 — verified at 86.7 us):
// 512-thread / 8-wave blocks, 32 q-rows/wave, grid 512 = 2/CU, DMA-dbuf
// staging, 1 barrier/tile, -m folded into MFMA acc init, l via ones-MFMA,
// swapped QK^T + defer-max + exp2-folded softmax + cvt_pk P-pack + max3 +
// rule-#21 XOR swizzle. XCD relabel: 8 consecutive bh per XCD.
// ---------------------------------------------------------------------------
__global__ __launch_bounds__(512) void attn_kernel(
    const unsigned short* __restrict__ Q,
    const unsigned short* __restrict__ K,
    const unsigned short* __restrict__ Vt,
    unsigned short* __restrict__ O) {
  __shared__ __align__(16) unsigned short sK[2][64 * 64];   // dbuf, XOR-swizzled
  __shared__ __align__(16) unsigned short sVt[2][64 * 64];  // dbuf, XOR-swizzled
  __shared__ __align__(16) unsigned short sP[16][16 * 72];  // [w*2+mi][q][key] pad 72

  const int tid = threadIdx.x, lane = tid & 63, w = tid >> 6;   // w = 0..7
  const int l15 = lane & 15, hi = lane >> 4;
  // bijective relabel: grid (8, 64); xcd = n&7 -> 8 consecutive bh per XCD
  const int n = blockIdx.x + (blockIdx.y << 3);
  const int bh = (n & 7) * 8 + (n >> 6);
  const int qx = (n >> 3) & 7;
  const int qb = qx * 256;
  const unsigned short* Qp  = Q  + (size_t)bh * 131072;
  const unsigned short* Kp  = K  + (size_t)bh * 131072;
  const unsigned short* Vtp = Vt + (size_t)bh * 131072;

  // per-wave 32 q-rows (mi = 0,1)
  bf16x8 qf[2][2];
#pragma unroll
  for (int mi = 0; mi < 2; ++mi) {
    int qrow = qb + w * 32 + mi * 16 + l15;
    qf[mi][0] = *(const bf16x8*)&Qp[(size_t)qrow * 64 + hi * 8];
    qf[mi][1] = *(const bf16x8*)&Qp[(size_t)qrow * 64 + 32 + hi * 8];
  }

  // ones fragment for the l-sum MFMA (bf16 1.0 = 0x3F80)
  bf16x8 ones;
#pragma unroll
  for (int j = 0; j < 8; ++j) ones[j] = (short)0x3F80;

  f32x4 o[2][4] = {};
  f32x4 lacc[2] = {};              // lacc[mi][j] = running l for q = hi*4+j
  float m_[2] = { 0.f, 0.f };      // defer-max: absolute running max (log2 units)

  // staging geometry: wave w owns rows w*8 .. w*8+7 of the 64-row tile.
  const int lrow = lane >> 3;                 // 0..7
  const int uch  = (lane & 7) ^ lrow;         // pre-swizzled global chunk
  const unsigned short* kg = Kp  + (size_t)(w * 8 + lrow) * 64   + uch * 8;
  const unsigned short* vg = Vtp + (size_t)(w * 8 + lrow) * 2048 + uch * 8;
  unsigned short* dK0 = &sK[0][w * 512];      // wave-uniform LDS bases
  unsigned short* dK1 = &sK[1][w * 512];
  unsigned short* dV0 = &sVt[0][w * 512];
  unsigned short* dV1 = &sVt[1][w * 512];

  // read-side swizzle constants
  const int x7 = l15 & 7;
  const int ck0 = (hi ^ x7) * 8;
  const int ck1 = ((hi + 4) ^ x7) * 8;

  // prologue: tile 0 -> buf 0
  __builtin_amdgcn_global_load_lds(AS1C(kg), AS3(dK0), 16, 0, 0);
  __builtin_amdgcn_global_load_lds(AS1C(vg), AS3(dV0), 16, 0, 0);
  __syncthreads();

  for (int kt = 0; kt < 32; ++kt) {
    const int cur = kt & 1;
    if (kt < 31) {                 // issue next tile's DMA into the other buf
      kg += 4096; vg += 64;
      __builtin_amdgcn_global_load_lds(AS1C(kg), AS3(cur ? dK0 : dK1), 16, 0, 0);
      __builtin_amdgcn_global_load_lds(AS1C(vg), AS3(cur ? dV0 : dV1), 16, 0, 0);
    }
    const unsigned short* sKc  = &sK[cur][0];
    const unsigned short* sVtc = &sVt[cur][0];

#pragma unroll
    for (int mi = 0; mi < 2; ++mi) {
      // S^T - m = K Q^T + (-m) : acc init carries the bias (cut 1)
      const float mneg = -m_[mi];
      f32x4 sc[4] = { { mneg, mneg, mneg, mneg }, { mneg, mneg, mneg, mneg },
                      { mneg, mneg, mneg, mneg }, { mneg, mneg, mneg, mneg } };
      __builtin_amdgcn_s_setprio(1);
#pragma unroll
      for (int ni = 0; ni < 4; ++ni) {
        bf16x8 kf0 = *(const bf16x8*)&sKc[(ni * 16 + l15) * 64 + ck0];
        bf16x8 kf1 = *(const bf16x8*)&sKc[(ni * 16 + l15) * 64 + ck1];
        sc[ni] = __builtin_amdgcn_mfma_f32_16x16x32_bf16(kf0, qf[mi][0], sc[ni], 0, 0, 0);
        sc[ni] = __builtin_amdgcn_mfma_f32_16x16x32_bf16(kf1, qf[mi][1], sc[ni], 0, 0, 0);
      }
      __builtin_amdgcn_s_setprio(0);

      // per-lane biased tile max via max3 (guard only)
      float t0 = MAX3(sc[0][0], sc[0][1], sc[0][2]);
      float t1 = MAX3(sc[0][3], sc[1][0], sc[1][1]);
      float t2 = MAX3(sc[1][2], sc[1][3], sc[2][0]);
      float t3 = MAX3(sc[2][1], sc[2][2], sc[2][3]);
      float t4 = MAX3(sc[3][0], sc[3][1], sc[3][2]);
      float pmax = fmaxf(MAX3(t0, t1, t2), MAX3(t3, t4, sc[3][3]));

      // T13: rescale only if biased P would exceed 2^8 (never fires normally)
      if (!__all(pmax <= 8.0f)) {
        pmax = fmaxf(pmax, __shfl_xor(pmax, 16));     // row-uniform biased max
        pmax = fmaxf(pmax, __shfl_xor(pmax, 32));
        float delta = fmaxf(pmax, 0.f);               // mnew - mold
#pragma unroll
        for (int j = 0; j < 4; ++j) {
          float dj = __shfl(delta, hi * 4 + j);
          float aj = EXP2(-dj);
          lacc[mi][j] *= aj;
#pragma unroll
          for (int ni = 0; ni < 4; ++ni) o[mi][ni][j] *= aj;
        }
#pragma unroll
        for (int ni = 0; ni < 4; ++ni)
#pragma unroll
          for (int r = 0; r < 4; ++r) sc[ni][r] -= delta;
        m_[mi] += delta;
      }

      f32x4 p4[4];
#pragma unroll
      for (int ni = 0; ni < 4; ++ni)
#pragma unroll
        for (int r = 0; r < 4; ++r)
          p4[ni][r] = EXP2(sc[ni][r]);

      // P -> per-wave LDS [q=l15][key]; v_cvt_pk_bf16_f32 (1 inst / 2 vals)
      unsigned short* pb = &sP[w * 2 + mi][l15 * 72];
#pragma unroll
      for (int ni = 0; ni < 4; ++ni) {
        uint2 pk = { cvtpk(p4[ni][0], p4[ni][1]), cvtpk(p4[ni][2], p4[ni][3]) };
        *(uint2*)&pb[ni * 16 + hi * 4] = pk;
      }
    }

    // O += P V ; lacc += P * ones (l on the matrix pipe)
    bf16x8 pa[2][2];
#pragma unroll
    for (int mi = 0; mi < 2; ++mi) {
      pa[mi][0] = *(const bf16x8*)&sP[w * 2 + mi][l15 * 72 + hi * 8];
      pa[mi][1] = *(const bf16x8*)&sP[w * 2 + mi][l15 * 72 + 32 + hi * 8];
    }
    __builtin_amdgcn_s_setprio(1);
#pragma unroll
    for (int mi = 0; mi < 2; ++mi) {
      lacc[mi] = __builtin_amdgcn_mfma_f32_16x16x32_bf16(pa[mi][0], ones, lacc[mi], 0, 0, 0);
      lacc[mi] = __builtin_amdgcn_mfma_f32_16x16x32_bf16(pa[mi][1], ones, lacc[mi], 0, 0, 0);
    }
#pragma unroll
    for (int ni = 0; ni < 4; ++ni) {
      bf16x8 vf0 = *(const bf16x8*)&sVtc[(ni * 16 + l15) * 64 + ck0];
      bf16x8 vf1 = *(const bf16x8*)&sVtc[(ni * 16 + l15) * 64 + ck1];
#pragma unroll
      for (int mi = 0; mi < 2; ++mi) {
        o[mi][ni] = __builtin_amdgcn_mfma_f32_16x16x32_bf16(pa[mi][0], vf0, o[mi][ni], 0, 0, 0);
        o[mi][ni] = __builtin_amdgcn_mfma_f32_16x16x32_bf16(pa[mi][1], vf1, o[mi][ni], 0, 0, 0);
      }
    }
    __builtin_amdgcn_s_setprio(0);

    __syncthreads();               // publish next tile (vmcnt drained here)
  }

  // epilogue: lacc[mi][j] already holds the full l for q = hi*4+j — no shuffles
  const int b = bh >> 4, h = bh & 15;
#pragma unroll
  for (int mi = 0; mi < 2; ++mi) {
#pragma unroll
    for (int j = 0; j < 4; ++j) {
      float inv = 1.0f / lacc[mi][j];
      int row = qb + w * 32 + mi * 16 + hi * 4 + j;
#pragma unroll
      for (int ni = 0; ni < 4; ++ni)
        O[((size_t)b * 2048 + row) * 1024 + h * 64 + ni * 16 + l15] = f2b(o[mi][ni][j] * inv);
    }
  }
}

// ---------------------------------------------------------------------------
extern "C" void kernel_launch(void* const* d_in, const int* in_sizes, int n_in,
                              void* d_out, int out_size, void* d_ws, size_t ws_size,
                              hipStream_t stream) {
  const float* x  = (const float*)d_in[0];
  const float* Wq = (const float*)d_in[1];
  const float* Wk = (const float*)d_in[2];
  const float* Wv = (const float*)d_in[3];
  const float* Wo = (const float*)d_in[4];
  float* out = (float*)d_out;

  char* w = (char*)d_ws;
  unsigned short* xb   = (unsigned short*)(w);                       // 16 MB
  unsigned short* wqkv = (unsigned short*)(w + 16777216);            //  6 MB
  unsigned short* wo   = (unsigned short*)(w + 23068672);            //  2 MB
  unsigned short* Qb   = (unsigned short*)(w + 25165824);            // 16 MB
  unsigned short* Kb   = (unsigned short*)(w + 41943040);            // 16 MB
  unsigned short* Vtb  = (unsigned short*)(w + 58720256);            // 16 MB (V transposed)
  unsigned short* Ob   = (unsigned short*)(w + 75497472);            // 16 MB

  conv_all_kernel<<<9216, 256, 0, stream>>>(x, xb, Wq, Wk, Wv, wqkv, Wo, wo);
  gemm_qkv_kernel<<<dim3(24, 64), 512, 0, stream>>>(xb, wqkv, Qb, Kb, Vtb);
  attn_kernel<<<dim3(8, 64), 512, 0, stream>>>(Qb, Kb, Vtb, Ob);
  gemm_out_kernel<<<dim3(8, 64), 512, 0, stream>>>(Ob, wo, out);
}

// Round 14
// 180.389 us; speedup vs baseline: 2.0835x; 1.0099x over previous
//
#include <hip/hip_runtime.h>
#include <hip/hip_bf16.h>
#include <stdint.h>

typedef __attribute__((ext_vector_type(8))) short bf16x8;
typedef __attribute__((ext_vector_type(4))) float f32x4;
typedef __attribute__((ext_vector_type(4))) unsigned short us4;

#define AS1C(p) ((const __attribute__((address_space(1))) void*)(p))
#define AS3(p)  ((__attribute__((address_space(3))) void*)(p))

// raw v_exp_f32 (2^x). exp2f (libm) lowers to OCML with denormal fixup — slow.
#if __has_builtin(__builtin_amdgcn_exp2f)
#define EXP2(x) __builtin_amdgcn_exp2f(x)
#else
#define EXP2(x) __expf((x) * 0.69314718f)
#endif

#define MAX3(a,b,c) fmaxf(fmaxf((a),(b)),(c))   // clang fuses to v_max3_f32

// compiler-fence + raw barrier discipline for counted-vmcnt pipelines.
// rule #18: every inline-asm waitcnt needs sched_barrier(0) so MFMAs/ds ops
// can't be hoisted across it; raw s_barrier is not a compiler fence either.
#define SBAR() __builtin_amdgcn_sched_barrier(0)
#define BARRIER() { SBAR(); __builtin_amdgcn_s_barrier(); SBAR(); }
#define WAIT_LGKM0() { asm volatile("s_waitcnt lgkmcnt(0)" ::: "memory"); SBAR(); }
#define WAIT_VM2() { asm volatile("s_waitcnt vmcnt(2)" ::: "memory"); SBAR(); }
#define WAIT_VM0() { asm volatile("s_waitcnt vmcnt(0)" ::: "memory"); SBAR(); }

static __device__ __forceinline__ unsigned short f2b(float f) {
  union { __hip_bfloat16 h; unsigned short u; } cv;
  cv.h = __float2bfloat16(f);
  return cv.u;
}

// T12 recipe: v_cvt_pk_bf16_f32 has no builtin on gfx950 — inline asm.
static __device__ __forceinline__ unsigned int cvtpk(float a, float b) {
  unsigned int r;
  asm("v_cvt_pk_bf16_f32 %0, %1, %2" : "=v"(r) : "v"(a), "v"(b));
  return r;
}

// ---------------------------------------------------------------------------
// Fused conversions: one dispatch, blockIdx ranges select the job.
// ---------------------------------------------------------------------------
__global__ __launch_bounds__(256) void conv_all_kernel(
    const float* __restrict__ x,  unsigned short* __restrict__ xb,
    const float* __restrict__ Wq, const float* __restrict__ Wk,
    const float* __restrict__ Wv, unsigned short* __restrict__ WqkvT,
    const float* __restrict__ Wo, unsigned short* __restrict__ WoT) {
  __shared__ float tile[64][65];
  const int bid = blockIdx.x;
  const int t = threadIdx.x;

  if (bid < 8192) {                       // ---- conv_x ----
    int i = bid * 256 + t;                // n4 = 2097152 exactly = 8192*256
    float4 v = ((const float4*)x)[i];
    us4 r = { f2b(v.x), f2b(v.y), f2b(v.z), f2b(v.w) };
    *(us4*)&xb[(size_t)i * 4] = r;
    return;
  }

  const int c  = t & 63;
  const int r0 = t >> 6;                  // 0..3

  if (bid < 8960) {                       // ---- conv_wqkv ----
    int b2 = bid - 8192;                  // 768 blocks
    int which = b2 >> 8;
    int h  = (b2 >> 4) & 15;
    int dt = b2 & 15;
    const float* W = (which == 0) ? Wq : (which == 1 ? Wk : Wv);
    const float* src = W + (size_t)h * 65536 + (size_t)dt * 64 * 64;
#pragma unroll
    for (int it = 0; it < 16; ++it) {
      int r = r0 + it * 4;
      tile[r][c] = src[r * 64 + c];       // tile[d_local][c_local]
    }
    __syncthreads();
    const size_t n0 = (size_t)which * 1024 + h * 64;
    const int d0 = dt * 64;
#pragma unroll
    for (int it = 0; it < 16; ++it) {
      int cc = r0 + it * 4;               // c_local (output row)
      WqkvT[(n0 + cc) * 1024 + d0 + c] = f2b(tile[c][cc]);
    }
    return;
  }

  {                                       // ---- conv_wo ----
    int b2 = bid - 8960;                  // 256 blocks
    int kt = b2 >> 4, nt = b2 & 15;
    const float* src = Wo + (size_t)(kt * 64) * 1024 + nt * 64;
#pragma unroll
    for (int it = 0; it < 16; ++it) {
      int r = r0 + it * 4;
      tile[r][c] = src[(size_t)r * 1024 + c];   // tile[k_local][n_local]
    }
    __syncthreads();
#pragma unroll
    for (int it = 0; it < 16; ++it) {
      int cc = r0 + it * 4;                     // n_local (output row)
      WoT[((size_t)nt * 64 + cc) * 1024 + kt * 64 + c] = f2b(tile[c][cc]);
    }
  }
}

// ---------------------------------------------------------------------------
// GEMM 1: C[8192][3072] = x_bf16 [8192][1024] * WqkvT[3072][1024]^T
// Ring-3 counted-vmcnt pipeline (T3/T4 mechanism): 3 LDS slots of one
// BK=32 K-tile; iter t stages tile t+2 (slot freed at t-1, reads fenced by
// lgkmcnt(0)+barrier), reads tile t (landed via prior iter's vmcnt(2),
// in-order completion), computes, vmcnt(2) + ONE raw s_barrier. Loads never
// drain to 0 in the loop — removes the ~20% barrier-drain stall.
// Read-side 2-way bank swizzle: src chunk c^((row>>1)&3), read hi^((l15>>1)&3).
// XCD-relabeled grid (bijective, 1536 = 8*192). 8 waves, 32x64 C per wave.
// epilogue: Q pre-scaled by (1/8)*log2(e); K straight; V transposed.
// ---------------------------------------------------------------------------
__global__ __launch_bounds__(512) void gemm_qkv_kernel(
    const unsigned short* __restrict__ A,
    const unsigned short* __restrict__ Bt,
    unsigned short* __restrict__ Q,
    unsigned short* __restrict__ Ko,
    unsigned short* __restrict__ Vt) {
  __shared__ __align__(16) unsigned short sL[3 * 8192];  // 48KB: 3 x (A[128][32] | B[128][32])
  const int tid  = threadIdx.x;
  const int lane = tid & 63;
  const int wid  = tid >> 6;              // 0..7
  const int l15 = lane & 15, hi = lane >> 4;
  const int wr = wid >> 1, wc = wid & 1;
  const int n0 = blockIdx.y * 24 + blockIdx.x;        // 1536 blocks
  const int n1 = (n0 & 7) * 192 + (n0 >> 3);          // XCD-contiguous relabel
  const int brow = (n1 / 24) * 128;
  const int bcol = (n1 % 24) * 128;
  const int K = 1024;

  f32x4 acc[2][4] = {};

  // staging: thread = chunk tid of [128 rows][4 x 16B]; source pre-swizzled
  const int srow = tid >> 2;
  const int suc  = (tid & 3) ^ ((srow >> 1) & 3);
  const unsigned short* gaS = A  + (size_t)(brow + srow) * K + suc * 8;
  const unsigned short* gbS = Bt + (size_t)(bcol + srow) * K + suc * 8;
  const int wofs = wid * 512;             // wave-uniform LDS base (shorts)

  // frag-read swizzle (row>>1)&3 == (l15>>1)&3 for all frag rows
  const int ck = (hi ^ ((l15 >> 1) & 3)) * 8;
  const int arow0 = wr * 32 + l15;        // + mi*16
  const int brow0 = wc * 64 + l15;        // + ni*16

#define QKV_STAGE(u) { \
    unsigned short* dst_ = sL + ((u) % 3) * 8192 + wofs; \
    __builtin_amdgcn_global_load_lds(AS1C(gaS + (u) * 32), AS3(dst_), 16, 0, 0); \
    __builtin_amdgcn_global_load_lds(AS1C(gbS + (u) * 32), AS3(dst_ + 4096), 16, 0, 0); \
  }

  QKV_STAGE(0); QKV_STAGE(1);
  WAIT_VM2(); BARRIER();

  for (int t = 0; t < 32; ++t) {
    if (t < 30) QKV_STAGE(t + 2);
    const unsigned short* sA_ = sL + (t % 3) * 8192;
    const unsigned short* sB_ = sA_ + 4096;
    bf16x8 af[2], bfr[4];
#pragma unroll
    for (int mi = 0; mi < 2; ++mi)
      af[mi] = *(const bf16x8*)&sA_[(arow0 + mi * 16) * 32 + ck];
#pragma unroll
    for (int ni = 0; ni < 4; ++ni)
      bfr[ni] = *(const bf16x8*)&sB_[(brow0 + ni * 16) * 32 + ck];
    WAIT_LGKM0();
#pragma unroll
    for (int mi = 0; mi < 2; ++mi)
#pragma unroll
      for (int ni = 0; ni < 4; ++ni)
        acc[mi][ni] = __builtin_amdgcn_mfma_f32_16x16x32_bf16(af[mi], bfr[ni], acc[mi][ni], 0, 0, 0);
    if (t < 30) { WAIT_VM2(); } else { WAIT_VM0(); }
    BARRIER();
  }
#undef QKV_STAGE

#pragma unroll
  for (int mi = 0; mi < 2; ++mi) {
    int row0 = brow + wr * 32 + mi * 16 + hi * 4;
    int b = row0 >> 11, s0 = row0 & 2047;
#pragma unroll
    for (int ni = 0; ni < 4; ++ni) {
      int col = bcol + wc * 64 + ni * 16 + l15;
      int which = col >> 10;      // block-uniform
      int h  = (col >> 6) & 15;
      int kk = col & 63;
      if (which == 2) {
        us4 pk = { f2b(acc[mi][ni][0]), f2b(acc[mi][ni][1]),
                   f2b(acc[mi][ni][2]), f2b(acc[mi][ni][3]) };
        *(us4*)&Vt[((size_t)(b * 16 + h) * 64 + kk) * 2048 + s0] = pk;
      } else {
        unsigned short* dst = (which == 0) ? Q : Ko;
        // Q: fold 1/sqrt(dk) * log2(e) so softmax uses raw v_exp (2^x)
        float scl = (which == 0) ? 0.18033688f : 1.0f;
#pragma unroll
        for (int j = 0; j < 4; ++j)
          dst[((size_t)(b * 16 + h) * 2048 + (s0 + j)) * 64 + kk] = f2b(acc[mi][ni][j] * scl);
      }
    }
  }
}

// ---------------------------------------------------------------------------
// GEMM 2: out[8192][1024] (fp32) = O_bf16 [8192][1024] * WoT[1024][1024]^T
// Same ring-3 counted-vmcnt structure. XCD-relabeled grid (512 = 8*64).
// ---------------------------------------------------------------------------
__global__ __launch_bounds__(512) void gemm_out_kernel(
    const unsigned short* __restrict__ A,
    const unsigned short* __restrict__ Bt,
    float* __restrict__ out) {
  __shared__ __align__(16) unsigned short sL[3 * 8192];
  const int tid  = threadIdx.x;
  const int lane = tid & 63;
  const int wid  = tid >> 6;
  const int l15 = lane & 15, hi = lane >> 4;
  const int wr = wid >> 1, wc = wid & 1;
  const int n0 = blockIdx.y * 8 + blockIdx.x;         // 512 blocks
  const int n1 = (n0 & 7) * 64 + (n0 >> 3);           // XCD-contiguous relabel
  const int brow = (n1 >> 3) * 128;
  const int bcol = (n1 & 7) * 128;
  const int K = 1024;

  f32x4 acc[2][4] = {};

  const int srow = tid >> 2;
  const int suc  = (tid & 3) ^ ((srow >> 1) & 3);
  const unsigned short* gaS = A  + (size_t)(brow + srow) * K + suc * 8;
  const unsigned short* gbS = Bt + (size_t)(bcol + srow) * K + suc * 8;
  const int wofs = wid * 512;

  const int ck = (hi ^ ((l15 >> 1) & 3)) * 8;
  const int arow0 = wr * 32 + l15;
  const int brow0 = wc * 64 + l15;

#define OUT_STAGE(u) { \
    unsigned short* dst_ = sL + ((u) % 3) * 8192 + wofs; \
    __builtin_amdgcn_global_load_lds(AS1C(gaS + (u) * 32), AS3(dst_), 16, 0, 0); \
    __builtin_amdgcn_global_load_lds(AS1C(gbS + (u) * 32), AS3(dst_ + 4096), 16, 0, 0); \
  }

  OUT_STAGE(0); OUT_STAGE(1);
  WAIT_VM2(); BARRIER();

  for (int t = 0; t < 32; ++t) {
    if (t < 30) OUT_STAGE(t + 2);
    const unsigned short* sA_ = sL + (t % 3) * 8192;
    const unsigned short* sB_ = sA_ + 4096;
    bf16x8 af[2], bfr[4];
#pragma unroll
    for (int mi = 0; mi < 2; ++mi)
      af[mi] = *(const bf16x8*)&sA_[(arow0 + mi * 16) * 32 + ck];
#pragma unroll
    for (int ni = 0; ni < 4; ++ni)
      bfr[ni] = *(const bf16x8*)&sB_[(brow0 + ni * 16) * 32 + ck];
    WAIT_LGKM0();
#pragma unroll
    for (int mi = 0; mi < 2; ++mi)
#pragma unroll
      for (int ni = 0; ni < 4; ++ni)
        acc[mi][ni] = __builtin_amdgcn_mfma_f32_16x16x32_bf16(af[mi], bfr[ni], acc[mi][ni], 0, 0, 0);
    if (t < 30) { WAIT_VM2(); } else { WAIT_VM0(); }
    BARRIER();
  }
#undef OUT_STAGE

#pragma unroll
  for (int mi = 0; mi < 2; ++mi) {
    int row0 = brow + wr * 32 + mi * 16 + hi * 4;
#pragma unroll
    for (int ni = 0; ni < 4; ++ni) {
      int col = bcol + wc * 64 + ni * 16 + l15;
#pragma unroll
      for (int j = 0; j < 4; ++j)
        out[(size_t)(row0 + j) * 1024 + col] = acc[mi][ni][j];
    }
  }
}

// ---------------------------------------------------------------------------
// Flash attention (UNCHANGED from R12/R13 — verified at ~87 us):
// 512-thread / 8-wave blocks, 32 q-rows/wave, grid 512 = 2/CU, DMA-dbuf
// staging, 1 barrier/tile, -m folded into MFMA acc init, l via ones-MFMA,
// swapped QK^T + defer-max + exp2-folded softmax + cvt_pk P-pack + max3 +
// rule-#21 XOR swizzle. XCD relabel: 8 consecutive bh per XCD.
// ---------------------------------------------------------------------------
__global__ __launch_bounds__(512) void attn_kernel(
    const unsigned short* __restrict__ Q,
    const unsigned short* __restrict__ K,
    const unsigned short* __restrict__ Vt,
    unsigned short* __restrict__ O) {
  __shared__ __align__(16) unsigned short sK[2][64 * 64];   // dbuf, XOR-swizzled
  __shared__ __align__(16) unsigned short sVt[2][64 * 64];  // dbuf, XOR-swizzled
  __shared__ __align__(16) unsigned short sP[16][16 * 72];  // [w*2+mi][q][key] pad 72

  const int tid = threadIdx.x, lane = tid & 63, w = tid >> 6;   // w = 0..7
  const int l15 = lane & 15, hi = lane >> 4;
  // bijective relabel: grid (8, 64); xcd = n&7 -> 8 consecutive bh per XCD
  const int n = blockIdx.x + (blockIdx.y << 3);
  const int bh = (n & 7) * 8 + (n >> 6);
  const int qx = (n >> 3) & 7;
  const int qb = qx * 256;
  const unsigned short* Qp  = Q  + (size_t)bh * 131072;
  const unsigned short* Kp  = K  + (size_t)bh * 131072;
  const unsigned short* Vtp = Vt + (size_t)bh * 131072;

  // per-wave 32 q-rows (mi = 0,1)
  bf16x8 qf[2][2];
#pragma unroll
  for (int mi = 0; mi < 2; ++mi) {
    int qrow = qb + w * 32 + mi * 16 + l15;
    qf[mi][0] = *(const bf16x8*)&Qp[(size_t)qrow * 64 + hi * 8];
    qf[mi][1] = *(const bf16x8*)&Qp[(size_t)qrow * 64 + 32 + hi * 8];
  }

  // ones fragment for the l-sum MFMA (bf16 1.0 = 0x3F80)
  bf16x8 ones;
#pragma unroll
  for (int j = 0; j < 8; ++j) ones[j] = (short)0x3F80;

  f32x4 o[2][4] = {};
  f32x4 lacc[2] = {};              // lacc[mi][j] = running l for q = hi*4+j
  float m_[2] = { 0.f, 0.f };      // defer-max: absolute running max (log2 units)

  // staging geometry: wave w owns rows w*8 .. w*8+7 of the 64-row tile.
  const int lrow = lane >> 3;                 // 0..7
  const int uch  = (lane & 7) ^ lrow;         // pre-swizzled global chunk
  const unsigned short* kg = Kp  + (size_t)(w * 8 + lrow) * 64   + uch * 8;
  const unsigned short* vg = Vtp + (size_t)(w * 8 + lrow) * 2048 + uch * 8;
  unsigned short* dK0 = &sK[0][w * 512];      // wave-uniform LDS bases
  unsigned short* dK1 = &sK[1][w * 512];
  unsigned short* dV0 = &sVt[0][w * 512];
  unsigned short* dV1 = &sVt[1][w * 512];

  // read-side swizzle constants
  const int x7 = l15 & 7;
  const int ck0 = (hi ^ x7) * 8;
  const int ck1 = ((hi + 4) ^ x7) * 8;

  // prologue: tile 0 -> buf 0
  __builtin_amdgcn_global_load_lds(AS1C(kg), AS3(dK0), 16, 0, 0);
  __builtin_amdgcn_global_load_lds(AS1C(vg), AS3(dV0), 16, 0, 0);
  __syncthreads();

  for (int kt = 0; kt < 32; ++kt) {
    const int cur = kt & 1;
    if (kt < 31) {                 // issue next tile's DMA into the other buf
      kg += 4096; vg += 64;
      __builtin_amdgcn_global_load_lds(AS1C(kg), AS3(cur ? dK0 : dK1), 16, 0, 0);
      __builtin_amdgcn_global_load_lds(AS1C(vg), AS3(cur ? dV0 : dV1), 16, 0, 0);
    }
    const unsigned short* sKc  = &sK[cur][0];
    const unsigned short* sVtc = &sVt[cur][0];

#pragma unroll
    for (int mi = 0; mi < 2; ++mi) {
      // S^T - m = K Q^T + (-m) : acc init carries the bias
      const float mneg = -m_[mi];
      f32x4 sc[4] = { { mneg, mneg, mneg, mneg }, { mneg, mneg, mneg, mneg },
                      { mneg, mneg, mneg, mneg }, { mneg, mneg, mneg, mneg } };
      __builtin_amdgcn_s_setprio(1);
#pragma unroll
      for (int ni = 0; ni < 4; ++ni) {
        bf16x8 kf0 = *(const bf16x8*)&sKc[(ni * 16 + l15) * 64 + ck0];
        bf16x8 kf1 = *(const bf16x8*)&sKc[(ni * 16 + l15) * 64 + ck1];
        sc[ni] = __builtin_amdgcn_mfma_f32_16x16x32_bf16(kf0, qf[mi][0], sc[ni], 0, 0, 0);
        sc[ni] = __builtin_amdgcn_mfma_f32_16x16x32_bf16(kf1, qf[mi][1], sc[ni], 0, 0, 0);
      }
      __builtin_amdgcn_s_setprio(0);

      // per-lane biased tile max via max3 (guard only)
      float t0 = MAX3(sc[0][0], sc[0][1], sc[0][2]);
      float t1 = MAX3(sc[0][3], sc[1][0], sc[1][1]);
      float t2 = MAX3(sc[1][2], sc[1][3], sc[2][0]);
      float t3 = MAX3(sc[2][1], sc[2][2], sc[2][3]);
      float t4 = MAX3(sc[3][0], sc[3][1], sc[3][2]);
      float pmax = fmaxf(MAX3(t0, t1, t2), MAX3(t3, t4, sc[3][3]));

      // T13: rescale only if biased P would exceed 2^8 (never fires normally)
      if (!__all(pmax <= 8.0f)) {
        pmax = fmaxf(pmax, __shfl_xor(pmax, 16));     // row-uniform biased max
        pmax = fmaxf(pmax, __shfl_xor(pmax, 32));
        float delta = fmaxf(pmax, 0.f);               // mnew - mold
#pragma unroll
        for (int j = 0; j < 4; ++j) {
          float dj = __shfl(delta, hi * 4 + j);
          float aj = EXP2(-dj);
          lacc[mi][j] *= aj;
#pragma unroll
          for (int ni = 0; ni < 4; ++ni) o[mi][ni][j] *= aj;
        }
#pragma unroll
        for (int ni = 0; ni < 4; ++ni)
#pragma unroll
          for (int r = 0; r < 4; ++r) sc[ni][r] -= delta;
        m_[mi] += delta;
      }

      f32x4 p4[4];
#pragma unroll
      for (int ni = 0; ni < 4; ++ni)
#pragma unroll
        for (int r = 0; r < 4; ++r)
          p4[ni][r] = EXP2(sc[ni][r]);

      // P -> per-wave LDS [q=l15][key]; v_cvt_pk_bf16_f32 (1 inst / 2 vals)
      unsigned short* pb = &sP[w * 2 + mi][l15 * 72];
#pragma unroll
      for (int ni = 0; ni < 4; ++ni) {
        uint2 pk = { cvtpk(p4[ni][0], p4[ni][1]), cvtpk(p4[ni][2], p4[ni][3]) };
        *(uint2*)&pb[ni * 16 + hi * 4] = pk;
      }
    }

    // O += P V ; lacc += P * ones (l on the matrix pipe)
    bf16x8 pa[2][2];
#pragma unroll
    for (int mi = 0; mi < 2; ++mi) {
      pa[mi][0] = *(const bf16x8*)&sP[w * 2 + mi][l15 * 72 + hi * 8];
      pa[mi][1] = *(const bf16x8*)&sP[w * 2 + mi][l15 * 72 + 32 + hi * 8];
    }
    __builtin_amdgcn_s_setprio(1);
#pragma unroll
    for (int mi = 0; mi < 2; ++mi) {
      lacc[mi] = __builtin_amdgcn_mfma_f32_16x16x32_bf16(pa[mi][0], ones, lacc[mi], 0, 0, 0);
      lacc[mi] = __builtin_amdgcn_mfma_f32_16x16x32_bf16(pa[mi][1], ones, lacc[mi], 0, 0, 0);
    }
#pragma unroll
    for (int ni = 0; ni < 4; ++ni) {
      bf16x8 vf0 = *(const bf16x8*)&sVtc[(ni * 16 + l15) * 64 + ck0];
      bf16x8 vf1 = *(const bf16x8*)&sVtc[(ni * 16 + l15) * 64 + ck1];
#pragma unroll
      for (int mi = 0; mi < 2; ++mi) {
        o[mi][ni] = __builtin_amdgcn_mfma_f32_16x16x32_bf16(pa[mi][0], vf0, o[mi][ni], 0, 0, 0);
        o[mi][ni] = __builtin_amdgcn_mfma_f32_16x16x32_bf16(pa[mi][1], vf1, o[mi][ni], 0, 0, 0);
      }
    }
    __builtin_amdgcn_s_setprio(0);

    __syncthreads();               // publish next tile (vmcnt drained here)
  }

  // epilogue: lacc[mi][j] already holds the full l for q = hi*4+j — no shuffles
  const int b = bh >> 4, h = bh & 15;
#pragma unroll
  for (int mi = 0; mi < 2; ++mi) {
#pragma unroll
    for (int j = 0; j < 4; ++j) {
      float inv = 1.0f / lacc[mi][j];
      int row = qb + w * 32 + mi * 16 + hi * 4 + j;
#pragma unroll
      for (int ni = 0; ni < 4; ++ni)
        O[((size_t)b * 2048 + row) * 1024 + h * 64 + ni * 16 + l15] = f2b(o[mi][ni][j] * inv);
    }
  }
}

// ---------------------------------------------------------------------------
extern "C" void kernel_launch(void* const* d_in, const int* in_sizes, int n_in,
                              void* d_out, int out_size, void* d_ws, size_t ws_size,
                              hipStream_t stream) {
  const float* x  = (const float*)d_in[0];
  const float* Wq = (const float*)d_in[1];
  const float* Wk = (const float*)d_in[2];
  const float* Wv = (const float*)d_in[3];
  const float* Wo = (const float*)d_in[4];
  float* out = (float*)d_out;

  char* w = (char*)d_ws;
  unsigned short* xb   = (unsigned short*)(w);                       // 16 MB
  unsigned short* wqkv = (unsigned short*)(w + 16777216);            //  6 MB
  unsigned short* wo   = (unsigned short*)(w + 23068672);            //  2 MB
  unsigned short* Qb   = (unsigned short*)(w + 25165824);            // 16 MB
  unsigned short* Kb   = (unsigned short*)(w + 41943040);            // 16 MB
  unsigned short* Vtb  = (unsigned short*)(w + 58720256);            // 16 MB (V transposed)
  unsigned short* Ob   = (unsigned short*)(w + 75497472);            // 16 MB

  conv_all_kernel<<<9216, 256, 0, stream>>>(x, xb, Wq, Wk, Wv, wqkv, Wo, wo);
  gemm_qkv_kernel<<<dim3(24, 64), 512, 0, stream>>>(xb, wqkv, Qb, Kb, Vtb);
  attn_kernel<<<dim3(8, 64), 512, 0, stream>>>(Qb, Kb, Vtb, Ob);
  gemm_out_kernel<<<dim3(8, 64), 512, 0, stream>>>(Ob, wo, out);
}